// Round 1
// baseline (1658.253 us; speedup 1.0000x reference)
//
#include <hip/hip_runtime.h>
#include <hip/hip_bf16.h>

#define NH 8
#define NLV 4
#define NPT 4
#define BS_ 8
#define NQ_ 100
#define NK_ 17
#define LQ 1700            // NQ_*NK_
#define T_TOK 13600        // BS_*LQ
#define LEN_VV 34000

__device__ __forceinline__ float wave_sum(float v){
#pragma unroll
  for (int m = 32; m; m >>= 1) v += __shfl_xor(v, m, 64);
  return v;
}
__device__ __forceinline__ float wave_max(float v){
#pragma unroll
  for (int m = 32; m; m >>= 1) v = fmaxf(v, __shfl_xor(v, m, 64));
  return v;
}

// ---------------- elementwise add (float4) ----------------
__global__ __launch_bounds__(256) void add_k(const float* __restrict__ a,
                                             const float* __restrict__ b,
                                             float* __restrict__ o, int n4){
  int i = blockIdx.x * 256 + threadIdx.x;
  if (i >= n4) return;
  float4 x = ((const float4*)a)[i];
  float4 y = ((const float4*)b)[i];
  float4 r; r.x = x.x + y.x; r.y = x.y + y.y; r.z = x.z + y.z; r.w = x.w + y.w;
  ((float4*)o)[i] = r;
}

// ---------------- transpose (b,q,k,d) -> (b,k,q,d) ----------------
__global__ __launch_bounds__(256) void transpose_k(const float* __restrict__ in,
                                                   float* __restrict__ outp){
  int i = blockIdx.x * 256 + threadIdx.x;
  if (i >= T_TOK * 64) return;
  int orow = i >> 6, c = i & 63;
  int b = orow / LQ, rem = orow % LQ;
  int kk = rem / NQ_, q = rem % NQ_;
  int irow = b * LQ + q * NK_ + kk;
  ((float4*)outp)[(size_t)orow * 64 + c] = ((const float4*)in)[(size_t)irow * 64 + c];
}

// ---------------- concat [a|b] rows 256+256 -> 512 ----------------
__global__ __launch_bounds__(256) void concat_k(const float* __restrict__ a,
                                                const float* __restrict__ b,
                                                float* __restrict__ o){
  int i = blockIdx.x * 256 + threadIdx.x;
  if (i >= T_TOK * 128) return;
  int row = i >> 7, c = i & 127;
  float4 v = (c < 64) ? ((const float4*)a)[(size_t)row * 64 + c]
                      : ((const float4*)b)[(size_t)row * 64 + (c - 64)];
  ((float4*)o)[(size_t)row * 128 + c] = v;
}

// ---------------- generic GEMM: C[M,N] = A[M,K] @ W[N,K]^T + bias ----------------
// EPI: 0 none, 1 relu, 2 sigmoid.  OUTB: 1 -> bf16 output
template<int EPI, int OUTB>
__global__ __launch_bounds__(256) void gemm_k(const float* __restrict__ A,
                                              const float* __restrict__ W,
                                              const float* __restrict__ bias,
                                              float* __restrict__ Cf,
                                              __hip_bfloat16* __restrict__ Cb,
                                              int M, int N, int K){
  __shared__ float As[16][68];
  __shared__ float Ws[16][68];
  int tid = threadIdx.x;
  int tx = tid & 15, ty = tid >> 4;
  int bm = blockIdx.x * 64, bn = blockIdx.y * 64;
  int lr = tid >> 2, lc = tid & 3;
  float acc[4][4] = {};
  const float* Arow = A + (size_t)(bm + lr) * K + lc * 4;
  const float* Wrow = W + (size_t)(bn + lr) * K + lc * 4;
  bool aok = (bm + lr) < M;
  for (int k0 = 0; k0 < K; k0 += 16){
    float4 av = make_float4(0.f, 0.f, 0.f, 0.f);
    if (aok) av = *(const float4*)(Arow + k0);
    float4 wv = *(const float4*)(Wrow + k0);
    As[lc * 4 + 0][lr] = av.x; As[lc * 4 + 1][lr] = av.y;
    As[lc * 4 + 2][lr] = av.z; As[lc * 4 + 3][lr] = av.w;
    Ws[lc * 4 + 0][lr] = wv.x; Ws[lc * 4 + 1][lr] = wv.y;
    Ws[lc * 4 + 2][lr] = wv.z; Ws[lc * 4 + 3][lr] = wv.w;
    __syncthreads();
#pragma unroll
    for (int k = 0; k < 16; k++){
      float4 a4 = *(const float4*)&As[k][ty * 4];
      float4 w4 = *(const float4*)&Ws[k][tx * 4];
      acc[0][0] += a4.x * w4.x; acc[0][1] += a4.x * w4.y; acc[0][2] += a4.x * w4.z; acc[0][3] += a4.x * w4.w;
      acc[1][0] += a4.y * w4.x; acc[1][1] += a4.y * w4.y; acc[1][2] += a4.y * w4.z; acc[1][3] += a4.y * w4.w;
      acc[2][0] += a4.z * w4.x; acc[2][1] += a4.z * w4.y; acc[2][2] += a4.z * w4.z; acc[2][3] += a4.z * w4.w;
      acc[3][0] += a4.w * w4.x; acc[3][1] += a4.w * w4.y; acc[3][2] += a4.w * w4.z; acc[3][3] += a4.w * w4.w;
    }
    __syncthreads();
  }
#pragma unroll
  for (int i = 0; i < 4; i++){
    int m = bm + ty * 4 + i;
    if (m >= M) continue;
#pragma unroll
    for (int j = 0; j < 4; j++){
      int n = bn + tx * 4 + j;
      float c = acc[i][j] + bias[n];
      if (EPI == 1) c = fmaxf(c, 0.f);
      if (EPI == 2) c = 1.f / (1.f + expf(-c));
      if (OUTB) Cb[(size_t)m * N + n] = __float2bfloat16(c);
      else      Cf[(size_t)m * N + n] = c;
    }
  }
}

// ---------------- MHA core: one block per (batch, head) ----------------
// qkv rows: token-major, 768 = [q(256)|k(256)|v(256)], each 256 = (H, dh)
__global__ __launch_bounds__(256) void mha_k(const float* __restrict__ qkv,
                                             float* __restrict__ out, int S){
  extern __shared__ float sm[];
  const int SP = 33;
  float* qs = sm;
  float* ks = qs + S * SP;
  float* vs = ks + S * SP;
  float* ps = vs + S * SP;   // [4][128]
  int bh = blockIdx.x;
  int batch = bh >> 3, h = bh & 7;
  int tid = threadIdx.x;
  size_t base = (size_t)batch * S * 768 + h * 32;
  for (int idx = tid; idx < S * 32; idx += 256){
    int s = idx >> 5, e = idx & 31;
    size_t g = base + (size_t)s * 768 + e;
    qs[s * SP + e] = qkv[g];
    ks[s * SP + e] = qkv[g + 256];
    vs[s * SP + e] = qkv[g + 512];
  }
  __syncthreads();
  int wave = tid >> 6, lane = tid & 63;
  const float scale = 0.17677669529663687f; // 1/sqrt(32)
  for (int r = wave; r < S; r += 4){
    int j1 = lane, j2 = lane + 64;
    float d1 = -1e30f, d2 = -1e30f;
    if (j1 < S){
      float t = 0.f;
#pragma unroll
      for (int e = 0; e < 32; e++) t += qs[r * SP + e] * ks[j1 * SP + e];
      d1 = t * scale;
    }
    if (j2 < S){
      float t = 0.f;
#pragma unroll
      for (int e = 0; e < 32; e++) t += qs[r * SP + e] * ks[j2 * SP + e];
      d2 = t * scale;
    }
    float mx = wave_max(fmaxf(d1, d2));
    float e1 = (j1 < S) ? expf(d1 - mx) : 0.f;
    float e2 = (j2 < S) ? expf(d2 - mx) : 0.f;
    float sum = wave_sum(e1 + e2);
    float inv = 1.f / sum;
    if (j1 < S) ps[wave * 128 + j1] = e1 * inv;
    if (j2 < S) ps[wave * 128 + j2] = e2 * inv;
    int e = lane & 31, half = lane >> 5;
    float acc = 0.f;
    for (int j = half; j < S; j += 2) acc += ps[wave * 128 + j] * vs[j * SP + e];
    acc += __shfl_xor(acc, 32, 64);
    if (lane < 32) out[((size_t)batch * S + r) * 256 + h * 32 + e] = acc;
  }
}

// ---------------- LayerNorm over 256; MODE 0 plain, 1 permuted-write, 2 clip ----------------
template<int MODE>
__global__ __launch_bounds__(64) void ln_k(const float* __restrict__ a,
                                           const float* __restrict__ b,
                                           const float* __restrict__ g,
                                           const float* __restrict__ be,
                                           float* __restrict__ out){
  int r = blockIdx.x;
  int lane = threadIdx.x;
  float4 xa = *(const float4*)(a + (size_t)r * 256 + lane * 4);
  float4 xb = *(const float4*)(b + (size_t)r * 256 + lane * 4);
  float x[4] = { xa.x + xb.x, xa.y + xb.y, xa.z + xb.z, xa.w + xb.w };
  if (MODE == 2){
#pragma unroll
    for (int i = 0; i < 4; i++) x[i] = fminf(fmaxf(x[i], -65504.f), 65504.f);
  }
  float s = x[0] + x[1] + x[2] + x[3];
  s = wave_sum(s);
  float mean = s * (1.f / 256.f);
  float sq = 0.f;
#pragma unroll
  for (int i = 0; i < 4; i++){ float d = x[i] - mean; sq += d * d; }
  float var = wave_sum(sq) * (1.f / 256.f);
  float rstd = rsqrtf(var + 1e-5f);
  float4 gg = *(const float4*)(g + lane * 4);
  float4 bb = *(const float4*)(be + lane * 4);
  size_t orow = r;
  if (MODE == 1){
    int bi = r / LQ; int rem = r % LQ; int kk = rem / NQ_; int q = rem % NQ_;
    orow = (size_t)bi * LQ + q * NK_ + kk;
  }
  float4 o;
  o.x = (x[0] - mean) * rstd * gg.x + bb.x;
  o.y = (x[1] - mean) * rstd * gg.y + bb.y;
  o.z = (x[2] - mean) * rstd * gg.z + bb.z;
  o.w = (x[3] - mean) * rstd * gg.w + bb.w;
  *(float4*)(out + orow * 256 + lane * 4) = o;
}

// ---------------- gate combine + LN ----------------
__global__ __launch_bounds__(64) void gate_ln_k(const float* __restrict__ G,
                                                const float* __restrict__ aq,
                                                const float* __restrict__ t2,
                                                const float* __restrict__ g,
                                                const float* __restrict__ be,
                                                float* __restrict__ out){
  int r = blockIdx.x;
  int lane = threadIdx.x;
  float4 g1 = *(const float4*)(G + (size_t)r * 512 + lane * 4);
  float4 g2 = *(const float4*)(G + (size_t)r * 512 + 256 + lane * 4);
  float4 xa = *(const float4*)(aq + (size_t)r * 256 + lane * 4);
  float4 xt = *(const float4*)(t2 + (size_t)r * 256 + lane * 4);
  float x[4] = { g1.x * xa.x + g2.x * xt.x, g1.y * xa.y + g2.y * xt.y,
                 g1.z * xa.z + g2.z * xt.z, g1.w * xa.w + g2.w * xt.w };
  float s = x[0] + x[1] + x[2] + x[3];
  s = wave_sum(s);
  float mean = s * (1.f / 256.f);
  float sq = 0.f;
#pragma unroll
  for (int i = 0; i < 4; i++){ float d = x[i] - mean; sq += d * d; }
  float var = wave_sum(sq) * (1.f / 256.f);
  float rstd = rsqrtf(var + 1e-5f);
  float4 gg = *(const float4*)(g + lane * 4);
  float4 bb = *(const float4*)(be + lane * 4);
  float4 o;
  o.x = (x[0] - mean) * rstd * gg.x + bb.x;
  o.y = (x[1] - mean) * rstd * gg.y + bb.y;
  o.z = (x[2] - mean) * rstd * gg.z + bb.z;
  o.w = (x[3] - mean) * rstd * gg.w + bb.w;
  *(float4*)(out + (size_t)r * 256 + lane * 4) = o;
}

// ---------------- deformable sampling (fused aw softmax + bilinear gather) ----------------
__global__ __launch_bounds__(256) void deform_k(const __hip_bfloat16* __restrict__ val,
                                                const float* __restrict__ off,
                                                const float* __restrict__ awr,
                                                const float* __restrict__ ref,
                                                float* __restrict__ out){
  int t = blockIdx.x;
  int e = threadIdx.x;   // 0..31
  int h = threadIdx.y;   // 0..7
  int b = t / LQ, q = t % LQ;
  float aw[16];
  const float* ap = awr + (size_t)t * 128 + h * 16;
  float mx = -1e30f;
#pragma unroll
  for (int i = 0; i < 16; i++){ aw[i] = ap[i]; mx = fmaxf(mx, aw[i]); }
  float sum = 0.f;
#pragma unroll
  for (int i = 0; i < 16; i++){ aw[i] = expf(aw[i] - mx); sum += aw[i]; }
  float inv = 1.f / sum;
  const int starts[4] = {0, 25600, 32000, 33600};
  const int HS[4]     = {160, 80, 40, 20};
  const float* op = off + (size_t)t * 256 + h * 32;
  const __hip_bfloat16* vb = val + (size_t)b * LEN_VV * 256 + h * 32 + e;
  float acc = 0.f;
#pragma unroll
  for (int l = 0; l < 4; l++){
    int w = HS[l];
    float rx = ref[((size_t)(b * LQ + q) * 4 + l) * 2 + 0];
    float ry = ref[((size_t)(b * LQ + q) * 4 + l) * 2 + 1];
#pragma unroll
    for (int p = 0; p < 4; p++){
      float px = rx * w + op[l * 8 + p * 2 + 0] - 0.5f;
      float py = ry * w + op[l * 8 + p * 2 + 1] - 0.5f;
      float x0f = floorf(px), y0f = floorf(py);
      float lx = px - x0f, ly = py - y0f;
      int x0 = (int)x0f, y0 = (int)y0f;
      float wgt = aw[l * 4 + p] * inv;
      float sample = 0.f;
#pragma unroll
      for (int c = 0; c < 4; c++){
        int dx = c & 1, dy = c >> 1;
        int xi = x0 + dx, yi = y0 + dy;
        if (xi >= 0 && xi < w && yi >= 0 && yi < w){
          float cw = (dx ? lx : 1.f - lx) * (dy ? ly : 1.f - ly);
          int idx = starts[l] + yi * w + xi;
          sample += cw * __bfloat162float(vb[(size_t)idx * 256]);
        }
      }
      acc += wgt * sample;
    }
  }
  out[(size_t)t * 256 + h * 32 + e] = acc;
}

extern "C" void kernel_launch(void* const* d_in, const int* in_sizes, int n_in,
                              void* d_out, int out_size, void* d_ws, size_t ws_size,
                              hipStream_t stream){
  const float* tgt_pose = (const float*)d_in[0];
  const float* qpos     = (const float*)d_in[1];
  const float* refp     = (const float*)d_in[2];
  const float* memory   = (const float*)d_in[3];
  const float* win_Wqkv = (const float*)d_in[4];
  const float* win_bqkv = (const float*)d_in[5];
  const float* win_Wo   = (const float*)d_in[6];
  const float* win_bo   = (const float*)d_in[7];
  const float* win_ng   = (const float*)d_in[8];
  const float* win_nb   = (const float*)d_in[9];
  const float* acr_Wqkv = (const float*)d_in[10];
  const float* acr_bqkv = (const float*)d_in[11];
  const float* acr_Wo   = (const float*)d_in[12];
  const float* acr_bo   = (const float*)d_in[13];
  const float* acr_ng   = (const float*)d_in[14];
  const float* acr_nb   = (const float*)d_in[15];
  const float* off_W    = (const float*)d_in[16];
  const float* off_b    = (const float*)d_in[17];
  const float* aw_W     = (const float*)d_in[18];
  const float* aw_b     = (const float*)d_in[19];
  const float* val_W    = (const float*)d_in[20];
  const float* val_b    = (const float*)d_in[21];
  const float* outp_W   = (const float*)d_in[22];
  const float* outp_b   = (const float*)d_in[23];
  const float* gate_W   = (const float*)d_in[24];
  const float* gate_b   = (const float*)d_in[25];
  const float* gate_ng  = (const float*)d_in[26];
  const float* gate_nb  = (const float*)d_in[27];
  const float* ffn_W1   = (const float*)d_in[28];
  const float* ffn_b1   = (const float*)d_in[29];
  const float* ffn_W2   = (const float*)d_in[30];
  const float* ffn_b2   = (const float*)d_in[31];
  const float* n2_g     = (const float*)d_in[32];
  const float* n2_b     = (const float*)d_in[33];

  float* out = (float*)d_out;
  char* ws = (char*)d_ws;
  const size_t TB = (size_t)T_TOK * 256 * 4;
  float* B0 = (float*)(ws);
  float* B1 = (float*)(ws + TB);
  float* B2 = (float*)(ws + 2 * TB);
  float* B3 = (float*)(ws + 3 * TB);
  float* Q  = (float*)(ws + 4 * TB);                       // T*768 floats (reused as gate out T*512)
  float* AW = (float*)(ws + 4 * TB + (size_t)T_TOK * 768 * 4);
  char*  Vb = ws + 4 * TB + (size_t)T_TOK * 768 * 4 + (size_t)T_TOK * 128 * 4;
  __hip_bfloat16* V = (__hip_bfloat16*)Vb;                 // B*LEN_V*256 bf16 (139 MB)
  float* CAT = (float*)Vb;                                 // overlay (V dead by then)
  float* FF  = (float*)(Vb + (size_t)T_TOK * 512 * 4);     // overlay

  const int n4 = T_TOK * 64;                               // float4 count for T*256
  const int GM = (T_TOK + 63) / 64;                        // 213

  // 1. tgt0 = tgt_pose + pos
  add_k<<<(n4 + 255) / 256, 256, 0, stream>>>(tgt_pose, qpos, B0, n4);
  // 2. within qkv
  gemm_k<0,0><<<dim3(GM, 12), 256, 0, stream>>>(B0, win_Wqkv, win_bqkv, Q, nullptr, T_TOK, 768, 256);
  // 3. within attention (800 batches of S=17)
  mha_k<<<800 * 8, 256, (3 * 17 * 33 + 512) * 4, stream>>>(Q, B1, 17);
  // 4. out proj
  gemm_k<0,0><<<dim3(GM, 4), 256, 0, stream>>>(B1, win_Wo, win_bo, B2, nullptr, T_TOK, 256, 256);
  // 5. LN -> tgt1
  ln_k<0><<<T_TOK, 64, 0, stream>>>(B0, B2, win_ng, win_nb, B1);
  // 6. transpose to (b,k,q,d)
  transpose_k<<<(n4 + 255) / 256, 256, 0, stream>>>(B1, B0);
  // 7. across qkv
  gemm_k<0,0><<<dim3(GM, 12), 256, 0, stream>>>(B0, acr_Wqkv, acr_bqkv, Q, nullptr, T_TOK, 768, 256);
  // 8. across attention (136 batches of S=100)
  mha_k<<<136 * 8, 256, (3 * 100 * 33 + 512) * 4, stream>>>(Q, B2, 100);
  // 9. out proj
  gemm_k<0,0><<<dim3(GM, 4), 256, 0, stream>>>(B2, acr_Wo, acr_bo, B3, nullptr, T_TOK, 256, 256);
  // 10. LN + write back un-transposed -> tgt2
  ln_k<1><<<T_TOK, 64, 0, stream>>>(B0, B3, acr_ng, acr_nb, B1);
  // 11. tgt_q = tgt2 + pos
  add_k<<<(n4 + 255) / 256, 256, 0, stream>>>(B1, qpos, B0, n4);
  // 12. value projection (big GEMM, bf16 out)
  gemm_k<0,1><<<dim3(4250, 4), 256, 0, stream>>>(memory, val_W, val_b, nullptr, V, BS_ * LEN_VV, 256, 256);
  // 13. offsets
  gemm_k<0,0><<<dim3(GM, 4), 256, 0, stream>>>(B0, off_W, off_b, B1, nullptr, T_TOK, 256, 256);
  // 14. attention-weight logits
  gemm_k<0,0><<<dim3(GM, 2), 256, 0, stream>>>(B0, aw_W, aw_b, AW, nullptr, T_TOK, 128, 256);
  // 15. deformable sampling
  deform_k<<<T_TOK, dim3(32, 8), 0, stream>>>(V, B1, AW, refp, B2);
  // 16. output proj of deformable attn
  gemm_k<0,0><<<dim3(GM, 4), 256, 0, stream>>>(B2, outp_W, outp_b, B3, nullptr, T_TOK, 256, 256);
  // 17. concat [tgt_q | t2]
  concat_k<<<(T_TOK * 128 + 255) / 256, 256, 0, stream>>>(B0, B3, CAT);
  // 18. gate GEMM (sigmoid epilogue), out into Q region (T*512)
  gemm_k<2,0><<<dim3(GM, 8), 256, 0, stream>>>(CAT, gate_W, gate_b, Q, nullptr, T_TOK, 512, 512);
  // 19. gate combine + LN -> tgt3
  gate_ln_k<<<T_TOK, 64, 0, stream>>>(Q, B0, B3, gate_ng, gate_nb, B1);
  // 20. FFN up (relu)
  gemm_k<1,0><<<dim3(GM, 16), 256, 0, stream>>>(B1, ffn_W1, ffn_b1, FF, nullptr, T_TOK, 1024, 256);
  // 21. FFN down
  gemm_k<0,0><<<dim3(GM, 4), 256, 0, stream>>>(FF, ffn_W2, ffn_b2, B2, nullptr, T_TOK, 256, 1024);
  // 22. final residual + clip + LN -> out
  ln_k<2><<<T_TOK, 64, 0, stream>>>(B1, B2, n2_g, n2_b, out);
}

// Round 2
// 1022.053 us; speedup vs baseline: 1.6225x; 1.6225x over previous
//
#include <hip/hip_runtime.h>
#include <hip/hip_bf16.h>

#define NH 8
#define BS_ 8
#define NQ_ 100
#define NK_ 17
#define LQ 1700            // NQ_*NK_
#define T_TOK 13600        // BS_*LQ
#define LEN_VV 34000

typedef __attribute__((ext_vector_type(8))) short short8v;
typedef __attribute__((ext_vector_type(8))) __bf16 bf16x8;
typedef __attribute__((ext_vector_type(4))) float f32x4;

__device__ __forceinline__ float wave_sum(float v){
#pragma unroll
  for (int m = 32; m; m >>= 1) v += __shfl_xor(v, m, 64);
  return v;
}
__device__ __forceinline__ float wave_max(float v){
#pragma unroll
  for (int m = 32; m; m >>= 1) v = fmaxf(v, __shfl_xor(v, m, 64));
  return v;
}
__device__ __forceinline__ short f2bf(float f){
  __hip_bfloat16 h = __float2bfloat16(f);
  return *reinterpret_cast<short*>(&h);
}

// ---------------- elementwise add (float4) ----------------
__global__ __launch_bounds__(256) void add_k(const float* __restrict__ a,
                                             const float* __restrict__ b,
                                             float* __restrict__ o, int n4){
  int i = blockIdx.x * 256 + threadIdx.x;
  if (i >= n4) return;
  float4 x = ((const float4*)a)[i];
  float4 y = ((const float4*)b)[i];
  float4 r; r.x = x.x + y.x; r.y = x.y + y.y; r.z = x.z + y.z; r.w = x.w + y.w;
  ((float4*)o)[i] = r;
}

// ---------------- transpose (b,q,k,d) -> (b,k,q,d) ----------------
__global__ __launch_bounds__(256) void transpose_k(const float* __restrict__ in,
                                                   float* __restrict__ outp){
  int i = blockIdx.x * 256 + threadIdx.x;
  if (i >= T_TOK * 64) return;
  int orow = i >> 6, c = i & 63;
  int b = orow / LQ, rem = orow % LQ;
  int kk = rem / NQ_, q = rem % NQ_;
  int irow = b * LQ + q * NK_ + kk;
  ((float4*)outp)[(size_t)orow * 64 + c] = ((const float4*)in)[(size_t)irow * 64 + c];
}

// ---------------- concat [a|b] rows 256+256 -> 512 ----------------
__global__ __launch_bounds__(256) void concat_k(const float* __restrict__ a,
                                                const float* __restrict__ b,
                                                float* __restrict__ o){
  int i = blockIdx.x * 256 + threadIdx.x;
  if (i >= T_TOK * 128) return;
  int row = i >> 7, c = i & 127;
  float4 v = (c < 64) ? ((const float4*)a)[(size_t)row * 64 + c]
                      : ((const float4*)b)[(size_t)row * 64 + (c - 64)];
  ((float4*)o)[(size_t)row * 128 + c] = v;
}

// ---------------- MFMA GEMM: C[M,N] = A[M,K] @ W[N,K]^T + bias ----------------
// fp32 in, bf16 MFMA, fp32 accum. Tile 128x128, BK=64, 4 waves (2x2), wave=64x64.
// EPI: 0 none, 1 relu, 2 sigmoid.  OUTB: 1 -> bf16 output
template<int EPI, int OUTB>
__global__ __launch_bounds__(256) void mgemm_k(const float* __restrict__ A,
                                               const float* __restrict__ W,
                                               const float* __restrict__ bias,
                                               float* __restrict__ Cf,
                                               __hip_bfloat16* __restrict__ Cb,
                                               int M, int N, int K){
  __shared__ short As[128 * 64];
  __shared__ short Ws[128 * 64];
  const int tid = threadIdx.x;
  const int bm = blockIdx.y * 128, bn = blockIdx.x * 128;
  const int wave = tid >> 6, lane = tid & 63;
  const int wm = (wave >> 1) * 64, wn = (wave & 1) * 64;
  const int s = tid & 7;            // 16B slot within row (staging)
  const int row0 = tid >> 3;        // staging row base (0..31), +32 per iter
  f32x4 acc[4][4] = {};
  const int lrow = lane & 15, lk = lane >> 4;

  for (int k0 = 0; k0 < K; k0 += 64){
#pragma unroll
    for (int i = 0; i < 4; i++){
      int row = row0 + i * 32;
      int sw = ((s ^ (row & 7)) << 3) + row * 64;
      // A tile
      {
        int gr = bm + row;
        float4 a0 = make_float4(0.f,0.f,0.f,0.f), a1 = a0;
        if (gr < M){
          const float* p = A + (size_t)gr * K + k0 + s * 8;
          a0 = *(const float4*)p; a1 = *(const float4*)(p + 4);
        }
        short8v v;
        v[0]=f2bf(a0.x); v[1]=f2bf(a0.y); v[2]=f2bf(a0.z); v[3]=f2bf(a0.w);
        v[4]=f2bf(a1.x); v[5]=f2bf(a1.y); v[6]=f2bf(a1.z); v[7]=f2bf(a1.w);
        *(short8v*)&As[sw] = v;
      }
      // W tile (N divisible by 128)
      {
        const float* p = W + (size_t)(bn + row) * K + k0 + s * 8;
        float4 a0 = *(const float4*)p, a1 = *(const float4*)(p + 4);
        short8v v;
        v[0]=f2bf(a0.x); v[1]=f2bf(a0.y); v[2]=f2bf(a0.z); v[3]=f2bf(a0.w);
        v[4]=f2bf(a1.x); v[5]=f2bf(a1.y); v[6]=f2bf(a1.z); v[7]=f2bf(a1.w);
        *(short8v*)&Ws[sw] = v;
      }
    }
    __syncthreads();
#pragma unroll
    for (int ks = 0; ks < 2; ks++){
      short8v af[4], bw[4];
      int slot = ks * 4 + lk;
#pragma unroll
      for (int m = 0; m < 4; m++){
        int r = wm + m * 16 + lrow;
        af[m] = *(const short8v*)&As[r * 64 + ((slot ^ (r & 7)) << 3)];
      }
#pragma unroll
      for (int n = 0; n < 4; n++){
        int r = wn + n * 16 + lrow;
        bw[n] = *(const short8v*)&Ws[r * 64 + ((slot ^ (r & 7)) << 3)];
      }
#pragma unroll
      for (int m = 0; m < 4; m++)
#pragma unroll
        for (int n = 0; n < 4; n++)
          acc[m][n] = __builtin_amdgcn_mfma_f32_16x16x32_bf16(
              __builtin_bit_cast(bf16x8, af[m]),
              __builtin_bit_cast(bf16x8, bw[n]), acc[m][n], 0, 0, 0);
    }
    __syncthreads();
  }
  // epilogue: C/D layout col = lane&15, row = (lane>>4)*4 + i
#pragma unroll
  for (int n = 0; n < 4; n++){
    int col = bn + wn + n * 16 + lrow;
    float bsv = bias[col];
#pragma unroll
    for (int m = 0; m < 4; m++){
#pragma unroll
      for (int i = 0; i < 4; i++){
        int row = bm + wm + m * 16 + lk * 4 + i;
        if (row >= M) continue;
        float c = acc[m][n][i] + bsv;
        if (EPI == 1) c = fmaxf(c, 0.f);
        if (EPI == 2) c = 1.f / (1.f + expf(-c));
        if (OUTB) Cb[(size_t)row * N + col] = __float2bfloat16(c);
        else      Cf[(size_t)row * N + col] = c;
      }
    }
  }
}

// ---------------- MHA core: one block per (batch, head) ----------------
__global__ __launch_bounds__(256) void mha_k(const float* __restrict__ qkv,
                                             float* __restrict__ out, int S){
  extern __shared__ float sm[];
  const int SP = 33;
  float* qs = sm;
  float* ks = qs + S * SP;
  float* vs = ks + S * SP;
  float* ps = vs + S * SP;   // [4][128]
  int bh = blockIdx.x;
  int batch = bh >> 3, h = bh & 7;
  int tid = threadIdx.x;
  size_t base = (size_t)batch * S * 768 + h * 32;
  for (int idx = tid; idx < S * 32; idx += 256){
    int s = idx >> 5, e = idx & 31;
    size_t g = base + (size_t)s * 768 + e;
    qs[s * SP + e] = qkv[g];
    ks[s * SP + e] = qkv[g + 256];
    vs[s * SP + e] = qkv[g + 512];
  }
  __syncthreads();
  int wave = tid >> 6, lane = tid & 63;
  const float scale = 0.17677669529663687f; // 1/sqrt(32)
  for (int r = wave; r < S; r += 4){
    int j1 = lane, j2 = lane + 64;
    float d1 = -1e30f, d2 = -1e30f;
    if (j1 < S){
      float t = 0.f;
#pragma unroll
      for (int e = 0; e < 32; e++) t += qs[r * SP + e] * ks[j1 * SP + e];
      d1 = t * scale;
    }
    if (j2 < S){
      float t = 0.f;
#pragma unroll
      for (int e = 0; e < 32; e++) t += qs[r * SP + e] * ks[j2 * SP + e];
      d2 = t * scale;
    }
    float mx = wave_max(fmaxf(d1, d2));
    float e1 = (j1 < S) ? expf(d1 - mx) : 0.f;
    float e2 = (j2 < S) ? expf(d2 - mx) : 0.f;
    float sum = wave_sum(e1 + e2);
    float inv = 1.f / sum;
    if (j1 < S) ps[wave * 128 + j1] = e1 * inv;
    if (j2 < S) ps[wave * 128 + j2] = e2 * inv;
    int e = lane & 31, half = lane >> 5;
    float acc = 0.f;
    for (int j = half; j < S; j += 2) acc += ps[wave * 128 + j] * vs[j * SP + e];
    acc += __shfl_xor(acc, 32, 64);
    if (lane < 32) out[((size_t)batch * S + r) * 256 + h * 32 + e] = acc;
  }
}

// ---------------- LayerNorm over 256; MODE 0 plain, 1 permuted-write, 2 clip ----------------
template<int MODE>
__global__ __launch_bounds__(64) void ln_k(const float* __restrict__ a,
                                           const float* __restrict__ b,
                                           const float* __restrict__ g,
                                           const float* __restrict__ be,
                                           float* __restrict__ out){
  int r = blockIdx.x;
  int lane = threadIdx.x;
  float4 xa = *(const float4*)(a + (size_t)r * 256 + lane * 4);
  float4 xb = *(const float4*)(b + (size_t)r * 256 + lane * 4);
  float x[4] = { xa.x + xb.x, xa.y + xb.y, xa.z + xb.z, xa.w + xb.w };
  if (MODE == 2){
#pragma unroll
    for (int i = 0; i < 4; i++) x[i] = fminf(fmaxf(x[i], -65504.f), 65504.f);
  }
  float s = x[0] + x[1] + x[2] + x[3];
  s = wave_sum(s);
  float mean = s * (1.f / 256.f);
  float sq = 0.f;
#pragma unroll
  for (int i = 0; i < 4; i++){ float d = x[i] - mean; sq += d * d; }
  float var = wave_sum(sq) * (1.f / 256.f);
  float rstd = rsqrtf(var + 1e-5f);
  float4 gg = *(const float4*)(g + lane * 4);
  float4 bb = *(const float4*)(be + lane * 4);
  size_t orow = r;
  if (MODE == 1){
    int bi = r / LQ; int rem = r % LQ; int kk = rem / NQ_; int q = rem % NQ_;
    orow = (size_t)bi * LQ + q * NK_ + kk;
  }
  float4 o;
  o.x = (x[0] - mean) * rstd * gg.x + bb.x;
  o.y = (x[1] - mean) * rstd * gg.y + bb.y;
  o.z = (x[2] - mean) * rstd * gg.z + bb.z;
  o.w = (x[3] - mean) * rstd * gg.w + bb.w;
  *(float4*)(out + orow * 256 + lane * 4) = o;
}

// ---------------- gate combine + LN ----------------
__global__ __launch_bounds__(64) void gate_ln_k(const float* __restrict__ G,
                                                const float* __restrict__ aq,
                                                const float* __restrict__ t2,
                                                const float* __restrict__ g,
                                                const float* __restrict__ be,
                                                float* __restrict__ out){
  int r = blockIdx.x;
  int lane = threadIdx.x;
  float4 g1 = *(const float4*)(G + (size_t)r * 512 + lane * 4);
  float4 g2 = *(const float4*)(G + (size_t)r * 512 + 256 + lane * 4);
  float4 xa = *(const float4*)(aq + (size_t)r * 256 + lane * 4);
  float4 xt = *(const float4*)(t2 + (size_t)r * 256 + lane * 4);
  float x[4] = { g1.x * xa.x + g2.x * xt.x, g1.y * xa.y + g2.y * xt.y,
                 g1.z * xa.z + g2.z * xt.z, g1.w * xa.w + g2.w * xt.w };
  float s = x[0] + x[1] + x[2] + x[3];
  s = wave_sum(s);
  float mean = s * (1.f / 256.f);
  float sq = 0.f;
#pragma unroll
  for (int i = 0; i < 4; i++){ float d = x[i] - mean; sq += d * d; }
  float var = wave_sum(sq) * (1.f / 256.f);
  float rstd = rsqrtf(var + 1e-5f);
  float4 gg = *(const float4*)(g + lane * 4);
  float4 bb = *(const float4*)(be + lane * 4);
  float4 o;
  o.x = (x[0] - mean) * rstd * gg.x + bb.x;
  o.y = (x[1] - mean) * rstd * gg.y + bb.y;
  o.z = (x[2] - mean) * rstd * gg.z + bb.z;
  o.w = (x[3] - mean) * rstd * gg.w + bb.w;
  *(float4*)(out + (size_t)r * 256 + lane * 4) = o;
}

// ---------------- deformable sampling (fused aw softmax + bilinear gather) ----------------
__global__ __launch_bounds__(256) void deform_k(const __hip_bfloat16* __restrict__ val,
                                                const float* __restrict__ off,
                                                const float* __restrict__ awr,
                                                const float* __restrict__ ref,
                                                float* __restrict__ out){
  int t = blockIdx.x;
  int e = threadIdx.x;   // 0..31
  int h = threadIdx.y;   // 0..7
  int b = t / LQ, q = t % LQ;
  float aw[16];
  const float* ap = awr + (size_t)t * 128 + h * 16;
  float mx = -1e30f;
#pragma unroll
  for (int i = 0; i < 16; i++){ aw[i] = ap[i]; mx = fmaxf(mx, aw[i]); }
  float sum = 0.f;
#pragma unroll
  for (int i = 0; i < 16; i++){ aw[i] = expf(aw[i] - mx); sum += aw[i]; }
  float inv = 1.f / sum;
  const int starts[4] = {0, 25600, 32000, 33600};
  const int HS[4]     = {160, 80, 40, 20};
  const float* op = off + (size_t)t * 256 + h * 32;
  const __hip_bfloat16* vb = val + (size_t)b * LEN_VV * 256 + h * 32 + e;
  float acc = 0.f;
#pragma unroll
  for (int l = 0; l < 4; l++){
    int w = HS[l];
    float rx = ref[((size_t)(b * LQ + q) * 4 + l) * 2 + 0];
    float ry = ref[((size_t)(b * LQ + q) * 4 + l) * 2 + 1];
#pragma unroll
    for (int p = 0; p < 4; p++){
      float px = rx * w + op[l * 8 + p * 2 + 0] - 0.5f;
      float py = ry * w + op[l * 8 + p * 2 + 1] - 0.5f;
      float x0f = floorf(px), y0f = floorf(py);
      float lx = px - x0f, ly = py - y0f;
      int x0 = (int)x0f, y0 = (int)y0f;
      float wgt = aw[l * 4 + p] * inv;
      float sample = 0.f;
#pragma unroll
      for (int c = 0; c < 4; c++){
        int dx = c & 1, dy = c >> 1;
        int xi = x0 + dx, yi = y0 + dy;
        if (xi >= 0 && xi < w && yi >= 0 && yi < w){
          float cw = (dx ? lx : 1.f - lx) * (dy ? ly : 1.f - ly);
          int idx = starts[l] + yi * w + xi;
          sample += cw * __bfloat162float(vb[(size_t)idx * 256]);
        }
      }
      acc += wgt * sample;
    }
  }
  out[(size_t)t * 256 + h * 32 + e] = acc;
}

extern "C" void kernel_launch(void* const* d_in, const int* in_sizes, int n_in,
                              void* d_out, int out_size, void* d_ws, size_t ws_size,
                              hipStream_t stream){
  const float* tgt_pose = (const float*)d_in[0];
  const float* qpos     = (const float*)d_in[1];
  const float* refp     = (const float*)d_in[2];
  const float* memory   = (const float*)d_in[3];
  const float* win_Wqkv = (const float*)d_in[4];
  const float* win_bqkv = (const float*)d_in[5];
  const float* win_Wo   = (const float*)d_in[6];
  const float* win_bo   = (const float*)d_in[7];
  const float* win_ng   = (const float*)d_in[8];
  const float* win_nb   = (const float*)d_in[9];
  const float* acr_Wqkv = (const float*)d_in[10];
  const float* acr_bqkv = (const float*)d_in[11];
  const float* acr_Wo   = (const float*)d_in[12];
  const float* acr_bo   = (const float*)d_in[13];
  const float* acr_ng   = (const float*)d_in[14];
  const float* acr_nb   = (const float*)d_in[15];
  const float* off_W    = (const float*)d_in[16];
  const float* off_b    = (const float*)d_in[17];
  const float* aw_W     = (const float*)d_in[18];
  const float* aw_b     = (const float*)d_in[19];
  const float* val_W    = (const float*)d_in[20];
  const float* val_b    = (const float*)d_in[21];
  const float* outp_W   = (const float*)d_in[22];
  const float* outp_b   = (const float*)d_in[23];
  const float* gate_W   = (const float*)d_in[24];
  const float* gate_b   = (const float*)d_in[25];
  const float* gate_ng  = (const float*)d_in[26];
  const float* gate_nb  = (const float*)d_in[27];
  const float* ffn_W1   = (const float*)d_in[28];
  const float* ffn_b1   = (const float*)d_in[29];
  const float* ffn_W2   = (const float*)d_in[30];
  const float* ffn_b2   = (const float*)d_in[31];
  const float* n2_g     = (const float*)d_in[32];
  const float* n2_b     = (const float*)d_in[33];

  float* out = (float*)d_out;
  char* ws = (char*)d_ws;
  const size_t TB = (size_t)T_TOK * 256 * 4;
  float* B0 = (float*)(ws);
  float* B1 = (float*)(ws + TB);
  float* B2 = (float*)(ws + 2 * TB);
  float* B3 = (float*)(ws + 3 * TB);
  float* Q  = (float*)(ws + 4 * TB);                       // T*768 floats (reused as gate out T*512)
  float* AW = (float*)(ws + 4 * TB + (size_t)T_TOK * 768 * 4);
  char*  Vb = ws + 4 * TB + (size_t)T_TOK * 768 * 4 + (size_t)T_TOK * 128 * 4;
  __hip_bfloat16* V = (__hip_bfloat16*)Vb;                 // B*LEN_V*256 bf16 (139 MB)
  float* CAT = (float*)Vb;                                 // overlay (V dead by then)
  float* FF  = (float*)(Vb + (size_t)T_TOK * 512 * 4);     // overlay

  const int n4 = T_TOK * 64;                               // float4 count for T*256
  const int GM = (T_TOK + 127) / 128;                      // 107 M-blocks

  // 1. tgt0 = tgt_pose + pos
  add_k<<<(n4 + 255) / 256, 256, 0, stream>>>(tgt_pose, qpos, B0, n4);
  // 2. within qkv
  mgemm_k<0,0><<<dim3(6, GM), 256, 0, stream>>>(B0, win_Wqkv, win_bqkv, Q, nullptr, T_TOK, 768, 256);
  // 3. within attention (800 batches of S=17)
  mha_k<<<800 * 8, 256, (3 * 17 * 33 + 512) * 4, stream>>>(Q, B1, 17);
  // 4. out proj
  mgemm_k<0,0><<<dim3(2, GM), 256, 0, stream>>>(B1, win_Wo, win_bo, B2, nullptr, T_TOK, 256, 256);
  // 5. LN -> tgt1
  ln_k<0><<<T_TOK, 64, 0, stream>>>(B0, B2, win_ng, win_nb, B1);
  // 6. transpose to (b,k,q,d)
  transpose_k<<<(n4 + 255) / 256, 256, 0, stream>>>(B1, B0);
  // 7. across qkv
  mgemm_k<0,0><<<dim3(6, GM), 256, 0, stream>>>(B0, acr_Wqkv, acr_bqkv, Q, nullptr, T_TOK, 768, 256);
  // 8. across attention (136 batches of S=100)
  mha_k<<<136 * 8, 256, (3 * 100 * 33 + 512) * 4, stream>>>(Q, B2, 100);
  // 9. out proj
  mgemm_k<0,0><<<dim3(2, GM), 256, 0, stream>>>(B2, acr_Wo, acr_bo, B3, nullptr, T_TOK, 256, 256);
  // 10. LN + write back un-transposed -> tgt2
  ln_k<1><<<T_TOK, 64, 0, stream>>>(B0, B3, acr_ng, acr_nb, B1);
  // 11. tgt_q = tgt2 + pos
  add_k<<<(n4 + 255) / 256, 256, 0, stream>>>(B1, qpos, B0, n4);
  // 12. value projection (big GEMM, bf16 out)
  mgemm_k<0,1><<<dim3(2, 2125), 256, 0, stream>>>(memory, val_W, val_b, nullptr, V, BS_ * LEN_VV, 256, 256);
  // 13. offsets
  mgemm_k<0,0><<<dim3(2, GM), 256, 0, stream>>>(B0, off_W, off_b, B1, nullptr, T_TOK, 256, 256);
  // 14. attention-weight logits
  mgemm_k<0,0><<<dim3(1, GM), 256, 0, stream>>>(B0, aw_W, aw_b, AW, nullptr, T_TOK, 128, 256);
  // 15. deformable sampling
  deform_k<<<T_TOK, dim3(32, 8), 0, stream>>>(V, B1, AW, refp, B2);
  // 16. output proj of deformable attn
  mgemm_k<0,0><<<dim3(2, GM), 256, 0, stream>>>(B2, outp_W, outp_b, B3, nullptr, T_TOK, 256, 256);
  // 17. concat [tgt_q | t2]
  concat_k<<<(T_TOK * 128 + 255) / 256, 256, 0, stream>>>(B0, B3, CAT);
  // 18. gate GEMM (sigmoid epilogue), out into Q region (T*512)
  mgemm_k<2,0><<<dim3(4, GM), 256, 0, stream>>>(CAT, gate_W, gate_b, Q, nullptr, T_TOK, 512, 512);
  // 19. gate combine + LN -> tgt3
  gate_ln_k<<<T_TOK, 64, 0, stream>>>(Q, B0, B3, gate_ng, gate_nb, B1);
  // 20. FFN up (relu)
  mgemm_k<1,0><<<dim3(8, GM), 256, 0, stream>>>(B1, ffn_W1, ffn_b1, FF, nullptr, T_TOK, 1024, 256);
  // 21. FFN down
  mgemm_k<0,0><<<dim3(2, GM), 256, 0, stream>>>(FF, ffn_W2, ffn_b2, B2, nullptr, T_TOK, 256, 1024);
  // 22. final residual + clip + LN -> out
  ln_k<2><<<T_TOK, 64, 0, stream>>>(B1, B2, n2_g, n2_b, out);
}

// Round 3
// 874.115 us; speedup vs baseline: 1.8971x; 1.1692x over previous
//
#include <hip/hip_runtime.h>
#include <hip/hip_bf16.h>

#define NH 8
#define BS_ 8
#define NQ_ 100
#define NK_ 17
#define LQ 1700            // NQ_*NK_
#define T_TOK 13600        // BS_*LQ
#define LEN_VV 34000

typedef __attribute__((ext_vector_type(8))) short short8v;
typedef __attribute__((ext_vector_type(8))) __bf16 bf16x8;
typedef __attribute__((ext_vector_type(4))) float f32x4;

__device__ __forceinline__ float wave_sum(float v){
#pragma unroll
  for (int m = 32; m; m >>= 1) v += __shfl_xor(v, m, 64);
  return v;
}
__device__ __forceinline__ float wave_max(float v){
#pragma unroll
  for (int m = 32; m; m >>= 1) v = fmaxf(v, __shfl_xor(v, m, 64));
  return v;
}
__device__ __forceinline__ short f2bf(float f){
  __hip_bfloat16 h = __float2bfloat16(f);
  return *reinterpret_cast<short*>(&h);
}

// ---------------- elementwise add (float4) ----------------
__global__ __launch_bounds__(256) void add_k(const float* __restrict__ a,
                                             const float* __restrict__ b,
                                             float* __restrict__ o, int n4){
  int i = blockIdx.x * 256 + threadIdx.x;
  if (i >= n4) return;
  float4 x = ((const float4*)a)[i];
  float4 y = ((const float4*)b)[i];
  float4 r; r.x = x.x + y.x; r.y = x.y + y.y; r.z = x.z + y.z; r.w = x.w + y.w;
  ((float4*)o)[i] = r;
}

// ---------------- transpose (b,q,k,d) -> (b,k,q,d) ----------------
__global__ __launch_bounds__(256) void transpose_k(const float* __restrict__ in,
                                                   float* __restrict__ outp){
  int i = blockIdx.x * 256 + threadIdx.x;
  if (i >= T_TOK * 64) return;
  int orow = i >> 6, c = i & 63;
  int b = orow / LQ, rem = orow % LQ;
  int kk = rem / NQ_, q = rem % NQ_;
  int irow = b * LQ + q * NK_ + kk;
  ((float4*)outp)[(size_t)orow * 64 + c] = ((const float4*)in)[(size_t)irow * 64 + c];
}

// ---------------- concat [a|b] rows 256+256 -> 512 ----------------
__global__ __launch_bounds__(256) void concat_k(const float* __restrict__ a,
                                                const float* __restrict__ b,
                                                float* __restrict__ o){
  int i = blockIdx.x * 256 + threadIdx.x;
  if (i >= T_TOK * 128) return;
  int row = i >> 7, c = i & 127;
  float4 v = (c < 64) ? ((const float4*)a)[(size_t)row * 64 + c]
                      : ((const float4*)b)[(size_t)row * 64 + (c - 64)];
  ((float4*)o)[(size_t)row * 128 + c] = v;
}

// ---------------- MFMA GEMM: C[M,N] = A[M,K] @ W[N,K]^T + bias ----------------
// fp32 in, bf16 MFMA, fp32 accum. Tile 128x128, BK=64, 4 waves (2x2), wave=64x64.
// EPI: 0 none, 1 relu, 2 sigmoid.  OUTB: 1 -> bf16 output
template<int EPI, int OUTB>
__global__ __launch_bounds__(256) void mgemm_k(const float* __restrict__ A,
                                               const float* __restrict__ W,
                                               const float* __restrict__ bias,
                                               float* __restrict__ Cf,
                                               __hip_bfloat16* __restrict__ Cb,
                                               int M, int N, int K){
  __shared__ short As[128 * 64];
  __shared__ short Ws[128 * 64];
  const int tid = threadIdx.x;
  const int bm = blockIdx.y * 128, bn = blockIdx.x * 128;
  const int wave = tid >> 6, lane = tid & 63;
  const int wm = (wave >> 1) * 64, wn = (wave & 1) * 64;
  const int s = tid & 7;            // 16B slot within row (staging)
  const int row0 = tid >> 3;        // staging row base (0..31), +32 per iter
  f32x4 acc[4][4] = {};
  const int lrow = lane & 15, lk = lane >> 4;

  for (int k0 = 0; k0 < K; k0 += 64){
#pragma unroll
    for (int i = 0; i < 4; i++){
      int row = row0 + i * 32;
      int sw = ((s ^ (row & 7)) << 3) + row * 64;
      // A tile
      {
        int gr = bm + row;
        float4 a0 = make_float4(0.f,0.f,0.f,0.f), a1 = a0;
        if (gr < M){
          const float* p = A + (size_t)gr * K + k0 + s * 8;
          a0 = *(const float4*)p; a1 = *(const float4*)(p + 4);
        }
        short8v v;
        v[0]=f2bf(a0.x); v[1]=f2bf(a0.y); v[2]=f2bf(a0.z); v[3]=f2bf(a0.w);
        v[4]=f2bf(a1.x); v[5]=f2bf(a1.y); v[6]=f2bf(a1.z); v[7]=f2bf(a1.w);
        *(short8v*)&As[sw] = v;
      }
      // W tile (N divisible by 128)
      {
        const float* p = W + (size_t)(bn + row) * K + k0 + s * 8;
        float4 a0 = *(const float4*)p, a1 = *(const float4*)(p + 4);
        short8v v;
        v[0]=f2bf(a0.x); v[1]=f2bf(a0.y); v[2]=f2bf(a0.z); v[3]=f2bf(a0.w);
        v[4]=f2bf(a1.x); v[5]=f2bf(a1.y); v[6]=f2bf(a1.z); v[7]=f2bf(a1.w);
        *(short8v*)&Ws[sw] = v;
      }
    }
    __syncthreads();
#pragma unroll
    for (int ks = 0; ks < 2; ks++){
      short8v af[4], bw[4];
      int slot = ks * 4 + lk;
#pragma unroll
      for (int m = 0; m < 4; m++){
        int r = wm + m * 16 + lrow;
        af[m] = *(const short8v*)&As[r * 64 + ((slot ^ (r & 7)) << 3)];
      }
#pragma unroll
      for (int n = 0; n < 4; n++){
        int r = wn + n * 16 + lrow;
        bw[n] = *(const short8v*)&Ws[r * 64 + ((slot ^ (r & 7)) << 3)];
      }
#pragma unroll
      for (int m = 0; m < 4; m++)
#pragma unroll
        for (int n = 0; n < 4; n++)
          acc[m][n] = __builtin_amdgcn_mfma_f32_16x16x32_bf16(
              __builtin_bit_cast(bf16x8, af[m]),
              __builtin_bit_cast(bf16x8, bw[n]), acc[m][n], 0, 0, 0);
    }
    __syncthreads();
  }
  // epilogue: C/D layout col = lane&15, row = (lane>>4)*4 + i
#pragma unroll
  for (int n = 0; n < 4; n++){
    int col = bn + wn + n * 16 + lrow;
    float bsv = bias[col];
#pragma unroll
    for (int m = 0; m < 4; m++){
#pragma unroll
      for (int i = 0; i < 4; i++){
        int row = bm + wm + m * 16 + lk * 4 + i;
        if (row >= M) continue;
        float c = acc[m][n][i] + bsv;
        if (EPI == 1) c = fmaxf(c, 0.f);
        if (EPI == 2) c = 1.f / (1.f + expf(-c));
        if (OUTB) Cb[(size_t)row * N + col] = __float2bfloat16(c);
        else      Cf[(size_t)row * N + col] = c;
      }
    }
  }
}

// ---------------- MHA core: one block per (batch, head) ----------------
__global__ __launch_bounds__(256) void mha_k(const float* __restrict__ qkv,
                                             float* __restrict__ out, int S){
  extern __shared__ float sm[];
  const int SP = 33;
  float* qs = sm;
  float* ks = qs + S * SP;
  float* vs = ks + S * SP;
  float* ps = vs + S * SP;   // [4][128]
  int bh = blockIdx.x;
  int batch = bh >> 3, h = bh & 7;
  int tid = threadIdx.x;
  size_t base = (size_t)batch * S * 768 + h * 32;
  for (int idx = tid; idx < S * 32; idx += 256){
    int s = idx >> 5, e = idx & 31;
    size_t g = base + (size_t)s * 768 + e;
    qs[s * SP + e] = qkv[g];
    ks[s * SP + e] = qkv[g + 256];
    vs[s * SP + e] = qkv[g + 512];
  }
  __syncthreads();
  int wave = tid >> 6, lane = tid & 63;
  const float scale = 0.17677669529663687f; // 1/sqrt(32)
  for (int r = wave; r < S; r += 4){
    int j1 = lane, j2 = lane + 64;
    float d1 = -1e30f, d2 = -1e30f;
    if (j1 < S){
      float t = 0.f;
#pragma unroll
      for (int e = 0; e < 32; e++) t += qs[r * SP + e] * ks[j1 * SP + e];
      d1 = t * scale;
    }
    if (j2 < S){
      float t = 0.f;
#pragma unroll
      for (int e = 0; e < 32; e++) t += qs[r * SP + e] * ks[j2 * SP + e];
      d2 = t * scale;
    }
    float mx = wave_max(fmaxf(d1, d2));
    float e1 = (j1 < S) ? expf(d1 - mx) : 0.f;
    float e2 = (j2 < S) ? expf(d2 - mx) : 0.f;
    float sum = wave_sum(e1 + e2);
    float inv = 1.f / sum;
    if (j1 < S) ps[wave * 128 + j1] = e1 * inv;
    if (j2 < S) ps[wave * 128 + j2] = e2 * inv;
    int e = lane & 31, half = lane >> 5;
    float acc = 0.f;
    for (int j = half; j < S; j += 2) acc += ps[wave * 128 + j] * vs[j * SP + e];
    acc += __shfl_xor(acc, 32, 64);
    if (lane < 32) out[((size_t)batch * S + r) * 256 + h * 32 + e] = acc;
  }
}

// ---------------- LayerNorm over 256; MODE 0 plain, 1 permuted-write, 2 clip ----------------
template<int MODE>
__global__ __launch_bounds__(64) void ln_k(const float* __restrict__ a,
                                           const float* __restrict__ b,
                                           const float* __restrict__ g,
                                           const float* __restrict__ be,
                                           float* __restrict__ out){
  int r = blockIdx.x;
  int lane = threadIdx.x;
  float4 xa = *(const float4*)(a + (size_t)r * 256 + lane * 4);
  float4 xb = *(const float4*)(b + (size_t)r * 256 + lane * 4);
  float x[4] = { xa.x + xb.x, xa.y + xb.y, xa.z + xb.z, xa.w + xb.w };
  if (MODE == 2){
#pragma unroll
    for (int i = 0; i < 4; i++) x[i] = fminf(fmaxf(x[i], -65504.f), 65504.f);
  }
  float s = x[0] + x[1] + x[2] + x[3];
  s = wave_sum(s);
  float mean = s * (1.f / 256.f);
  float sq = 0.f;
#pragma unroll
  for (int i = 0; i < 4; i++){ float d = x[i] - mean; sq += d * d; }
  float var = wave_sum(sq) * (1.f / 256.f);
  float rstd = rsqrtf(var + 1e-5f);
  float4 gg = *(const float4*)(g + lane * 4);
  float4 bb = *(const float4*)(be + lane * 4);
  size_t orow = r;
  if (MODE == 1){
    int bi = r / LQ; int rem = r % LQ; int kk = rem / NQ_; int q = rem % NQ_;
    orow = (size_t)bi * LQ + q * NK_ + kk;
  }
  float4 o;
  o.x = (x[0] - mean) * rstd * gg.x + bb.x;
  o.y = (x[1] - mean) * rstd * gg.y + bb.y;
  o.z = (x[2] - mean) * rstd * gg.z + bb.z;
  o.w = (x[3] - mean) * rstd * gg.w + bb.w;
  *(float4*)(out + orow * 256 + lane * 4) = o;
}

// ---------------- gate combine + LN ----------------
__global__ __launch_bounds__(64) void gate_ln_k(const float* __restrict__ G,
                                                const float* __restrict__ aq,
                                                const float* __restrict__ t2,
                                                const float* __restrict__ g,
                                                const float* __restrict__ be,
                                                float* __restrict__ out){
  int r = blockIdx.x;
  int lane = threadIdx.x;
  float4 g1 = *(const float4*)(G + (size_t)r * 512 + lane * 4);
  float4 g2 = *(const float4*)(G + (size_t)r * 512 + 256 + lane * 4);
  float4 xa = *(const float4*)(aq + (size_t)r * 256 + lane * 4);
  float4 xt = *(const float4*)(t2 + (size_t)r * 256 + lane * 4);
  float x[4] = { g1.x * xa.x + g2.x * xt.x, g1.y * xa.y + g2.y * xt.y,
                 g1.z * xa.z + g2.z * xt.z, g1.w * xa.w + g2.w * xt.w };
  float s = x[0] + x[1] + x[2] + x[3];
  s = wave_sum(s);
  float mean = s * (1.f / 256.f);
  float sq = 0.f;
#pragma unroll
  for (int i = 0; i < 4; i++){ float d = x[i] - mean; sq += d * d; }
  float var = wave_sum(sq) * (1.f / 256.f);
  float rstd = rsqrtf(var + 1e-5f);
  float4 gg = *(const float4*)(g + lane * 4);
  float4 bb = *(const float4*)(be + lane * 4);
  float4 o;
  o.x = (x[0] - mean) * rstd * gg.x + bb.x;
  o.y = (x[1] - mean) * rstd * gg.y + bb.y;
  o.z = (x[2] - mean) * rstd * gg.z + bb.z;
  o.w = (x[3] - mean) * rstd * gg.w + bb.w;
  *(float4*)(out + (size_t)r * 256 + lane * 4) = o;
}

// ---------------- deformable sampling, two-phase ----------------
// Block: 256 threads, 4 tokens. Phase 1 computes (idx, weight) metadata for
// 32 (t,h) groups x 16 points x 4 corners into LDS. Phase 2: 16-lane
// subgroups gather bf16x2 pairs and accumulate.
__global__ __launch_bounds__(256) void deform_k(const __hip_bfloat16* __restrict__ val,
                                                const float* __restrict__ off,
                                                const float* __restrict__ awr,
                                                const float* __restrict__ ref,
                                                float* __restrict__ out){
  __shared__ uint2 meta[32][16][4];   // (pair-index, weight-bits), 16 KB
  const int tid = threadIdx.x;
  const int t0 = blockIdx.x * 4;
  // ---- phase 1: metadata ----
  {
    int g = tid >> 3;           // group 0..31 = (lt, h)
    int pair = tid & 7;         // 2 points
    int lt = g >> 3, h = g & 7;
    int t = t0 + lt;
    int b = t / LQ;
    int p0 = pair * 2;
    int l = p0 >> 2;            // level (both points same level)
    const int starts[4] = {0, 25600, 32000, 33600};
    const int HS[4] = {160, 80, 40, 20};
    int w = HS[l];
    float a0 = awr[(size_t)t * 128 + h * 16 + p0];
    float a1 = awr[(size_t)t * 128 + h * 16 + p0 + 1];
    float mx = fmaxf(a0, a1);
#pragma unroll
    for (int m = 1; m <= 4; m <<= 1) mx = fmaxf(mx, __shfl_xor(mx, m, 64));
    float e0 = expf(a0 - mx), e1 = expf(a1 - mx);
    float s = e0 + e1;
#pragma unroll
    for (int m = 1; m <= 4; m <<= 1) s += __shfl_xor(s, m, 64);
    float inv = 1.f / s;
    float rx = ref[((size_t)t * 4 + l) * 2 + 0];
    float ry = ref[((size_t)t * 4 + l) * 2 + 1];
    float4 ov = *(const float4*)(off + (size_t)t * 256 + h * 32 + l * 8 + p0 * 2);
    int vbase = (b * LEN_VV + starts[l]) * 128 + h * 16;
#pragma unroll
    for (int pp = 0; pp < 2; pp++){
      float wgt = (pp ? e1 : e0) * inv;
      float px = rx * w + (pp ? ov.z : ov.x) - 0.5f;
      float py = ry * w + (pp ? ov.w : ov.y) - 0.5f;
      float x0f = floorf(px), y0f = floorf(py);
      float lx = px - x0f, ly = py - y0f;
      int x0 = (int)x0f, y0 = (int)y0f;
#pragma unroll
      for (int c = 0; c < 4; c++){
        int dx = c & 1, dy = c >> 1;
        int xi = x0 + dx, yi = y0 + dy;
        bool ok = (xi >= 0) & (xi < w) & (yi >= 0) & (yi < w);
        float cw = ok ? wgt * (dx ? lx : 1.f - lx) * (dy ? ly : 1.f - ly) : 0.f;
        uint idx = ok ? (uint)(vbase + (yi * w + xi) * 128) : 0u;
        uint2 m2; m2.x = idx; m2.y = __float_as_uint(cw);
        meta[g][p0 + pp][c] = m2;
      }
    }
  }
  __syncthreads();
  // ---- phase 2: gather-accumulate ----
  const uint* V2 = (const uint*)val;
  int sg = tid >> 4, lane = tid & 15;
#pragma unroll
  for (int it = 0; it < 2; it++){
    int g = it * 16 + sg;
    int lt = g >> 3, h = g & 7;
    int t = t0 + lt;
    float ax = 0.f, ay = 0.f;
#pragma unroll 4
    for (int c = 0; c < 64; c++){
      uint2 mw = meta[g][c >> 2][c & 3];
      float wv = __uint_as_float(mw.y);
      uint v = V2[(size_t)mw.x + lane];
      float lo = __uint_as_float(v << 16);
      float hi = __uint_as_float(v & 0xffff0000u);
      ax += wv * lo;
      ay += wv * hi;
    }
    float2 r; r.x = ax; r.y = ay;
    *(float2*)(out + (size_t)t * 256 + h * 32 + lane * 2) = r;
  }
}

extern "C" void kernel_launch(void* const* d_in, const int* in_sizes, int n_in,
                              void* d_out, int out_size, void* d_ws, size_t ws_size,
                              hipStream_t stream){
  const float* tgt_pose = (const float*)d_in[0];
  const float* qpos     = (const float*)d_in[1];
  const float* refp     = (const float*)d_in[2];
  const float* memory   = (const float*)d_in[3];
  const float* win_Wqkv = (const float*)d_in[4];
  const float* win_bqkv = (const float*)d_in[5];
  const float* win_Wo   = (const float*)d_in[6];
  const float* win_bo   = (const float*)d_in[7];
  const float* win_ng   = (const float*)d_in[8];
  const float* win_nb   = (const float*)d_in[9];
  const float* acr_Wqkv = (const float*)d_in[10];
  const float* acr_bqkv = (const float*)d_in[11];
  const float* acr_Wo   = (const float*)d_in[12];
  const float* acr_bo   = (const float*)d_in[13];
  const float* acr_ng   = (const float*)d_in[14];
  const float* acr_nb   = (const float*)d_in[15];
  const float* off_W    = (const float*)d_in[16];
  const float* off_b    = (const float*)d_in[17];
  const float* aw_W     = (const float*)d_in[18];
  const float* aw_b     = (const float*)d_in[19];
  const float* val_W    = (const float*)d_in[20];
  const float* val_b    = (const float*)d_in[21];
  const float* outp_W   = (const float*)d_in[22];
  const float* outp_b   = (const float*)d_in[23];
  const float* gate_W   = (const float*)d_in[24];
  const float* gate_b   = (const float*)d_in[25];
  const float* gate_ng  = (const float*)d_in[26];
  const float* gate_nb  = (const float*)d_in[27];
  const float* ffn_W1   = (const float*)d_in[28];
  const float* ffn_b1   = (const float*)d_in[29];
  const float* ffn_W2   = (const float*)d_in[30];
  const float* ffn_b2   = (const float*)d_in[31];
  const float* n2_g     = (const float*)d_in[32];
  const float* n2_b     = (const float*)d_in[33];

  float* out = (float*)d_out;
  char* ws = (char*)d_ws;
  const size_t TB = (size_t)T_TOK * 256 * 4;
  float* B0 = (float*)(ws);
  float* B1 = (float*)(ws + TB);
  float* B2 = (float*)(ws + 2 * TB);
  float* B3 = (float*)(ws + 3 * TB);
  float* Q  = (float*)(ws + 4 * TB);                       // T*768 floats (reused as gate out T*512)
  float* AW = (float*)(ws + 4 * TB + (size_t)T_TOK * 768 * 4);
  char*  Vb = ws + 4 * TB + (size_t)T_TOK * 768 * 4 + (size_t)T_TOK * 128 * 4;
  __hip_bfloat16* V = (__hip_bfloat16*)Vb;                 // B*LEN_V*256 bf16 (139 MB)
  float* CAT = (float*)Vb;                                 // overlay (V dead by then)
  float* FF  = (float*)(Vb + (size_t)T_TOK * 512 * 4);     // overlay

  const int n4 = T_TOK * 64;                               // float4 count for T*256
  const int GM = (T_TOK + 127) / 128;                      // 107 M-blocks

  // 1. tgt0 = tgt_pose + pos
  add_k<<<(n4 + 255) / 256, 256, 0, stream>>>(tgt_pose, qpos, B0, n4);
  // 2. within qkv
  mgemm_k<0,0><<<dim3(6, GM), 256, 0, stream>>>(B0, win_Wqkv, win_bqkv, Q, nullptr, T_TOK, 768, 256);
  // 3. within attention (800 batches of S=17)
  mha_k<<<800 * 8, 256, (3 * 17 * 33 + 512) * 4, stream>>>(Q, B1, 17);
  // 4. out proj
  mgemm_k<0,0><<<dim3(2, GM), 256, 0, stream>>>(B1, win_Wo, win_bo, B2, nullptr, T_TOK, 256, 256);
  // 5. LN -> tgt1
  ln_k<0><<<T_TOK, 64, 0, stream>>>(B0, B2, win_ng, win_nb, B1);
  // 6. transpose to (b,k,q,d)
  transpose_k<<<(n4 + 255) / 256, 256, 0, stream>>>(B1, B0);
  // 7. across qkv
  mgemm_k<0,0><<<dim3(6, GM), 256, 0, stream>>>(B0, acr_Wqkv, acr_bqkv, Q, nullptr, T_TOK, 768, 256);
  // 8. across attention (136 batches of S=100)
  mha_k<<<136 * 8, 256, (3 * 100 * 33 + 512) * 4, stream>>>(Q, B2, 100);
  // 9. out proj
  mgemm_k<0,0><<<dim3(2, GM), 256, 0, stream>>>(B2, acr_Wo, acr_bo, B3, nullptr, T_TOK, 256, 256);
  // 10. LN + write back un-transposed -> tgt2
  ln_k<1><<<T_TOK, 64, 0, stream>>>(B0, B3, acr_ng, acr_nb, B1);
  // 11. tgt_q = tgt2 + pos
  add_k<<<(n4 + 255) / 256, 256, 0, stream>>>(B1, qpos, B0, n4);
  // 12. value projection (big GEMM, bf16 out)
  mgemm_k<0,1><<<dim3(2, 2125), 256, 0, stream>>>(memory, val_W, val_b, nullptr, V, BS_ * LEN_VV, 256, 256);
  // 13. offsets
  mgemm_k<0,0><<<dim3(2, GM), 256, 0, stream>>>(B0, off_W, off_b, B1, nullptr, T_TOK, 256, 256);
  // 14. attention-weight logits
  mgemm_k<0,0><<<dim3(1, GM), 256, 0, stream>>>(B0, aw_W, aw_b, AW, nullptr, T_TOK, 128, 256);
  // 15. deformable sampling (two-phase)
  deform_k<<<T_TOK / 4, 256, 0, stream>>>(V, B1, AW, refp, B2);
  // 16. output proj of deformable attn
  mgemm_k<0,0><<<dim3(2, GM), 256, 0, stream>>>(B2, outp_W, outp_b, B3, nullptr, T_TOK, 256, 256);
  // 17. concat [tgt_q | t2]
  concat_k<<<(T_TOK * 128 + 255) / 256, 256, 0, stream>>>(B0, B3, CAT);
  // 18. gate GEMM (sigmoid epilogue), out into Q region (T*512)
  mgemm_k<2,0><<<dim3(4, GM), 256, 0, stream>>>(CAT, gate_W, gate_b, Q, nullptr, T_TOK, 512, 512);
  // 19. gate combine + LN -> tgt3
  gate_ln_k<<<T_TOK, 64, 0, stream>>>(Q, B0, B3, gate_ng, gate_nb, B1);
  // 20. FFN up (relu)
  mgemm_k<1,0><<<dim3(8, GM), 256, 0, stream>>>(B1, ffn_W1, ffn_b1, FF, nullptr, T_TOK, 1024, 256);
  // 21. FFN down
  mgemm_k<0,0><<<dim3(2, GM), 256, 0, stream>>>(FF, ffn_W2, ffn_b2, B2, nullptr, T_TOK, 256, 1024);
  // 22. final residual + clip + LN -> out
  ln_k<2><<<T_TOK, 64, 0, stream>>>(B1, B2, n2_g, n2_b, out);
}

// Round 4
// 744.529 us; speedup vs baseline: 2.2273x; 1.1741x over previous
//
#include <hip/hip_runtime.h>
#include <hip/hip_bf16.h>

#define NH 8
#define BS_ 8
#define NQ_ 100
#define NK_ 17
#define LQ 1700            // NQ_*NK_
#define T_TOK 13600        // BS_*LQ
#define LEN_VV 34000

typedef __attribute__((ext_vector_type(8))) short short8v;
typedef __attribute__((ext_vector_type(8))) __bf16 bf16x8;
typedef __attribute__((ext_vector_type(4))) float f32x4;

__device__ __forceinline__ float wave_sum(float v){
#pragma unroll
  for (int m = 32; m; m >>= 1) v += __shfl_xor(v, m, 64);
  return v;
}
__device__ __forceinline__ float wave_max(float v){
#pragma unroll
  for (int m = 32; m; m >>= 1) v = fmaxf(v, __shfl_xor(v, m, 64));
  return v;
}
__device__ __forceinline__ short f2bf(float f){
  __hip_bfloat16 h = __float2bfloat16(f);
  return *reinterpret_cast<short*>(&h);
}

// ---------------- elementwise add (float4) ----------------
__global__ __launch_bounds__(256) void add_k(const float* __restrict__ a,
                                             const float* __restrict__ b,
                                             float* __restrict__ o, int n4){
  int i = blockIdx.x * 256 + threadIdx.x;
  if (i >= n4) return;
  float4 x = ((const float4*)a)[i];
  float4 y = ((const float4*)b)[i];
  float4 r; r.x = x.x + y.x; r.y = x.y + y.y; r.z = x.z + y.z; r.w = x.w + y.w;
  ((float4*)o)[i] = r;
}

// ---------------- transpose (b,q,k,d) -> (b,k,q,d) ----------------
__global__ __launch_bounds__(256) void transpose_k(const float* __restrict__ in,
                                                   float* __restrict__ outp){
  int i = blockIdx.x * 256 + threadIdx.x;
  if (i >= T_TOK * 64) return;
  int orow = i >> 6, c = i & 63;
  int b = orow / LQ, rem = orow % LQ;
  int kk = rem / NQ_, q = rem % NQ_;
  int irow = b * LQ + q * NK_ + kk;
  ((float4*)outp)[(size_t)orow * 64 + c] = ((const float4*)in)[(size_t)irow * 64 + c];
}

// ---------------- concat [a|b] rows 256+256 -> 512 ----------------
__global__ __launch_bounds__(256) void concat_k(const float* __restrict__ a,
                                                const float* __restrict__ b,
                                                float* __restrict__ o){
  int i = blockIdx.x * 256 + threadIdx.x;
  if (i >= T_TOK * 128) return;
  int row = i >> 7, c = i & 127;
  float4 v = (c < 64) ? ((const float4*)a)[(size_t)row * 64 + c]
                      : ((const float4*)b)[(size_t)row * 64 + (c - 64)];
  ((float4*)o)[(size_t)row * 128 + c] = v;
}

// ---------------- MFMA GEMM: C[M,N] = A[M,K] @ W[N,K]^T + bias ----------------
// fp32 in, bf16 MFMA, fp32 accum. Tile 128x128, BK=64, 4 waves (2x2), wave=64x64.
// Register-prefetch pipelined staging; bf16 output via LDS-staged coalesced epilogue.
// EPI: 0 none, 1 relu, 2 sigmoid.  OUTB: 1 -> bf16 output
template<int EPI, int OUTB>
__global__ __launch_bounds__(256) void mgemm_k(const float* __restrict__ A,
                                               const float* __restrict__ W,
                                               const float* __restrict__ bias,
                                               float* __restrict__ Cf,
                                               __hip_bfloat16* __restrict__ Cb,
                                               int M, int N, int K){
  __shared__ short sh[OUTB ? 128 * 136 : 128 * 128];
  short* As = sh;
  short* Ws = sh + 128 * 64;
  const int tid = threadIdx.x;
  const int bm = blockIdx.y * 128, bn = blockIdx.x * 128;
  const int wave = tid >> 6, lane = tid & 63;
  const int wm = (wave >> 1) * 64, wn = (wave & 1) * 64;
  const int s = tid & 7;            // 16B slot within row (staging)
  const int row0 = tid >> 3;        // staging row base (0..31), +32 per iter
  f32x4 acc[4][4] = {};
  const int lrow = lane & 15, lk = lane >> 4;

  float4 ra[8], rw[8];
  // prefetch K-step 0
#pragma unroll
  for (int i = 0; i < 4; i++){
    int row = row0 + i * 32;
    int gr = bm + row;
    float4 z = make_float4(0.f, 0.f, 0.f, 0.f);
    if (gr < M){
      const float* p = A + (size_t)gr * K + s * 8;
      ra[2 * i] = ((const float4*)p)[0]; ra[2 * i + 1] = ((const float4*)p)[1];
    } else { ra[2 * i] = z; ra[2 * i + 1] = z; }
    const float* q = W + (size_t)(bn + row) * K + s * 8;
    rw[2 * i] = ((const float4*)q)[0]; rw[2 * i + 1] = ((const float4*)q)[1];
  }

  for (int k0 = 0; k0 < K; k0 += 64){
    // stage regs -> LDS (bf16)
#pragma unroll
    for (int i = 0; i < 4; i++){
      int row = row0 + i * 32;
      int sw = ((s ^ (row & 7)) << 3) + row * 64;
      float4 a0 = ra[2 * i], a1 = ra[2 * i + 1];
      short8v v;
      v[0]=f2bf(a0.x); v[1]=f2bf(a0.y); v[2]=f2bf(a0.z); v[3]=f2bf(a0.w);
      v[4]=f2bf(a1.x); v[5]=f2bf(a1.y); v[6]=f2bf(a1.z); v[7]=f2bf(a1.w);
      *(short8v*)&As[sw] = v;
      a0 = rw[2 * i]; a1 = rw[2 * i + 1];
      short8v u;
      u[0]=f2bf(a0.x); u[1]=f2bf(a0.y); u[2]=f2bf(a0.z); u[3]=f2bf(a0.w);
      u[4]=f2bf(a1.x); u[5]=f2bf(a1.y); u[6]=f2bf(a1.z); u[7]=f2bf(a1.w);
      *(short8v*)&Ws[sw] = u;
    }
    __syncthreads();
    // prefetch next K-step while MFMAs run
    if (k0 + 64 < K){
#pragma unroll
      for (int i = 0; i < 4; i++){
        int row = row0 + i * 32;
        int gr = bm + row;
        float4 z = make_float4(0.f, 0.f, 0.f, 0.f);
        if (gr < M){
          const float* p = A + (size_t)gr * K + k0 + 64 + s * 8;
          ra[2 * i] = ((const float4*)p)[0]; ra[2 * i + 1] = ((const float4*)p)[1];
        } else { ra[2 * i] = z; ra[2 * i + 1] = z; }
        const float* q = W + (size_t)(bn + row) * K + k0 + 64 + s * 8;
        rw[2 * i] = ((const float4*)q)[0]; rw[2 * i + 1] = ((const float4*)q)[1];
      }
    }
#pragma unroll
    for (int ks = 0; ks < 2; ks++){
      short8v af[4], bw[4];
      int slot = ks * 4 + lk;
#pragma unroll
      for (int m = 0; m < 4; m++){
        int r = wm + m * 16 + lrow;
        af[m] = *(const short8v*)&As[r * 64 + ((slot ^ (r & 7)) << 3)];
      }
#pragma unroll
      for (int n = 0; n < 4; n++){
        int r = wn + n * 16 + lrow;
        bw[n] = *(const short8v*)&Ws[r * 64 + ((slot ^ (r & 7)) << 3)];
      }
#pragma unroll
      for (int m = 0; m < 4; m++)
#pragma unroll
        for (int n = 0; n < 4; n++)
          acc[m][n] = __builtin_amdgcn_mfma_f32_16x16x32_bf16(
              __builtin_bit_cast(bf16x8, af[m]),
              __builtin_bit_cast(bf16x8, bw[n]), acc[m][n], 0, 0, 0);
    }
    __syncthreads();
  }

  if (OUTB){
    // stage C tile in LDS (row stride 136 shorts = 272 B, 16B-aligned rows)
    const int STR = 136;
#pragma unroll
    for (int n = 0; n < 4; n++){
      int col = wn + n * 16 + lrow;
      float bsv = bias[bn + col];
#pragma unroll
      for (int m = 0; m < 4; m++){
#pragma unroll
        for (int i = 0; i < 4; i++){
          int row = wm + m * 16 + lk * 4 + i;
          float c = acc[m][n][i] + bsv;
          if (EPI == 1) c = fmaxf(c, 0.f);
          if (EPI == 2) c = 1.f / (1.f + expf(-c));
          sh[row * STR + col] = f2bf(c);
        }
      }
    }
    __syncthreads();
    // coalesced writeback: 16 lanes cover 256 B of one row
#pragma unroll
    for (int it = 0; it < 8; it++){
      int r = it * 16 + (tid >> 4);
      int chunk = tid & 15;
      if (bm + r < M){
        uint4 v = *(const uint4*)((const char*)sh + r * 272 + chunk * 16);
        *(uint4*)((char*)Cb + ((size_t)(bm + r) * N + bn) * 2 + chunk * 16) = v;
      }
    }
  } else {
    // fp32 epilogue: 16-lane groups write 64 B contiguous (full lines)
#pragma unroll
    for (int n = 0; n < 4; n++){
      int col = bn + wn + n * 16 + lrow;
      float bsv = bias[col];
#pragma unroll
      for (int m = 0; m < 4; m++){
#pragma unroll
        for (int i = 0; i < 4; i++){
          int row = bm + wm + m * 16 + lk * 4 + i;
          if (row >= M) continue;
          float c = acc[m][n][i] + bsv;
          if (EPI == 1) c = fmaxf(c, 0.f);
          if (EPI == 2) c = 1.f / (1.f + expf(-c));
          Cf[(size_t)row * N + col] = c;
        }
      }
    }
  }
}

// ---------------- MHA core: one block per (batch, head) ----------------
__global__ __launch_bounds__(256) void mha_k(const float* __restrict__ qkv,
                                             float* __restrict__ out, int S){
  extern __shared__ float sm[];
  const int SP = 33;
  float* qs = sm;
  float* ks = qs + S * SP;
  float* vs = ks + S * SP;
  float* ps = vs + S * SP;   // [4][128]
  int bh = blockIdx.x;
  int batch = bh >> 3, h = bh & 7;
  int tid = threadIdx.x;
  size_t base = (size_t)batch * S * 768 + h * 32;
  for (int idx = tid; idx < S * 32; idx += 256){
    int s = idx >> 5, e = idx & 31;
    size_t g = base + (size_t)s * 768 + e;
    qs[s * SP + e] = qkv[g];
    ks[s * SP + e] = qkv[g + 256];
    vs[s * SP + e] = qkv[g + 512];
  }
  __syncthreads();
  int wave = tid >> 6, lane = tid & 63;
  const float scale = 0.17677669529663687f; // 1/sqrt(32)
  for (int r = wave; r < S; r += 4){
    int j1 = lane, j2 = lane + 64;
    float d1 = -1e30f, d2 = -1e30f;
    if (j1 < S){
      float t = 0.f;
#pragma unroll
      for (int e = 0; e < 32; e++) t += qs[r * SP + e] * ks[j1 * SP + e];
      d1 = t * scale;
    }
    if (j2 < S){
      float t = 0.f;
#pragma unroll
      for (int e = 0; e < 32; e++) t += qs[r * SP + e] * ks[j2 * SP + e];
      d2 = t * scale;
    }
    float mx = wave_max(fmaxf(d1, d2));
    float e1 = (j1 < S) ? expf(d1 - mx) : 0.f;
    float e2 = (j2 < S) ? expf(d2 - mx) : 0.f;
    float sum = wave_sum(e1 + e2);
    float inv = 1.f / sum;
    if (j1 < S) ps[wave * 128 + j1] = e1 * inv;
    if (j2 < S) ps[wave * 128 + j2] = e2 * inv;
    int e = lane & 31, half = lane >> 5;
    float acc = 0.f;
    for (int j = half; j < S; j += 2) acc += ps[wave * 128 + j] * vs[j * SP + e];
    acc += __shfl_xor(acc, 32, 64);
    if (lane < 32) out[((size_t)batch * S + r) * 256 + h * 32 + e] = acc;
  }
}

// ---------------- LayerNorm over 256; MODE 0 plain, 1 permuted-write, 2 clip ----------------
template<int MODE>
__global__ __launch_bounds__(64) void ln_k(const float* __restrict__ a,
                                           const float* __restrict__ b,
                                           const float* __restrict__ g,
                                           const float* __restrict__ be,
                                           float* __restrict__ out){
  int r = blockIdx.x;
  int lane = threadIdx.x;
  float4 xa = *(const float4*)(a + (size_t)r * 256 + lane * 4);
  float4 xb = *(const float4*)(b + (size_t)r * 256 + lane * 4);
  float x[4] = { xa.x + xb.x, xa.y + xb.y, xa.z + xb.z, xa.w + xb.w };
  if (MODE == 2){
#pragma unroll
    for (int i = 0; i < 4; i++) x[i] = fminf(fmaxf(x[i], -65504.f), 65504.f);
  }
  float s = x[0] + x[1] + x[2] + x[3];
  s = wave_sum(s);
  float mean = s * (1.f / 256.f);
  float sq = 0.f;
#pragma unroll
  for (int i = 0; i < 4; i++){ float d = x[i] - mean; sq += d * d; }
  float var = wave_sum(sq) * (1.f / 256.f);
  float rstd = rsqrtf(var + 1e-5f);
  float4 gg = *(const float4*)(g + lane * 4);
  float4 bb = *(const float4*)(be + lane * 4);
  size_t orow = r;
  if (MODE == 1){
    int bi = r / LQ; int rem = r % LQ; int kk = rem / NQ_; int q = rem % NQ_;
    orow = (size_t)bi * LQ + q * NK_ + kk;
  }
  float4 o;
  o.x = (x[0] - mean) * rstd * gg.x + bb.x;
  o.y = (x[1] - mean) * rstd * gg.y + bb.y;
  o.z = (x[2] - mean) * rstd * gg.z + bb.z;
  o.w = (x[3] - mean) * rstd * gg.w + bb.w;
  *(float4*)(out + orow * 256 + lane * 4) = o;
}

// ---------------- gate combine + LN ----------------
__global__ __launch_bounds__(64) void gate_ln_k(const float* __restrict__ G,
                                                const float* __restrict__ aq,
                                                const float* __restrict__ t2,
                                                const float* __restrict__ g,
                                                const float* __restrict__ be,
                                                float* __restrict__ out){
  int r = blockIdx.x;
  int lane = threadIdx.x;
  float4 g1 = *(const float4*)(G + (size_t)r * 512 + lane * 4);
  float4 g2 = *(const float4*)(G + (size_t)r * 512 + 256 + lane * 4);
  float4 xa = *(const float4*)(aq + (size_t)r * 256 + lane * 4);
  float4 xt = *(const float4*)(t2 + (size_t)r * 256 + lane * 4);
  float x[4] = { g1.x * xa.x + g2.x * xt.x, g1.y * xa.y + g2.y * xt.y,
                 g1.z * xa.z + g2.z * xt.z, g1.w * xa.w + g2.w * xt.w };
  float s = x[0] + x[1] + x[2] + x[3];
  s = wave_sum(s);
  float mean = s * (1.f / 256.f);
  float sq = 0.f;
#pragma unroll
  for (int i = 0; i < 4; i++){ float d = x[i] - mean; sq += d * d; }
  float var = wave_sum(sq) * (1.f / 256.f);
  float rstd = rsqrtf(var + 1e-5f);
  float4 gg = *(const float4*)(g + lane * 4);
  float4 bb = *(const float4*)(be + lane * 4);
  float4 o;
  o.x = (x[0] - mean) * rstd * gg.x + bb.x;
  o.y = (x[1] - mean) * rstd * gg.y + bb.y;
  o.z = (x[2] - mean) * rstd * gg.z + bb.z;
  o.w = (x[3] - mean) * rstd * gg.w + bb.w;
  *(float4*)(out + (size_t)r * 256 + lane * 4) = o;
}

// ---------------- deformable sampling, two-phase ----------------
__global__ __launch_bounds__(256) void deform_k(const __hip_bfloat16* __restrict__ val,
                                                const float* __restrict__ off,
                                                const float* __restrict__ awr,
                                                const float* __restrict__ ref,
                                                float* __restrict__ out){
  __shared__ uint2 meta[32][16][4];   // (pair-index, weight-bits), 16 KB
  const int tid = threadIdx.x;
  const int t0 = blockIdx.x * 4;
  // ---- phase 1: metadata ----
  {
    int g = tid >> 3;           // group 0..31 = (lt, h)
    int pair = tid & 7;         // 2 points
    int lt = g >> 3, h = g & 7;
    int t = t0 + lt;
    int b = t / LQ;
    int p0 = pair * 2;
    int l = p0 >> 2;            // level (both points same level)
    const int starts[4] = {0, 25600, 32000, 33600};
    const int HS[4] = {160, 80, 40, 20};
    int w = HS[l];
    float a0 = awr[(size_t)t * 128 + h * 16 + p0];
    float a1 = awr[(size_t)t * 128 + h * 16 + p0 + 1];
    float mx = fmaxf(a0, a1);
#pragma unroll
    for (int m = 1; m <= 4; m <<= 1) mx = fmaxf(mx, __shfl_xor(mx, m, 64));
    float e0 = expf(a0 - mx), e1 = expf(a1 - mx);
    float s = e0 + e1;
#pragma unroll
    for (int m = 1; m <= 4; m <<= 1) s += __shfl_xor(s, m, 64);
    float inv = 1.f / s;
    float rx = ref[((size_t)t * 4 + l) * 2 + 0];
    float ry = ref[((size_t)t * 4 + l) * 2 + 1];
    float4 ov = *(const float4*)(off + (size_t)t * 256 + h * 32 + l * 8 + p0 * 2);
    int vbase = (b * LEN_VV + starts[l]) * 128 + h * 16;
#pragma unroll
    for (int pp = 0; pp < 2; pp++){
      float wgt = (pp ? e1 : e0) * inv;
      float px = rx * w + (pp ? ov.z : ov.x) - 0.5f;
      float py = ry * w + (pp ? ov.w : ov.y) - 0.5f;
      float x0f = floorf(px), y0f = floorf(py);
      float lx = px - x0f, ly = py - y0f;
      int x0 = (int)x0f, y0 = (int)y0f;
#pragma unroll
      for (int c = 0; c < 4; c++){
        int dx = c & 1, dy = c >> 1;
        int xi = x0 + dx, yi = y0 + dy;
        bool ok = (xi >= 0) & (xi < w) & (yi >= 0) & (yi < w);
        float cw = ok ? wgt * (dx ? lx : 1.f - lx) * (dy ? ly : 1.f - ly) : 0.f;
        uint idx = ok ? (uint)(vbase + (yi * w + xi) * 128) : 0u;
        uint2 m2; m2.x = idx; m2.y = __float_as_uint(cw);
        meta[g][p0 + pp][c] = m2;
      }
    }
  }
  __syncthreads();
  // ---- phase 2: gather-accumulate ----
  const uint* V2 = (const uint*)val;
  int sg = tid >> 4, lane = tid & 15;
#pragma unroll
  for (int it = 0; it < 2; it++){
    int g = it * 16 + sg;
    int lt = g >> 3, h = g & 7;
    int t = t0 + lt;
    float ax = 0.f, ay = 0.f;
#pragma unroll 4
    for (int c = 0; c < 64; c++){
      uint2 mw = meta[g][c >> 2][c & 3];
      float wv = __uint_as_float(mw.y);
      uint v = V2[(size_t)mw.x + lane];
      float lo = __uint_as_float(v << 16);
      float hi = __uint_as_float(v & 0xffff0000u);
      ax += wv * lo;
      ay += wv * hi;
    }
    float2 r; r.x = ax; r.y = ay;
    *(float2*)(out + (size_t)t * 256 + h * 32 + lane * 2) = r;
  }
}

extern "C" void kernel_launch(void* const* d_in, const int* in_sizes, int n_in,
                              void* d_out, int out_size, void* d_ws, size_t ws_size,
                              hipStream_t stream){
  const float* tgt_pose = (const float*)d_in[0];
  const float* qpos     = (const float*)d_in[1];
  const float* refp     = (const float*)d_in[2];
  const float* memory   = (const float*)d_in[3];
  const float* win_Wqkv = (const float*)d_in[4];
  const float* win_bqkv = (const float*)d_in[5];
  const float* win_Wo   = (const float*)d_in[6];
  const float* win_bo   = (const float*)d_in[7];
  const float* win_ng   = (const float*)d_in[8];
  const float* win_nb   = (const float*)d_in[9];
  const float* acr_Wqkv = (const float*)d_in[10];
  const float* acr_bqkv = (const float*)d_in[11];
  const float* acr_Wo   = (const float*)d_in[12];
  const float* acr_bo   = (const float*)d_in[13];
  const float* acr_ng   = (const float*)d_in[14];
  const float* acr_nb   = (const float*)d_in[15];
  const float* off_W    = (const float*)d_in[16];
  const float* off_b    = (const float*)d_in[17];
  const float* aw_W     = (const float*)d_in[18];
  const float* aw_b     = (const float*)d_in[19];
  const float* val_W    = (const float*)d_in[20];
  const float* val_b    = (const float*)d_in[21];
  const float* outp_W   = (const float*)d_in[22];
  const float* outp_b   = (const float*)d_in[23];
  const float* gate_W   = (const float*)d_in[24];
  const float* gate_b   = (const float*)d_in[25];
  const float* gate_ng  = (const float*)d_in[26];
  const float* gate_nb  = (const float*)d_in[27];
  const float* ffn_W1   = (const float*)d_in[28];
  const float* ffn_b1   = (const float*)d_in[29];
  const float* ffn_W2   = (const float*)d_in[30];
  const float* ffn_b2   = (const float*)d_in[31];
  const float* n2_g     = (const float*)d_in[32];
  const float* n2_b     = (const float*)d_in[33];

  float* out = (float*)d_out;
  char* ws = (char*)d_ws;
  const size_t TB = (size_t)T_TOK * 256 * 4;
  float* B0 = (float*)(ws);
  float* B1 = (float*)(ws + TB);
  float* B2 = (float*)(ws + 2 * TB);
  float* B3 = (float*)(ws + 3 * TB);
  float* Q  = (float*)(ws + 4 * TB);                       // T*768 floats (reused as gate out T*512)
  float* AW = (float*)(ws + 4 * TB + (size_t)T_TOK * 768 * 4);
  char*  Vb = ws + 4 * TB + (size_t)T_TOK * 768 * 4 + (size_t)T_TOK * 128 * 4;
  __hip_bfloat16* V = (__hip_bfloat16*)Vb;                 // B*LEN_V*256 bf16 (139 MB)
  float* CAT = (float*)Vb;                                 // overlay (V dead by then)
  float* FF  = (float*)(Vb + (size_t)T_TOK * 512 * 4);     // overlay

  const int n4 = T_TOK * 64;                               // float4 count for T*256
  const int GM = (T_TOK + 127) / 128;                      // 107 M-blocks

  // 1. tgt0 = tgt_pose + pos
  add_k<<<(n4 + 255) / 256, 256, 0, stream>>>(tgt_pose, qpos, B0, n4);
  // 2. within qkv
  mgemm_k<0,0><<<dim3(6, GM), 256, 0, stream>>>(B0, win_Wqkv, win_bqkv, Q, nullptr, T_TOK, 768, 256);
  // 3. within attention (800 batches of S=17)
  mha_k<<<800 * 8, 256, (3 * 17 * 33 + 512) * 4, stream>>>(Q, B1, 17);
  // 4. out proj
  mgemm_k<0,0><<<dim3(2, GM), 256, 0, stream>>>(B1, win_Wo, win_bo, B2, nullptr, T_TOK, 256, 256);
  // 5. LN -> tgt1
  ln_k<0><<<T_TOK, 64, 0, stream>>>(B0, B2, win_ng, win_nb, B1);
  // 6. transpose to (b,k,q,d)
  transpose_k<<<(n4 + 255) / 256, 256, 0, stream>>>(B1, B0);
  // 7. across qkv
  mgemm_k<0,0><<<dim3(6, GM), 256, 0, stream>>>(B0, acr_Wqkv, acr_bqkv, Q, nullptr, T_TOK, 768, 256);
  // 8. across attention (136 batches of S=100)
  mha_k<<<136 * 8, 256, (3 * 100 * 33 + 512) * 4, stream>>>(Q, B2, 100);
  // 9. out proj
  mgemm_k<0,0><<<dim3(2, GM), 256, 0, stream>>>(B2, acr_Wo, acr_bo, B3, nullptr, T_TOK, 256, 256);
  // 10. LN + write back un-transposed -> tgt2
  ln_k<1><<<T_TOK, 64, 0, stream>>>(B0, B3, acr_ng, acr_nb, B1);
  // 11. tgt_q = tgt2 + pos
  add_k<<<(n4 + 255) / 256, 256, 0, stream>>>(B1, qpos, B0, n4);
  // 12. value projection (big GEMM, bf16 out, coalesced epilogue)
  mgemm_k<0,1><<<dim3(2, 2125), 256, 0, stream>>>(memory, val_W, val_b, nullptr, V, BS_ * LEN_VV, 256, 256);
  // 13. offsets
  mgemm_k<0,0><<<dim3(2, GM), 256, 0, stream>>>(B0, off_W, off_b, B1, nullptr, T_TOK, 256, 256);
  // 14. attention-weight logits
  mgemm_k<0,0><<<dim3(1, GM), 256, 0, stream>>>(B0, aw_W, aw_b, AW, nullptr, T_TOK, 128, 256);
  // 15. deformable sampling (two-phase)
  deform_k<<<T_TOK / 4, 256, 0, stream>>>(V, B1, AW, refp, B2);
  // 16. output proj of deformable attn
  mgemm_k<0,0><<<dim3(2, GM), 256, 0, stream>>>(B2, outp_W, outp_b, B3, nullptr, T_TOK, 256, 256);
  // 17. concat [tgt_q | t2]
  concat_k<<<(T_TOK * 128 + 255) / 256, 256, 0, stream>>>(B0, B3, CAT);
  // 18. gate GEMM (sigmoid epilogue), out into Q region (T*512)
  mgemm_k<2,0><<<dim3(4, GM), 256, 0, stream>>>(CAT, gate_W, gate_b, Q, nullptr, T_TOK, 512, 512);
  // 19. gate combine + LN -> tgt3
  gate_ln_k<<<T_TOK, 64, 0, stream>>>(Q, B0, B3, gate_ng, gate_nb, B1);
  // 20. FFN up (relu)
  mgemm_k<1,0><<<dim3(8, GM), 256, 0, stream>>>(B1, ffn_W1, ffn_b1, FF, nullptr, T_TOK, 1024, 256);
  // 21. FFN down
  mgemm_k<0,0><<<dim3(2, GM), 256, 0, stream>>>(FF, ffn_W2, ffn_b2, B2, nullptr, T_TOK, 256, 1024);
  // 22. final residual + clip + LN -> out
  ln_k<2><<<T_TOK, 64, 0, stream>>>(B1, B2, n2_g, n2_b, out);
}

// Round 5
// 571.154 us; speedup vs baseline: 2.9033x; 1.3036x over previous
//
#include <hip/hip_runtime.h>
#include <hip/hip_bf16.h>

#define NH 8
#define BS_ 8
#define NQ_ 100
#define NK_ 17
#define LQ 1700            // NQ_*NK_
#define T_TOK 13600        // BS_*LQ
#define LEN_VV 34000

typedef __attribute__((ext_vector_type(8))) short short8v;
typedef __attribute__((ext_vector_type(8))) __bf16 bf16x8;
typedef __attribute__((ext_vector_type(4))) float f32x4;

__device__ __forceinline__ float wave_sum(float v){
#pragma unroll
  for (int m = 32; m; m >>= 1) v += __shfl_xor(v, m, 64);
  return v;
}
__device__ __forceinline__ short f2bf(float f){
  __hip_bfloat16 h = __float2bfloat16(f);
  return *reinterpret_cast<short*>(&h);
}

// ---------------- elementwise add (float4) ----------------
__global__ __launch_bounds__(256) void add_k(const float* __restrict__ a,
                                             const float* __restrict__ b,
                                             float* __restrict__ o, int n4){
  int i = blockIdx.x * 256 + threadIdx.x;
  if (i >= n4) return;
  float4 x = ((const float4*)a)[i];
  float4 y = ((const float4*)b)[i];
  float4 r; r.x = x.x + y.x; r.y = x.y + y.y; r.z = x.z + y.z; r.w = x.w + y.w;
  ((float4*)o)[i] = r;
}

// ---------------- transpose (b,q,k,d) -> (b,k,q,d) ----------------
__global__ __launch_bounds__(256) void transpose_k(const float* __restrict__ in,
                                                   float* __restrict__ outp){
  int i = blockIdx.x * 256 + threadIdx.x;
  if (i >= T_TOK * 64) return;
  int orow = i >> 6, c = i & 63;
  int b = orow / LQ, rem = orow % LQ;
  int kk = rem / NQ_, q = rem % NQ_;
  int irow = b * LQ + q * NK_ + kk;
  ((float4*)outp)[(size_t)orow * 64 + c] = ((const float4*)in)[(size_t)irow * 64 + c];
}

// ---------------- concat [a|b] rows 256+256 -> 512 ----------------
__global__ __launch_bounds__(256) void concat_k(const float* __restrict__ a,
                                                const float* __restrict__ b,
                                                float* __restrict__ o){
  int i = blockIdx.x * 256 + threadIdx.x;
  if (i >= T_TOK * 128) return;
  int row = i >> 7, c = i & 127;
  float4 v = (c < 64) ? ((const float4*)a)[(size_t)row * 64 + c]
                      : ((const float4*)b)[(size_t)row * 64 + (c - 64)];
  ((float4*)o)[(size_t)row * 128 + c] = v;
}

// ---------------- MFMA GEMM: C[M,N] = A[M,K] @ W[N,K]^T + bias ----------------
template<int EPI, int OUTB>
__global__ __launch_bounds__(256) void mgemm_k(const float* __restrict__ A,
                                               const float* __restrict__ W,
                                               const float* __restrict__ bias,
                                               float* __restrict__ Cf,
                                               __hip_bfloat16* __restrict__ Cb,
                                               int M, int N, int K){
  __shared__ short sh[OUTB ? 128 * 136 : 128 * 128];
  short* As = sh;
  short* Ws = sh + 128 * 64;
  const int tid = threadIdx.x;
  const int bm = blockIdx.y * 128, bn = blockIdx.x * 128;
  const int wave = tid >> 6, lane = tid & 63;
  const int wm = (wave >> 1) * 64, wn = (wave & 1) * 64;
  const int s = tid & 7;
  const int row0 = tid >> 3;
  f32x4 acc[4][4] = {};
  const int lrow = lane & 15, lk = lane >> 4;

  float4 ra[8], rw[8];
#pragma unroll
  for (int i = 0; i < 4; i++){
    int row = row0 + i * 32;
    int gr = bm + row;
    float4 z = make_float4(0.f, 0.f, 0.f, 0.f);
    if (gr < M){
      const float* p = A + (size_t)gr * K + s * 8;
      ra[2 * i] = ((const float4*)p)[0]; ra[2 * i + 1] = ((const float4*)p)[1];
    } else { ra[2 * i] = z; ra[2 * i + 1] = z; }
    const float* q = W + (size_t)(bn + row) * K + s * 8;
    rw[2 * i] = ((const float4*)q)[0]; rw[2 * i + 1] = ((const float4*)q)[1];
  }

  for (int k0 = 0; k0 < K; k0 += 64){
#pragma unroll
    for (int i = 0; i < 4; i++){
      int row = row0 + i * 32;
      int sw = ((s ^ (row & 7)) << 3) + row * 64;
      float4 a0 = ra[2 * i], a1 = ra[2 * i + 1];
      short8v v;
      v[0]=f2bf(a0.x); v[1]=f2bf(a0.y); v[2]=f2bf(a0.z); v[3]=f2bf(a0.w);
      v[4]=f2bf(a1.x); v[5]=f2bf(a1.y); v[6]=f2bf(a1.z); v[7]=f2bf(a1.w);
      *(short8v*)&As[sw] = v;
      a0 = rw[2 * i]; a1 = rw[2 * i + 1];
      short8v u;
      u[0]=f2bf(a0.x); u[1]=f2bf(a0.y); u[2]=f2bf(a0.z); u[3]=f2bf(a0.w);
      u[4]=f2bf(a1.x); u[5]=f2bf(a1.y); u[6]=f2bf(a1.z); u[7]=f2bf(a1.w);
      *(short8v*)&Ws[sw] = u;
    }
    __syncthreads();
    if (k0 + 64 < K){
#pragma unroll
      for (int i = 0; i < 4; i++){
        int row = row0 + i * 32;
        int gr = bm + row;
        float4 z = make_float4(0.f, 0.f, 0.f, 0.f);
        if (gr < M){
          const float* p = A + (size_t)gr * K + k0 + 64 + s * 8;
          ra[2 * i] = ((const float4*)p)[0]; ra[2 * i + 1] = ((const float4*)p)[1];
        } else { ra[2 * i] = z; ra[2 * i + 1] = z; }
        const float* q = W + (size_t)(bn + row) * K + k0 + 64 + s * 8;
        rw[2 * i] = ((const float4*)q)[0]; rw[2 * i + 1] = ((const float4*)q)[1];
      }
    }
#pragma unroll
    for (int ks = 0; ks < 2; ks++){
      short8v af[4], bw[4];
      int slot = ks * 4 + lk;
#pragma unroll
      for (int m = 0; m < 4; m++){
        int r = wm + m * 16 + lrow;
        af[m] = *(const short8v*)&As[r * 64 + ((slot ^ (r & 7)) << 3)];
      }
#pragma unroll
      for (int n = 0; n < 4; n++){
        int r = wn + n * 16 + lrow;
        bw[n] = *(const short8v*)&Ws[r * 64 + ((slot ^ (r & 7)) << 3)];
      }
#pragma unroll
      for (int m = 0; m < 4; m++)
#pragma unroll
        for (int n = 0; n < 4; n++)
          acc[m][n] = __builtin_amdgcn_mfma_f32_16x16x32_bf16(
              __builtin_bit_cast(bf16x8, af[m]),
              __builtin_bit_cast(bf16x8, bw[n]), acc[m][n], 0, 0, 0);
    }
    __syncthreads();
  }
  if (OUTB){
    const int STR = 136;
#pragma unroll
    for (int n = 0; n < 4; n++){
      int col = wn + n * 16 + lrow;
      float bsv = bias[bn + col];
#pragma unroll
      for (int m = 0; m < 4; m++){
#pragma unroll
        for (int i = 0; i < 4; i++){
          int row = wm + m * 16 + lk * 4 + i;
          float c = acc[m][n][i] + bsv;
          if (EPI == 1) c = fmaxf(c, 0.f);
          if (EPI == 2) c = 1.f / (1.f + expf(-c));
          sh[row * STR + col] = f2bf(c);
        }
      }
    }
    __syncthreads();
#pragma unroll
    for (int it = 0; it < 8; it++){
      int r = it * 16 + (tid >> 4);
      int chunk = tid & 15;
      if (bm + r < M){
        uint4 v = *(const uint4*)((const char*)sh + r * 272 + chunk * 16);
        *(uint4*)((char*)Cb + ((size_t)(bm + r) * N + bn) * 2 + chunk * 16) = v;
      }
    }
  } else {
#pragma unroll
    for (int n = 0; n < 4; n++){
      int col = bn + wn + n * 16 + lrow;
      float bsv = bias[col];
#pragma unroll
      for (int m = 0; m < 4; m++){
#pragma unroll
        for (int i = 0; i < 4; i++){
          int row = bm + wm + m * 16 + lk * 4 + i;
          if (row >= M) continue;
          float c = acc[m][n][i] + bsv;
          if (EPI == 1) c = fmaxf(c, 0.f);
          if (EPI == 2) c = 1.f / (1.f + expf(-c));
          Cf[(size_t)row * N + col] = c;
        }
      }
    }
  }
}

// ---------------- MFMA MHA: block = (batch, head-pair), 2 waves per head ----------
// TP: S padded to 16 (112 for S=100, 32 for S=17)
template<int TP>
__global__ __launch_bounds__(256) void mha_mfma_k(const float* __restrict__ qkv,
                                                  float* __restrict__ out, int S){
  constexpr int MT = TP / 16;
  constexpr int KSTEPS = (TP + 31) / 32;     // PV k-steps (4 or 1)
  constexpr int KS32 = KSTEPS * 32;          // Vt staged cols (128 or 32)
  constexpr int VSTRB = (KS32 == 128) ? 256 : 128;  // Vt row stride bytes
  __shared__ short QK[2][TP][64];            // Q slots 0-3 | K slots 4-7, swz ^(row&7)
  __shared__ short Vt[2][32][VSTRB / 2];     // V^T, swz ^(row&7) on 16B slots
  __shared__ float Sc[2][16][128];           // score strip f32 (swz); P bf16 in-place
  __shared__ float rinv[2][16];

  const int tid = threadIdx.x;
  const int bid = blockIdx.x;
  const int batch = bid >> 2, hp = bid & 3;
  const int wave = tid >> 6, lane = tid & 63;
  const int hh = wave >> 1, wsub = wave & 1;
  const int lrow = lane & 15, lk = lane >> 4;
  const float scale = 0.17677669529663687f;  // 1/sqrt(32)
  const size_t qbase = (size_t)batch * S * 768;

  // ---- stage Q (x scale) and K ----
  for (int idx = tid; idx < 2 * TP * 4; idx += 256){
    int h2 = idx >= TP * 4;
    int rem = idx - h2 * TP * 4;
    int j = rem >> 2, s = rem & 3;
    int h = hp * 2 + h2;
    short8v qv = {}, kv = {};
    if (j < S){
      const float* p = qkv + qbase + (size_t)j * 768 + h * 32 + s * 8;
      float4 a = ((const float4*)p)[0];
      float4 b = ((const float4*)p)[1];
      qv[0]=f2bf(a.x*scale); qv[1]=f2bf(a.y*scale); qv[2]=f2bf(a.z*scale); qv[3]=f2bf(a.w*scale);
      qv[4]=f2bf(b.x*scale); qv[5]=f2bf(b.y*scale); qv[6]=f2bf(b.z*scale); qv[7]=f2bf(b.w*scale);
      float4 c = ((const float4*)(p + 256))[0];
      float4 d = ((const float4*)(p + 256))[1];
      kv[0]=f2bf(c.x); kv[1]=f2bf(c.y); kv[2]=f2bf(c.z); kv[3]=f2bf(c.w);
      kv[4]=f2bf(d.x); kv[5]=f2bf(d.y); kv[6]=f2bf(d.z); kv[7]=f2bf(d.w);
    }
    *(short8v*)&QK[h2][j][(s ^ (j & 7)) << 3] = qv;
    *(short8v*)&QK[h2][j][((s + 4) ^ (j & 7)) << 3] = kv;
  }
  // ---- stage V transposed (zero for j >= S) ----
  for (int idx = tid; idx < 2 * KS32 * 8; idx += 256){
    int h2 = idx >= KS32 * 8;
    int rem = idx - h2 * KS32 * 8;
    int j = rem >> 3, e4 = rem & 7;
    int h = hp * 2 + h2;
    float4 v = make_float4(0.f, 0.f, 0.f, 0.f);
    if (j < S) v = *(const float4*)(qkv + qbase + (size_t)j * 768 + h * 32 + 512 + e4 * 4);
    short vs4[4] = { f2bf(v.x), f2bf(v.y), f2bf(v.z), f2bf(v.w) };
#pragma unroll
    for (int c = 0; c < 4; c++){
      int e = e4 * 4 + c;
      char* pb = (char*)&Vt[h2][0][0] + e * VSTRB + (((j >> 3) ^ (e & 7)) << 4) + ((j & 7) << 1);
      *(short*)pb = vs4[c];
    }
  }
  __syncthreads();

  for (int mt = 0; mt < MT; mt++){
    // ---- scores for strip mt ----
    for (int nt = wsub; nt < MT; nt += 2){
      int ar = mt * 16 + lrow;
      short8v aq = *(const short8v*)&QK[hh][ar][(lk ^ (ar & 7)) << 3];
      int br = nt * 16 + lrow;
      short8v bk = *(const short8v*)&QK[hh][br][((lk + 4) ^ (br & 7)) << 3];
      f32x4 z = {};
      f32x4 d = __builtin_amdgcn_mfma_f32_16x16x32_bf16(
          __builtin_bit_cast(bf16x8, aq), __builtin_bit_cast(bf16x8, bk), z, 0, 0, 0);
#pragma unroll
      for (int i = 0; i < 4; i++){
        int rr = lk * 4 + i;
        int c = nt * 16 + lrow;
        Sc[hh][rr][(((c >> 2) ^ (rr & 7)) << 2) + (c & 3)] = d[i];
      }
    }
    __syncthreads();
    // ---- softmax (one wave per head; 4 lanes per row) ----
    if (wsub == 0){
      int rr = lane >> 2, p = lane & 3;
      int grow = mt * 16 + rr;
      int Seff = (grow < S) ? S : 0;
      float mx = -1e30f;
#pragma unroll
      for (int m = 0; m < KSTEPS; m++){
        int j = p + 4 * m;
#pragma unroll
        for (int half = 0; half < 2; half++){
          int ls = 2 * j + half;
          float4 v = *(const float4*)&Sc[hh][rr][(ls ^ (rr & 7)) << 2];
          int c0 = ls * 4;
          mx = fmaxf(mx, (c0 + 0 < Seff) ? v.x : -1e30f);
          mx = fmaxf(mx, (c0 + 1 < Seff) ? v.y : -1e30f);
          mx = fmaxf(mx, (c0 + 2 < Seff) ? v.z : -1e30f);
          mx = fmaxf(mx, (c0 + 3 < Seff) ? v.w : -1e30f);
        }
      }
      mx = fmaxf(mx, __shfl_xor(mx, 1, 64));
      mx = fmaxf(mx, __shfl_xor(mx, 2, 64));
      float sum = 0.f;
#pragma unroll
      for (int m = 0; m < KSTEPS; m++){
        int j = p + 4 * m;
        float ev[8];
#pragma unroll
        for (int half = 0; half < 2; half++){
          int ls = 2 * j + half;
          float4 v = *(const float4*)&Sc[hh][rr][(ls ^ (rr & 7)) << 2];
          int c0 = ls * 4;
          ev[half * 4 + 0] = (c0 + 0 < Seff) ? __expf(v.x - mx) : 0.f;
          ev[half * 4 + 1] = (c0 + 1 < Seff) ? __expf(v.y - mx) : 0.f;
          ev[half * 4 + 2] = (c0 + 2 < Seff) ? __expf(v.z - mx) : 0.f;
          ev[half * 4 + 3] = (c0 + 3 < Seff) ? __expf(v.w - mx) : 0.f;
        }
        short8v pb;
#pragma unroll
        for (int q2 = 0; q2 < 8; q2++){ pb[q2] = f2bf(ev[q2]); sum += ev[q2]; }
        *(short8v*)((char*)&Sc[hh][rr][0] + ((j ^ (rr & 7)) << 4)) = pb;
      }
      sum += __shfl_xor(sum, 1, 64);
      sum += __shfl_xor(sum, 2, 64);
      if (p == 0) rinv[hh][rr] = (sum > 0.f) ? 1.f / sum : 0.f;
    }
    __syncthreads();
    // ---- PV for strip: wave owns n-tile wsub (16 of 32 cols) ----
    {
      int nt2 = wsub;
      f32x4 acc = {};
#pragma unroll
      for (int ks = 0; ks < KSTEPS; ks++){
        int slot = ks * 4 + lk;
        short8v ap = *(const short8v*)((const char*)&Sc[hh][lrow][0] + ((slot ^ (lrow & 7)) << 4));
        int e = nt2 * 16 + lrow;
        short8v bv = *(const short8v*)((const char*)&Vt[hh][0][0] + e * VSTRB + ((slot ^ (e & 7)) << 4));
        acc = __builtin_amdgcn_mfma_f32_16x16x32_bf16(
            __builtin_bit_cast(bf16x8, ap), __builtin_bit_cast(bf16x8, bv), acc, 0, 0, 0);
      }
      int h = hp * 2 + hh;
#pragma unroll
      for (int i = 0; i < 4; i++){
        int row = mt * 16 + lk * 4 + i;
        if (row < S){
          float rv = rinv[hh][lk * 4 + i];
          out[((size_t)batch * S + row) * 256 + h * 32 + nt2 * 16 + lrow] = acc[i] * rv;
        }
      }
    }
    __syncthreads();
  }
}

// ---------------- LayerNorm over 256; MODE 0 plain, 1 permuted-write, 2 clip ----------------
template<int MODE>
__global__ __launch_bounds__(64) void ln_k(const float* __restrict__ a,
                                           const float* __restrict__ b,
                                           const float* __restrict__ g,
                                           const float* __restrict__ be,
                                           float* __restrict__ out){
  int r = blockIdx.x;
  int lane = threadIdx.x;
  float4 xa = *(const float4*)(a + (size_t)r * 256 + lane * 4);
  float4 xb = *(const float4*)(b + (size_t)r * 256 + lane * 4);
  float x[4] = { xa.x + xb.x, xa.y + xb.y, xa.z + xb.z, xa.w + xb.w };
  if (MODE == 2){
#pragma unroll
    for (int i = 0; i < 4; i++) x[i] = fminf(fmaxf(x[i], -65504.f), 65504.f);
  }
  float s = x[0] + x[1] + x[2] + x[3];
  s = wave_sum(s);
  float mean = s * (1.f / 256.f);
  float sq = 0.f;
#pragma unroll
  for (int i = 0; i < 4; i++){ float d = x[i] - mean; sq += d * d; }
  float var = wave_sum(sq) * (1.f / 256.f);
  float rstd = rsqrtf(var + 1e-5f);
  float4 gg = *(const float4*)(g + lane * 4);
  float4 bb = *(const float4*)(be + lane * 4);
  size_t orow = r;
  if (MODE == 1){
    int bi = r / LQ; int rem = r % LQ; int kk = rem / NQ_; int q = rem % NQ_;
    orow = (size_t)bi * LQ + q * NK_ + kk;
  }
  float4 o;
  o.x = (x[0] - mean) * rstd * gg.x + bb.x;
  o.y = (x[1] - mean) * rstd * gg.y + bb.y;
  o.z = (x[2] - mean) * rstd * gg.z + bb.z;
  o.w = (x[3] - mean) * rstd * gg.w + bb.w;
  *(float4*)(out + orow * 256 + lane * 4) = o;
}

// ---------------- gate combine + LN ----------------
__global__ __launch_bounds__(64) void gate_ln_k(const float* __restrict__ G,
                                                const float* __restrict__ aq,
                                                const float* __restrict__ t2,
                                                const float* __restrict__ g,
                                                const float* __restrict__ be,
                                                float* __restrict__ out){
  int r = blockIdx.x;
  int lane = threadIdx.x;
  float4 g1 = *(const float4*)(G + (size_t)r * 512 + lane * 4);
  float4 g2 = *(const float4*)(G + (size_t)r * 512 + 256 + lane * 4);
  float4 xa = *(const float4*)(aq + (size_t)r * 256 + lane * 4);
  float4 xt = *(const float4*)(t2 + (size_t)r * 256 + lane * 4);
  float x[4] = { g1.x * xa.x + g2.x * xt.x, g1.y * xa.y + g2.y * xt.y,
                 g1.z * xa.z + g2.z * xt.z, g1.w * xa.w + g2.w * xt.w };
  float s = x[0] + x[1] + x[2] + x[3];
  s = wave_sum(s);
  float mean = s * (1.f / 256.f);
  float sq = 0.f;
#pragma unroll
  for (int i = 0; i < 4; i++){ float d = x[i] - mean; sq += d * d; }
  float var = wave_sum(sq) * (1.f / 256.f);
  float rstd = rsqrtf(var + 1e-5f);
  float4 gg = *(const float4*)(g + lane * 4);
  float4 bb = *(const float4*)(be + lane * 4);
  float4 o;
  o.x = (x[0] - mean) * rstd * gg.x + bb.x;
  o.y = (x[1] - mean) * rstd * gg.y + bb.y;
  o.z = (x[2] - mean) * rstd * gg.z + bb.z;
  o.w = (x[3] - mean) * rstd * gg.w + bb.w;
  *(float4*)(out + (size_t)r * 256 + lane * 4) = o;
}

// ---------------- deformable sampling, two-phase ----------------
__global__ __launch_bounds__(256) void deform_k(const __hip_bfloat16* __restrict__ val,
                                                const float* __restrict__ off,
                                                const float* __restrict__ awr,
                                                const float* __restrict__ ref,
                                                float* __restrict__ out){
  __shared__ uint2 meta[32][16][4];
  const int tid = threadIdx.x;
  const int t0 = blockIdx.x * 4;
  {
    int g = tid >> 3;
    int pair = tid & 7;
    int lt = g >> 3, h = g & 7;
    int t = t0 + lt;
    int b = t / LQ;
    int p0 = pair * 2;
    int l = p0 >> 2;
    const int starts[4] = {0, 25600, 32000, 33600};
    const int HS[4] = {160, 80, 40, 20};
    int w = HS[l];
    float a0 = awr[(size_t)t * 128 + h * 16 + p0];
    float a1 = awr[(size_t)t * 128 + h * 16 + p0 + 1];
    float mx = fmaxf(a0, a1);
#pragma unroll
    for (int m = 1; m <= 4; m <<= 1) mx = fmaxf(mx, __shfl_xor(mx, m, 64));
    float e0 = expf(a0 - mx), e1 = expf(a1 - mx);
    float s = e0 + e1;
#pragma unroll
    for (int m = 1; m <= 4; m <<= 1) s += __shfl_xor(s, m, 64);
    float inv = 1.f / s;
    float rx = ref[((size_t)t * 4 + l) * 2 + 0];
    float ry = ref[((size_t)t * 4 + l) * 2 + 1];
    float4 ov = *(const float4*)(off + (size_t)t * 256 + h * 32 + l * 8 + p0 * 2);
    int vbase = (b * LEN_VV + starts[l]) * 128 + h * 16;
#pragma unroll
    for (int pp = 0; pp < 2; pp++){
      float wgt = (pp ? e1 : e0) * inv;
      float px = rx * w + (pp ? ov.z : ov.x) - 0.5f;
      float py = ry * w + (pp ? ov.w : ov.y) - 0.5f;
      float x0f = floorf(px), y0f = floorf(py);
      float lx = px - x0f, ly = py - y0f;
      int x0 = (int)x0f, y0 = (int)y0f;
#pragma unroll
      for (int c = 0; c < 4; c++){
        int dx = c & 1, dy = c >> 1;
        int xi = x0 + dx, yi = y0 + dy;
        bool ok = (xi >= 0) & (xi < w) & (yi >= 0) & (yi < w);
        float cw = ok ? wgt * (dx ? lx : 1.f - lx) * (dy ? ly : 1.f - ly) : 0.f;
        uint idx = ok ? (uint)(vbase + (yi * w + xi) * 128) : 0u;
        uint2 m2; m2.x = idx; m2.y = __float_as_uint(cw);
        meta[g][p0 + pp][c] = m2;
      }
    }
  }
  __syncthreads();
  const uint* V2 = (const uint*)val;
  int sg = tid >> 4, lane = tid & 15;
#pragma unroll
  for (int it = 0; it < 2; it++){
    int g = it * 16 + sg;
    int lt = g >> 3, h = g & 7;
    int t = t0 + lt;
    float ax = 0.f, ay = 0.f;
#pragma unroll 4
    for (int c = 0; c < 64; c++){
      uint2 mw = meta[g][c >> 2][c & 3];
      float wv = __uint_as_float(mw.y);
      uint v = V2[(size_t)mw.x + lane];
      float lo = __uint_as_float(v << 16);
      float hi = __uint_as_float(v & 0xffff0000u);
      ax += wv * lo;
      ay += wv * hi;
    }
    float2 r; r.x = ax; r.y = ay;
    *(float2*)(out + (size_t)t * 256 + h * 32 + lane * 2) = r;
  }
}

extern "C" void kernel_launch(void* const* d_in, const int* in_sizes, int n_in,
                              void* d_out, int out_size, void* d_ws, size_t ws_size,
                              hipStream_t stream){
  const float* tgt_pose = (const float*)d_in[0];
  const float* qpos     = (const float*)d_in[1];
  const float* refp     = (const float*)d_in[2];
  const float* memory   = (const float*)d_in[3];
  const float* win_Wqkv = (const float*)d_in[4];
  const float* win_bqkv = (const float*)d_in[5];
  const float* win_Wo   = (const float*)d_in[6];
  const float* win_bo   = (const float*)d_in[7];
  const float* win_ng   = (const float*)d_in[8];
  const float* win_nb   = (const float*)d_in[9];
  const float* acr_Wqkv = (const float*)d_in[10];
  const float* acr_bqkv = (const float*)d_in[11];
  const float* acr_Wo   = (const float*)d_in[12];
  const float* acr_bo   = (const float*)d_in[13];
  const float* acr_ng   = (const float*)d_in[14];
  const float* acr_nb   = (const float*)d_in[15];
  const float* off_W    = (const float*)d_in[16];
  const float* off_b    = (const float*)d_in[17];
  const float* aw_W     = (const float*)d_in[18];
  const float* aw_b     = (const float*)d_in[19];
  const float* val_W    = (const float*)d_in[20];
  const float* val_b    = (const float*)d_in[21];
  const float* outp_W   = (const float*)d_in[22];
  const float* outp_b   = (const float*)d_in[23];
  const float* gate_W   = (const float*)d_in[24];
  const float* gate_b   = (const float*)d_in[25];
  const float* gate_ng  = (const float*)d_in[26];
  const float* gate_nb  = (const float*)d_in[27];
  const float* ffn_W1   = (const float*)d_in[28];
  const float* ffn_b1   = (const float*)d_in[29];
  const float* ffn_W2   = (const float*)d_in[30];
  const float* ffn_b2   = (const float*)d_in[31];
  const float* n2_g     = (const float*)d_in[32];
  const float* n2_b     = (const float*)d_in[33];

  float* out = (float*)d_out;
  char* ws = (char*)d_ws;
  const size_t TB = (size_t)T_TOK * 256 * 4;
  float* B0 = (float*)(ws);
  float* B1 = (float*)(ws + TB);
  float* B2 = (float*)(ws + 2 * TB);
  float* B3 = (float*)(ws + 3 * TB);
  float* Q  = (float*)(ws + 4 * TB);
  float* AW = (float*)(ws + 4 * TB + (size_t)T_TOK * 768 * 4);
  char*  Vb = ws + 4 * TB + (size_t)T_TOK * 768 * 4 + (size_t)T_TOK * 128 * 4;
  __hip_bfloat16* V = (__hip_bfloat16*)Vb;
  float* CAT = (float*)Vb;
  float* FF  = (float*)(Vb + (size_t)T_TOK * 512 * 4);

  const int n4 = T_TOK * 64;
  const int GM = (T_TOK + 127) / 128;

  // 1. tgt0 = tgt_pose + pos
  add_k<<<(n4 + 255) / 256, 256, 0, stream>>>(tgt_pose, qpos, B0, n4);
  // 2. within qkv
  mgemm_k<0,0><<<dim3(6, GM), 256, 0, stream>>>(B0, win_Wqkv, win_bqkv, Q, nullptr, T_TOK, 768, 256);
  // 3. within attention (800 batches of S=17) — MFMA
  mha_mfma_k<32><<<800 * 4, 256, 0, stream>>>(Q, B1, 17);
  // 4. out proj
  mgemm_k<0,0><<<dim3(2, GM), 256, 0, stream>>>(B1, win_Wo, win_bo, B2, nullptr, T_TOK, 256, 256);
  // 5. LN -> tgt1
  ln_k<0><<<T_TOK, 64, 0, stream>>>(B0, B2, win_ng, win_nb, B1);
  // 6. transpose to (b,k,q,d)
  transpose_k<<<(n4 + 255) / 256, 256, 0, stream>>>(B1, B0);
  // 7. across qkv
  mgemm_k<0,0><<<dim3(6, GM), 256, 0, stream>>>(B0, acr_Wqkv, acr_bqkv, Q, nullptr, T_TOK, 768, 256);
  // 8. across attention (136 batches of S=100) — MFMA
  mha_mfma_k<112><<<136 * 4, 256, 0, stream>>>(Q, B2, 100);
  // 9. out proj
  mgemm_k<0,0><<<dim3(2, GM), 256, 0, stream>>>(B2, acr_Wo, acr_bo, B3, nullptr, T_TOK, 256, 256);
  // 10. LN + write back un-transposed -> tgt2
  ln_k<1><<<T_TOK, 64, 0, stream>>>(B0, B3, acr_ng, acr_nb, B1);
  // 11. tgt_q = tgt2 + pos
  add_k<<<(n4 + 255) / 256, 256, 0, stream>>>(B1, qpos, B0, n4);
  // 12. value projection (big GEMM, bf16 out, coalesced epilogue)
  mgemm_k<0,1><<<dim3(2, 2125), 256, 0, stream>>>(memory, val_W, val_b, nullptr, V, BS_ * LEN_VV, 256, 256);
  // 13. offsets
  mgemm_k<0,0><<<dim3(2, GM), 256, 0, stream>>>(B0, off_W, off_b, B1, nullptr, T_TOK, 256, 256);
  // 14. attention-weight logits
  mgemm_k<0,0><<<dim3(1, GM), 256, 0, stream>>>(B0, aw_W, aw_b, AW, nullptr, T_TOK, 128, 256);
  // 15. deformable sampling (two-phase)
  deform_k<<<T_TOK / 4, 256, 0, stream>>>(V, B1, AW, refp, B2);
  // 16. output proj of deformable attn
  mgemm_k<0,0><<<dim3(2, GM), 256, 0, stream>>>(B2, outp_W, outp_b, B3, nullptr, T_TOK, 256, 256);
  // 17. concat [tgt_q | t2]
  concat_k<<<(T_TOK * 128 + 255) / 256, 256, 0, stream>>>(B0, B3, CAT);
  // 18. gate GEMM (sigmoid epilogue)
  mgemm_k<2,0><<<dim3(4, GM), 256, 0, stream>>>(CAT, gate_W, gate_b, Q, nullptr, T_TOK, 512, 512);
  // 19. gate combine + LN -> tgt3
  gate_ln_k<<<T_TOK, 64, 0, stream>>>(Q, B0, B3, gate_ng, gate_nb, B1);
  // 20. FFN up (relu)
  mgemm_k<1,0><<<dim3(8, GM), 256, 0, stream>>>(B1, ffn_W1, ffn_b1, FF, nullptr, T_TOK, 1024, 256);
  // 21. FFN down
  mgemm_k<0,0><<<dim3(2, GM), 256, 0, stream>>>(FF, ffn_W2, ffn_b2, B2, nullptr, T_TOK, 256, 1024);
  // 22. final residual + clip + LN -> out
  ln_k<2><<<T_TOK, 64, 0, stream>>>(B1, B2, n2_g, n2_b, out);
}

// Round 6
// 465.404 us; speedup vs baseline: 3.5630x; 1.2272x over previous
//
#include <hip/hip_runtime.h>
#include <hip/hip_bf16.h>

#define NH 8
#define BS_ 8
#define NQ_ 100
#define NK_ 17
#define LQ 1700            // NQ_*NK_
#define T_TOK 13600        // BS_*LQ
#define LEN_VV 34000

typedef __attribute__((ext_vector_type(8))) short short8v;
typedef __attribute__((ext_vector_type(8))) __bf16 bf16x8;
typedef __attribute__((ext_vector_type(4))) float f32x4;

__device__ __forceinline__ float wave_sum(float v){
#pragma unroll
  for (int m = 32; m; m >>= 1) v += __shfl_xor(v, m, 64);
  return v;
}
__device__ __forceinline__ short f2bf(float f){
  __hip_bfloat16 h = __float2bfloat16(f);
  return *reinterpret_cast<short*>(&h);
}
__device__ __forceinline__ float bf2f(short s){
  return __uint_as_float(((uint)(unsigned short)s) << 16);
}

// ---------------- elementwise add (float4) ----------------
__global__ __launch_bounds__(256) void add_k(const float* __restrict__ a,
                                             const float* __restrict__ b,
                                             float* __restrict__ o, int n4){
  int i = blockIdx.x * 256 + threadIdx.x;
  if (i >= n4) return;
  float4 x = ((const float4*)a)[i];
  float4 y = ((const float4*)b)[i];
  float4 r; r.x = x.x + y.x; r.y = x.y + y.y; r.z = x.z + y.z; r.w = x.w + y.w;
  ((float4*)o)[i] = r;
}

// ---------------- 128x128 MFMA GEMM (fp32 in) ----------------
template<int EPI, int OUTB>
__global__ __launch_bounds__(256) void mgemm_k(const float* __restrict__ A,
                                               const float* __restrict__ W,
                                               const float* __restrict__ bias,
                                               float* __restrict__ Cf,
                                               __hip_bfloat16* __restrict__ Cb,
                                               int M, int N, int K){
  __shared__ short sh[OUTB ? 128 * 136 : 128 * 128];
  short* As = sh;
  short* Ws = sh + 128 * 64;
  const int tid = threadIdx.x;
  const int bm = blockIdx.y * 128, bn = blockIdx.x * 128;
  const int wave = tid >> 6, lane = tid & 63;
  const int wm = (wave >> 1) * 64, wn = (wave & 1) * 64;
  const int s = tid & 7;
  const int row0 = tid >> 3;
  f32x4 acc[4][4] = {};
  const int lrow = lane & 15, lk = lane >> 4;

  float4 ra[8], rw[8];
#pragma unroll
  for (int i = 0; i < 4; i++){
    int row = row0 + i * 32;
    int gr = bm + row;
    float4 z = make_float4(0.f, 0.f, 0.f, 0.f);
    if (gr < M){
      const float* p = A + (size_t)gr * K + s * 8;
      ra[2 * i] = ((const float4*)p)[0]; ra[2 * i + 1] = ((const float4*)p)[1];
    } else { ra[2 * i] = z; ra[2 * i + 1] = z; }
    const float* q = W + (size_t)(bn + row) * K + s * 8;
    rw[2 * i] = ((const float4*)q)[0]; rw[2 * i + 1] = ((const float4*)q)[1];
  }

  for (int k0 = 0; k0 < K; k0 += 64){
#pragma unroll
    for (int i = 0; i < 4; i++){
      int row = row0 + i * 32;
      int sw = ((s ^ (row & 7)) << 3) + row * 64;
      float4 a0 = ra[2 * i], a1 = ra[2 * i + 1];
      short8v v;
      v[0]=f2bf(a0.x); v[1]=f2bf(a0.y); v[2]=f2bf(a0.z); v[3]=f2bf(a0.w);
      v[4]=f2bf(a1.x); v[5]=f2bf(a1.y); v[6]=f2bf(a1.z); v[7]=f2bf(a1.w);
      *(short8v*)&As[sw] = v;
      a0 = rw[2 * i]; a1 = rw[2 * i + 1];
      short8v u;
      u[0]=f2bf(a0.x); u[1]=f2bf(a0.y); u[2]=f2bf(a0.z); u[3]=f2bf(a0.w);
      u[4]=f2bf(a1.x); u[5]=f2bf(a1.y); u[6]=f2bf(a1.z); u[7]=f2bf(a1.w);
      *(short8v*)&Ws[sw] = u;
    }
    __syncthreads();
    if (k0 + 64 < K){
#pragma unroll
      for (int i = 0; i < 4; i++){
        int row = row0 + i * 32;
        int gr = bm + row;
        float4 z = make_float4(0.f, 0.f, 0.f, 0.f);
        if (gr < M){
          const float* p = A + (size_t)gr * K + k0 + 64 + s * 8;
          ra[2 * i] = ((const float4*)p)[0]; ra[2 * i + 1] = ((const float4*)p)[1];
        } else { ra[2 * i] = z; ra[2 * i + 1] = z; }
        const float* q = W + (size_t)(bn + row) * K + k0 + 64 + s * 8;
        rw[2 * i] = ((const float4*)q)[0]; rw[2 * i + 1] = ((const float4*)q)[1];
      }
    }
#pragma unroll
    for (int ks = 0; ks < 2; ks++){
      short8v af[4], bw[4];
      int slot = ks * 4 + lk;
#pragma unroll
      for (int m = 0; m < 4; m++){
        int r = wm + m * 16 + lrow;
        af[m] = *(const short8v*)&As[r * 64 + ((slot ^ (r & 7)) << 3)];
      }
#pragma unroll
      for (int n = 0; n < 4; n++){
        int r = wn + n * 16 + lrow;
        bw[n] = *(const short8v*)&Ws[r * 64 + ((slot ^ (r & 7)) << 3)];
      }
#pragma unroll
      for (int m = 0; m < 4; m++)
#pragma unroll
        for (int n = 0; n < 4; n++)
          acc[m][n] = __builtin_amdgcn_mfma_f32_16x16x32_bf16(
              __builtin_bit_cast(bf16x8, af[m]),
              __builtin_bit_cast(bf16x8, bw[n]), acc[m][n], 0, 0, 0);
    }
    __syncthreads();
  }
  if (OUTB){
    const int STR = 136;
#pragma unroll
    for (int n = 0; n < 4; n++){
      int col = wn + n * 16 + lrow;
      float bsv = bias[bn + col];
#pragma unroll
      for (int m = 0; m < 4; m++){
#pragma unroll
        for (int i = 0; i < 4; i++){
          int row = wm + m * 16 + lk * 4 + i;
          float c = acc[m][n][i] + bsv;
          if (EPI == 1) c = fmaxf(c, 0.f);
          if (EPI == 2) c = 1.f / (1.f + expf(-c));
          sh[row * STR + col] = f2bf(c);
        }
      }
    }
    __syncthreads();
#pragma unroll
    for (int it = 0; it < 8; it++){
      int r = it * 16 + (tid >> 4);
      int chunk = tid & 15;
      if (bm + r < M){
        uint4 v = *(const uint4*)((const char*)sh + r * 272 + chunk * 16);
        *(uint4*)((char*)Cb + ((size_t)(bm + r) * N + bn) * 2 + chunk * 16) = v;
      }
    }
  } else {
#pragma unroll
    for (int n = 0; n < 4; n++){
      int col = bn + wn + n * 16 + lrow;
      float bsv = bias[col];
#pragma unroll
      for (int m = 0; m < 4; m++){
#pragma unroll
        for (int i = 0; i < 4; i++){
          int row = bm + wm + m * 16 + lk * 4 + i;
          if (row >= M) continue;
          float c = acc[m][n][i] + bsv;
          if (EPI == 1) c = fmaxf(c, 0.f);
          if (EPI == 2) c = 1.f / (1.f + expf(-c));
          Cf[(size_t)row * N + col] = c;
        }
      }
    }
  }
}

// ---------------- 64x64 MFMA GEMM (high-parallelism, small N) ----------------
// INB: A is bf16. DUALA: A = [A0(256) | A1(256)] along K (fp32, stride 256).
// W split at NSPLIT: rows < NSPLIT from W0, else W1 (same for bias).
template<int EPI, int OUTB, int INB, int DUALA>
__global__ __launch_bounds__(256) void g64_k(const void* __restrict__ Av,
                                             const void* __restrict__ A1v,
                                             const float* __restrict__ W0,
                                             const float* __restrict__ W1,
                                             int NSPLIT,
                                             const float* __restrict__ bias0,
                                             const float* __restrict__ bias1,
                                             float* __restrict__ Cf,
                                             __hip_bfloat16* __restrict__ Cb,
                                             int M, int N, int K, int sA){
  __shared__ short sh64[2 * 64 * 64];
  short* As = sh64;
  short* Ws = sh64 + 64 * 64;
  const int tid = threadIdx.x;
  const int bn = blockIdx.x * 64, bm = blockIdx.y * 64;
  const int wave = tid >> 6, lane = tid & 63;
  const int wm = (wave >> 1) * 32, wn = (wave & 1) * 32;
  const int s = tid & 7, row0 = tid >> 3;        // rows 0..31, +32
  const int lrow = lane & 15, lk = lane >> 4;
  f32x4 acc[2][2] = {};

  for (int k0 = 0; k0 < K; k0 += 64){
#pragma unroll
    for (int i = 0; i < 2; i++){
      int row = row0 + i * 32;
      int sw = ((s ^ (row & 7)) << 3) + row * 64;
      // A tile
      short8v v = {};
      int gr = bm + row;
      if (gr < M){
        if (INB){
          v = *(const short8v*)((const short*)Av + (size_t)gr * sA + k0 + s * 8);
        } else {
          const float* Ap;
          if (DUALA) Ap = (k0 < 256) ? (const float*)Av + (size_t)gr * 256 + k0
                                     : (const float*)A1v + (size_t)gr * 256 + (k0 - 256);
          else Ap = (const float*)Av + (size_t)gr * sA + k0;
          float4 a0 = ((const float4*)(Ap + s * 8))[0];
          float4 a1 = ((const float4*)(Ap + s * 8))[1];
          v[0]=f2bf(a0.x); v[1]=f2bf(a0.y); v[2]=f2bf(a0.z); v[3]=f2bf(a0.w);
          v[4]=f2bf(a1.x); v[5]=f2bf(a1.y); v[6]=f2bf(a1.z); v[7]=f2bf(a1.w);
        }
      }
      *(short8v*)&As[sw] = v;
      // W tile
      int wr = bn + row;
      const float* Wp = (wr < NSPLIT) ? W0 + (size_t)wr * K + k0
                                      : W1 + (size_t)(wr - NSPLIT) * K + k0;
      float4 b0 = ((const float4*)(Wp + s * 8))[0];
      float4 b1 = ((const float4*)(Wp + s * 8))[1];
      short8v u;
      u[0]=f2bf(b0.x); u[1]=f2bf(b0.y); u[2]=f2bf(b0.z); u[3]=f2bf(b0.w);
      u[4]=f2bf(b1.x); u[5]=f2bf(b1.y); u[6]=f2bf(b1.z); u[7]=f2bf(b1.w);
      *(short8v*)&Ws[sw] = u;
    }
    __syncthreads();
#pragma unroll
    for (int ks = 0; ks < 2; ks++){
      int slot = ks * 4 + lk;
      short8v af[2], bw[2];
#pragma unroll
      for (int m = 0; m < 2; m++){
        int r = wm + m * 16 + lrow;
        af[m] = *(const short8v*)&As[r * 64 + ((slot ^ (r & 7)) << 3)];
      }
#pragma unroll
      for (int n = 0; n < 2; n++){
        int r = wn + n * 16 + lrow;
        bw[n] = *(const short8v*)&Ws[r * 64 + ((slot ^ (r & 7)) << 3)];
      }
#pragma unroll
      for (int m = 0; m < 2; m++)
#pragma unroll
        for (int n = 0; n < 2; n++)
          acc[m][n] = __builtin_amdgcn_mfma_f32_16x16x32_bf16(
              __builtin_bit_cast(bf16x8, af[m]),
              __builtin_bit_cast(bf16x8, bw[n]), acc[m][n], 0, 0, 0);
    }
    __syncthreads();
  }
  if (OUTB){
    const int STR = 72;
#pragma unroll
    for (int n = 0; n < 2; n++){
      int col = wn + n * 16 + lrow;
      int gc = bn + col;
      float bsv = (gc < NSPLIT) ? bias0[gc] : bias1[gc - NSPLIT];
#pragma unroll
      for (int m = 0; m < 2; m++){
#pragma unroll
        for (int i = 0; i < 4; i++){
          int row = wm + m * 16 + lk * 4 + i;
          float c = acc[m][n][i] + bsv;
          if (EPI == 1) c = fmaxf(c, 0.f);
          if (EPI == 2) c = 1.f / (1.f + expf(-c));
          sh64[row * STR + col] = f2bf(c);
        }
      }
    }
    __syncthreads();
#pragma unroll
    for (int it = 0; it < 2; it++){
      int r = it * 32 + (tid >> 3);
      int chunk = tid & 7;
      if (bm + r < M){
        uint4 v = *(const uint4*)((const char*)sh64 + r * 144 + chunk * 16);
        *(uint4*)((char*)Cb + ((size_t)(bm + r) * N + bn) * 2 + chunk * 16) = v;
      }
    }
  } else {
#pragma unroll
    for (int n = 0; n < 2; n++){
      int gc = bn + wn + n * 16 + lrow;
      float bsv = (gc < NSPLIT) ? bias0[gc] : bias1[gc - NSPLIT];
#pragma unroll
      for (int m = 0; m < 2; m++){
#pragma unroll
        for (int i = 0; i < 4; i++){
          int row = bm + wm + m * 16 + lk * 4 + i;
          if (row >= M) continue;
          float c = acc[m][n][i] + bsv;
          if (EPI == 1) c = fmaxf(c, 0.f);
          if (EPI == 2) c = 1.f / (1.f + expf(-c));
          Cf[(size_t)row * N + gc] = c;
        }
      }
    }
  }
}

// ---------------- MFMA MHA: bf16 qkv in, bf16 out. block = (batch, head-pair) ----
template<int TP>
__global__ __launch_bounds__(256) void mha_mfma_k(const short* __restrict__ qkv,
                                                  __hip_bfloat16* __restrict__ out, int S){
  constexpr int MT = TP / 16;
  constexpr int KSTEPS = (TP + 31) / 32;
  constexpr int KS32 = KSTEPS * 32;
  constexpr int VSTRB = (KS32 == 128) ? 256 : 128;
  __shared__ short QK[2][TP][64];
  __shared__ short Vt[2][32][VSTRB / 2];
  __shared__ float Sc[2][16][128];
  __shared__ float rinv[2][16];

  const int tid = threadIdx.x;
  const int bid = blockIdx.x;
  const int batch = bid >> 2, hp = bid & 3;
  const int wave = tid >> 6, lane = tid & 63;
  const int hh = wave >> 1, wsub = wave & 1;
  const int lrow = lane & 15, lk = lane >> 4;
  const float scale = 0.17677669529663687f;  // 1/sqrt(32)
  const size_t qbase = (size_t)batch * S * 768;

  // stage Q | K (bf16 passthrough)
  for (int idx = tid; idx < 2 * TP * 4; idx += 256){
    int h2 = idx >= TP * 4;
    int rem = idx - h2 * TP * 4;
    int j = rem >> 2, s = rem & 3;
    int h = hp * 2 + h2;
    short8v qv = {}, kv = {};
    if (j < S){
      const short* p = qkv + qbase + (size_t)j * 768 + h * 32 + s * 8;
      qv = *(const short8v*)p;
      kv = *(const short8v*)(p + 256);
    }
    *(short8v*)&QK[h2][j][(s ^ (j & 7)) << 3] = qv;
    *(short8v*)&QK[h2][j][((s + 4) ^ (j & 7)) << 3] = kv;
  }
  // stage V transposed
  for (int idx = tid; idx < 2 * KS32 * 4; idx += 256){
    int h2 = idx >= KS32 * 4;
    int rem = idx - h2 * KS32 * 4;
    int j = rem >> 2, e8 = rem & 3;
    int h = hp * 2 + h2;
    short8v v = {};
    if (j < S) v = *(const short8v*)(qkv + qbase + (size_t)j * 768 + h * 32 + 512 + e8 * 8);
#pragma unroll
    for (int c = 0; c < 8; c++){
      int e = e8 * 8 + c;
      char* pb = (char*)&Vt[h2][0][0] + e * VSTRB + (((j >> 3) ^ (e & 7)) << 4) + ((j & 7) << 1);
      *(short*)pb = v[c];
    }
  }
  __syncthreads();

  for (int mt = 0; mt < MT; mt++){
    for (int nt = wsub; nt < MT; nt += 2){
      int ar = mt * 16 + lrow;
      short8v aq = *(const short8v*)&QK[hh][ar][(lk ^ (ar & 7)) << 3];
      int br = nt * 16 + lrow;
      short8v bk = *(const short8v*)&QK[hh][br][((lk + 4) ^ (br & 7)) << 3];
      f32x4 z = {};
      f32x4 d = __builtin_amdgcn_mfma_f32_16x16x32_bf16(
          __builtin_bit_cast(bf16x8, aq), __builtin_bit_cast(bf16x8, bk), z, 0, 0, 0);
#pragma unroll
      for (int i = 0; i < 4; i++){
        int rr = lk * 4 + i;
        int c = nt * 16 + lrow;
        Sc[hh][rr][(((c >> 2) ^ (rr & 7)) << 2) + (c & 3)] = d[i] * scale;
      }
    }
    __syncthreads();
    if (wsub == 0){
      int rr = lane >> 2, p = lane & 3;
      int grow = mt * 16 + rr;
      int Seff = (grow < S) ? S : 0;
      float mx = -1e30f;
#pragma unroll
      for (int m = 0; m < KSTEPS; m++){
        int j = p + 4 * m;
#pragma unroll
        for (int half = 0; half < 2; half++){
          int ls = 2 * j + half;
          float4 v = *(const float4*)&Sc[hh][rr][(ls ^ (rr & 7)) << 2];
          int c0 = ls * 4;
          mx = fmaxf(mx, (c0 + 0 < Seff) ? v.x : -1e30f);
          mx = fmaxf(mx, (c0 + 1 < Seff) ? v.y : -1e30f);
          mx = fmaxf(mx, (c0 + 2 < Seff) ? v.z : -1e30f);
          mx = fmaxf(mx, (c0 + 3 < Seff) ? v.w : -1e30f);
        }
      }
      mx = fmaxf(mx, __shfl_xor(mx, 1, 64));
      mx = fmaxf(mx, __shfl_xor(mx, 2, 64));
      float sum = 0.f;
#pragma unroll
      for (int m = 0; m < KSTEPS; m++){
        int j = p + 4 * m;
        float ev[8];
#pragma unroll
        for (int half = 0; half < 2; half++){
          int ls = 2 * j + half;
          float4 v = *(const float4*)&Sc[hh][rr][(ls ^ (rr & 7)) << 2];
          int c0 = ls * 4;
          ev[half * 4 + 0] = (c0 + 0 < Seff) ? __expf(v.x - mx) : 0.f;
          ev[half * 4 + 1] = (c0 + 1 < Seff) ? __expf(v.y - mx) : 0.f;
          ev[half * 4 + 2] = (c0 + 2 < Seff) ? __expf(v.z - mx) : 0.f;
          ev[half * 4 + 3] = (c0 + 3 < Seff) ? __expf(v.w - mx) : 0.f;
        }
        short8v pb;
#pragma unroll
        for (int q2 = 0; q2 < 8; q2++){ pb[q2] = f2bf(ev[q2]); sum += ev[q2]; }
        *(short8v*)((char*)&Sc[hh][rr][0] + ((j ^ (rr & 7)) << 4)) = pb;
      }
      sum += __shfl_xor(sum, 1, 64);
      sum += __shfl_xor(sum, 2, 64);
      if (p == 0) rinv[hh][rr] = (sum > 0.f) ? 1.f / sum : 0.f;
    }
    __syncthreads();
    {
      int nt2 = wsub;
      f32x4 acc = {};
#pragma unroll
      for (int ks = 0; ks < KSTEPS; ks++){
        int slot = ks * 4 + lk;
        short8v ap = *(const short8v*)((const char*)&Sc[hh][lrow][0] + ((slot ^ (lrow & 7)) << 4));
        int e = nt2 * 16 + lrow;
        short8v bv = *(const short8v*)((const char*)&Vt[hh][0][0] + e * VSTRB + ((slot ^ (e & 7)) << 4));
        acc = __builtin_amdgcn_mfma_f32_16x16x32_bf16(
            __builtin_bit_cast(bf16x8, ap), __builtin_bit_cast(bf16x8, bv), acc, 0, 0, 0);
      }
      int h = hp * 2 + hh;
#pragma unroll
      for (int i = 0; i < 4; i++){
        int row = mt * 16 + lk * 4 + i;
        if (row < S){
          float rv = rinv[hh][lk * 4 + i];
          out[((size_t)batch * S + row) * 256 + h * 32 + nt2 * 16 + lrow] =
              __float2bfloat16(acc[i] * rv);
        }
      }
    }
    __syncthreads();
  }
}

// ---------------- LayerNorm over 256 ----------------
// MODE 0 plain; 2 clip; 3 un-transpose write + qpos add; 4 transpose write
template<int MODE>
__global__ __launch_bounds__(64) void ln_k(const float* __restrict__ a,
                                           const float* __restrict__ b,
                                           const float* __restrict__ g,
                                           const float* __restrict__ be,
                                           float* __restrict__ out,
                                           const float* __restrict__ qp){
  int r = blockIdx.x;
  int lane = threadIdx.x;
  float4 xa = *(const float4*)(a + (size_t)r * 256 + lane * 4);
  float4 xb = *(const float4*)(b + (size_t)r * 256 + lane * 4);
  float x[4] = { xa.x + xb.x, xa.y + xb.y, xa.z + xb.z, xa.w + xb.w };
  if (MODE == 2){
#pragma unroll
    for (int i = 0; i < 4; i++) x[i] = fminf(fmaxf(x[i], -65504.f), 65504.f);
  }
  float s = x[0] + x[1] + x[2] + x[3];
  s = wave_sum(s);
  float mean = s * (1.f / 256.f);
  float sq = 0.f;
#pragma unroll
  for (int i = 0; i < 4; i++){ float d = x[i] - mean; sq += d * d; }
  float var = wave_sum(sq) * (1.f / 256.f);
  float rstd = rsqrtf(var + 1e-5f);
  float4 gg = *(const float4*)(g + lane * 4);
  float4 bb = *(const float4*)(be + lane * 4);
  size_t orow = r;
  if (MODE == 3){            // input rows (b,k,q) -> output (b,q,k)
    int bi = r / LQ; int rem = r % LQ; int kk = rem / NQ_; int q = rem % NQ_;
    orow = (size_t)bi * LQ + q * NK_ + kk;
  }
  if (MODE == 4){            // input rows (b,q,k) -> output (b,k,q)
    int bi = r / LQ; int rem = r % LQ; int q = rem / NK_; int kk = rem % NK_;
    orow = (size_t)bi * LQ + kk * NQ_ + q;
  }
  float4 o;
  o.x = (x[0] - mean) * rstd * gg.x + bb.x;
  o.y = (x[1] - mean) * rstd * gg.y + bb.y;
  o.z = (x[2] - mean) * rstd * gg.z + bb.z;
  o.w = (x[3] - mean) * rstd * gg.w + bb.w;
  if (MODE == 3){
    float4 qv = *(const float4*)(qp + orow * 256 + lane * 4);
    o.x += qv.x; o.y += qv.y; o.z += qv.z; o.w += qv.w;
  }
  *(float4*)(out + orow * 256 + lane * 4) = o;
}

// ---------------- gate combine + LN (G in bf16) ----------------
__global__ __launch_bounds__(64) void gate_ln_k(const short* __restrict__ G,
                                                const float* __restrict__ aq,
                                                const float* __restrict__ t2,
                                                const float* __restrict__ g,
                                                const float* __restrict__ be,
                                                float* __restrict__ out){
  int r = blockIdx.x;
  int lane = threadIdx.x;
  const short* gp = G + (size_t)r * 512 + lane * 4;
  float g1v[4], g2v[4];
#pragma unroll
  for (int i = 0; i < 4; i++){ g1v[i] = bf2f(gp[i]); g2v[i] = bf2f(gp[256 + i]); }
  float4 xa = *(const float4*)(aq + (size_t)r * 256 + lane * 4);
  float4 xt = *(const float4*)(t2 + (size_t)r * 256 + lane * 4);
  float x[4] = { g1v[0] * xa.x + g2v[0] * xt.x, g1v[1] * xa.y + g2v[1] * xt.y,
                 g1v[2] * xa.z + g2v[2] * xt.z, g1v[3] * xa.w + g2v[3] * xt.w };
  float s = x[0] + x[1] + x[2] + x[3];
  s = wave_sum(s);
  float mean = s * (1.f / 256.f);
  float sq = 0.f;
#pragma unroll
  for (int i = 0; i < 4; i++){ float d = x[i] - mean; sq += d * d; }
  float var = wave_sum(sq) * (1.f / 256.f);
  float rstd = rsqrtf(var + 1e-5f);
  float4 gg = *(const float4*)(g + lane * 4);
  float4 bb = *(const float4*)(be + lane * 4);
  float4 o;
  o.x = (x[0] - mean) * rstd * gg.x + bb.x;
  o.y = (x[1] - mean) * rstd * gg.y + bb.y;
  o.z = (x[2] - mean) * rstd * gg.z + bb.z;
  o.w = (x[3] - mean) * rstd * gg.w + bb.w;
  *(float4*)(out + (size_t)r * 256 + lane * 4) = o;
}

// ---------------- deformable sampling, two-phase; bf16 out ----------------
__global__ __launch_bounds__(256) void deform_k(const __hip_bfloat16* __restrict__ val,
                                                const float* __restrict__ offaw,
                                                const float* __restrict__ ref,
                                                unsigned int* __restrict__ outb){
  __shared__ uint2 meta[32][16][4];
  const int tid = threadIdx.x;
  const int t0 = blockIdx.x * 4;
  {
    int g = tid >> 3;
    int pair = tid & 7;
    int lt = g >> 3, h = g & 7;
    int t = t0 + lt;
    int b = t / LQ;
    int p0 = pair * 2;
    int l = p0 >> 2;
    const int starts[4] = {0, 25600, 32000, 33600};
    const int HS[4] = {160, 80, 40, 20};
    int w = HS[l];
    const float* ap = offaw + (size_t)t * 384 + 256 + h * 16;
    float a0 = ap[p0];
    float a1 = ap[p0 + 1];
    float mx = fmaxf(a0, a1);
#pragma unroll
    for (int m = 1; m <= 4; m <<= 1) mx = fmaxf(mx, __shfl_xor(mx, m, 64));
    float e0 = expf(a0 - mx), e1 = expf(a1 - mx);
    float s = e0 + e1;
#pragma unroll
    for (int m = 1; m <= 4; m <<= 1) s += __shfl_xor(s, m, 64);
    float inv = 1.f / s;
    float rx = ref[((size_t)t * 4 + l) * 2 + 0];
    float ry = ref[((size_t)t * 4 + l) * 2 + 1];
    float4 ov = *(const float4*)(offaw + (size_t)t * 384 + h * 32 + l * 8 + p0 * 2);
    int vbase = (b * LEN_VV + starts[l]) * 128 + h * 16;
#pragma unroll
    for (int pp = 0; pp < 2; pp++){
      float wgt = (pp ? e1 : e0) * inv;
      float px = rx * w + (pp ? ov.z : ov.x) - 0.5f;
      float py = ry * w + (pp ? ov.w : ov.y) - 0.5f;
      float x0f = floorf(px), y0f = floorf(py);
      float lx = px - x0f, ly = py - y0f;
      int x0 = (int)x0f, y0 = (int)y0f;
#pragma unroll
      for (int c = 0; c < 4; c++){
        int dx = c & 1, dy = c >> 1;
        int xi = x0 + dx, yi = y0 + dy;
        bool ok = (xi >= 0) & (xi < w) & (yi >= 0) & (yi < w);
        float cw = ok ? wgt * (dx ? lx : 1.f - lx) * (dy ? ly : 1.f - ly) : 0.f;
        uint idx = ok ? (uint)(vbase + (yi * w + xi) * 128) : 0u;
        uint2 m2; m2.x = idx; m2.y = __float_as_uint(cw);
        meta[g][p0 + pp][c] = m2;
      }
    }
  }
  __syncthreads();
  const uint* V2 = (const uint*)val;
  int sg = tid >> 4, lane = tid & 15;
#pragma unroll
  for (int it = 0; it < 2; it++){
    int g = it * 16 + sg;
    int lt = g >> 3, h = g & 7;
    int t = t0 + lt;
    float ax = 0.f, ay = 0.f;
#pragma unroll 4
    for (int c = 0; c < 64; c++){
      uint2 mw = meta[g][c >> 2][c & 3];
      float wv = __uint_as_float(mw.y);
      uint v = V2[(size_t)mw.x + lane];
      float lo = __uint_as_float(v << 16);
      float hi = __uint_as_float(v & 0xffff0000u);
      ax += wv * lo;
      ay += wv * hi;
    }
    uint u = ((uint)(unsigned short)f2bf(ay) << 16) | (uint)(unsigned short)f2bf(ax);
    outb[((size_t)t * 256 + h * 32) / 2 + lane] = u;
  }
}

extern "C" void kernel_launch(void* const* d_in, const int* in_sizes, int n_in,
                              void* d_out, int out_size, void* d_ws, size_t ws_size,
                              hipStream_t stream){
  const float* tgt_pose = (const float*)d_in[0];
  const float* qpos     = (const float*)d_in[1];
  const float* refp     = (const float*)d_in[2];
  const float* memory   = (const float*)d_in[3];
  const float* win_Wqkv = (const float*)d_in[4];
  const float* win_bqkv = (const float*)d_in[5];
  const float* win_Wo   = (const float*)d_in[6];
  const float* win_bo   = (const float*)d_in[7];
  const float* win_ng   = (const float*)d_in[8];
  const float* win_nb   = (const float*)d_in[9];
  const float* acr_Wqkv = (const float*)d_in[10];
  const float* acr_bqkv = (const float*)d_in[11];
  const float* acr_Wo   = (const float*)d_in[12];
  const float* acr_bo   = (const float*)d_in[13];
  const float* acr_ng   = (const float*)d_in[14];
  const float* acr_nb   = (const float*)d_in[15];
  const float* off_W    = (const float*)d_in[16];
  const float* off_b    = (const float*)d_in[17];
  const float* aw_W     = (const float*)d_in[18];
  const float* aw_b     = (const float*)d_in[19];
  const float* val_W    = (const float*)d_in[20];
  const float* val_b    = (const float*)d_in[21];
  const float* outp_W   = (const float*)d_in[22];
  const float* outp_b   = (const float*)d_in[23];
  const float* gate_W   = (const float*)d_in[24];
  const float* gate_b   = (const float*)d_in[25];
  const float* gate_ng  = (const float*)d_in[26];
  const float* gate_nb  = (const float*)d_in[27];
  const float* ffn_W1   = (const float*)d_in[28];
  const float* ffn_b1   = (const float*)d_in[29];
  const float* ffn_W2   = (const float*)d_in[30];
  const float* ffn_b2   = (const float*)d_in[31];
  const float* n2_g     = (const float*)d_in[32];
  const float* n2_b     = (const float*)d_in[33];

  float* out = (float*)d_out;
  char* ws = (char*)d_ws;
  const size_t TB = (size_t)T_TOK * 256 * 4;          // 13.93 MB
  float* B0 = (float*)(ws);
  float* B1 = (float*)(ws + TB);
  float* B2 = (float*)(ws + 2 * TB);
  float* B3 = (float*)(ws + 3 * TB);
  char* p = ws + 4 * TB;
  short* Qb = (short*)p;                 p += (size_t)T_TOK * 768 * 2;   // bf16 qkv
  short* ABF = (short*)p;                p += (size_t)T_TOK * 256 * 2;   // bf16 attn/deform out
  float* OFFAW = (float*)p;              p += (size_t)T_TOK * 384 * 4;   // off|aw logits
  short* Gb = (short*)p;                 p += (size_t)T_TOK * 512 * 2;   // bf16 gate
  char* Vregion = p;
  __hip_bfloat16* V = (__hip_bfloat16*)Vregion;                          // 139 MB
  short* FF = (short*)Vregion;                                           // overlay (V dead)

  const int n4 = T_TOK * 64;
  const int GM128 = (T_TOK + 127) / 128;   // 107
  const int GM64  = (T_TOK + 63) / 64;     // 213
  const int BIG = 1 << 30;

  // 1. tgt0 = tgt_pose + pos
  add_k<<<(n4 + 255) / 256, 256, 0, stream>>>(tgt_pose, qpos, B0, n4);
  // 2. within qkv -> Qb (bf16)
  mgemm_k<0,1><<<dim3(6, GM128), 256, 0, stream>>>(B0, win_Wqkv, win_bqkv, nullptr, (__hip_bfloat16*)Qb, T_TOK, 768, 256);
  // 3. within attention (S=17)
  mha_mfma_k<32><<<800 * 4, 256, 0, stream>>>(Qb, (__hip_bfloat16*)ABF, 17);
  // 4. out proj (bf16 A) -> B2
  g64_k<0,0,1,0><<<dim3(4, GM64), 256, 0, stream>>>(ABF, nullptr, win_Wo, win_Wo, BIG, win_bo, win_bo, B2, nullptr, T_TOK, 256, 256, 256);
  // 5+6. LN + transpose-write -> B1 = xk (b,k,q)
  ln_k<4><<<T_TOK, 64, 0, stream>>>(B0, B2, win_ng, win_nb, B1, nullptr);
  // 7. across qkv -> Qb
  mgemm_k<0,1><<<dim3(6, GM128), 256, 0, stream>>>(B1, acr_Wqkv, acr_bqkv, nullptr, (__hip_bfloat16*)Qb, T_TOK, 768, 256);
  // 8. across attention (S=100)
  mha_mfma_k<112><<<136 * 4, 256, 0, stream>>>(Qb, (__hip_bfloat16*)ABF, 100);
  // 9. out proj -> B2
  g64_k<0,0,1,0><<<dim3(4, GM64), 256, 0, stream>>>(ABF, nullptr, acr_Wo, acr_Wo, BIG, acr_bo, acr_bo, B2, nullptr, T_TOK, 256, 256, 256);
  // 10+11. LN + un-transpose + qpos add -> B0 = tgt_q (b,q,k)
  ln_k<3><<<T_TOK, 64, 0, stream>>>(B1, B2, acr_ng, acr_nb, B0, qpos);
  // 12. value projection -> V bf16
  mgemm_k<0,1><<<dim3(2, 2125), 256, 0, stream>>>(memory, val_W, val_b, nullptr, V, BS_ * LEN_VV, 256, 256);
  // 13+14. offsets + aw logits fused (N=384) -> OFFAW
  g64_k<0,0,0,0><<<dim3(6, GM64), 256, 0, stream>>>(B0, nullptr, off_W, aw_W, 256, off_b, aw_b, OFFAW, nullptr, T_TOK, 384, 256, 256);
  // 15. deformable sampling -> ABF bf16
  deform_k<<<T_TOK / 4, 256, 0, stream>>>(V, OFFAW, refp, (unsigned int*)ABF);
  // 16. output proj of deformable attn -> B3
  g64_k<0,0,1,0><<<dim3(4, GM64), 256, 0, stream>>>(ABF, nullptr, outp_W, outp_W, BIG, outp_b, outp_b, B3, nullptr, T_TOK, 256, 256, 256);
  // 18. gate GEMM (dual-A concat, sigmoid, bf16 out) -> Gb
  g64_k<2,1,0,1><<<dim3(8, GM64), 256, 0, stream>>>(B0, B3, gate_W, gate_W, BIG, gate_b, gate_b, nullptr, (__hip_bfloat16*)Gb, T_TOK, 512, 512, 256);
  // 19. gate combine + LN -> B2 = tgt3
  gate_ln_k<<<T_TOK, 64, 0, stream>>>(Gb, B0, B3, gate_ng, gate_nb, B2);
  // 20. FFN up (relu, bf16 out) -> FF
  mgemm_k<1,1><<<dim3(8, GM128), 256, 0, stream>>>(B2, ffn_W1, ffn_b1, nullptr, (__hip_bfloat16*)FF, T_TOK, 1024, 256);
  // 21. FFN down (bf16 A) -> B1
  g64_k<0,0,1,0><<<dim3(4, GM64), 256, 0, stream>>>(FF, nullptr, ffn_W2, ffn_W2, BIG, ffn_b2, ffn_b2, B1, nullptr, T_TOK, 256, 1024, 1024);
  // 22. final residual + clip + LN -> out
  ln_k<2><<<T_TOK, 64, 0, stream>>>(B2, B1, n2_g, n2_b, out, nullptr);
}

// Round 7
// 460.042 us; speedup vs baseline: 3.6046x; 1.0117x over previous
//
#include <hip/hip_runtime.h>
#include <hip/hip_bf16.h>

#define NH 8
#define BS_ 8
#define NQ_ 100
#define NK_ 17
#define LQ 1700            // NQ_*NK_
#define T_TOK 13600        // BS_*LQ
#define LEN_VV 34000

typedef __attribute__((ext_vector_type(8))) short short8v;
typedef __attribute__((ext_vector_type(8))) __bf16 bf16x8;
typedef __attribute__((ext_vector_type(4))) float f32x4;

__device__ __forceinline__ float wave_sum(float v){
#pragma unroll
  for (int m = 32; m; m >>= 1) v += __shfl_xor(v, m, 64);
  return v;
}
__device__ __forceinline__ short f2bf(float f){
  __hip_bfloat16 h = __float2bfloat16(f);
  return *reinterpret_cast<short*>(&h);
}
__device__ __forceinline__ float bf2f(short s){
  return __uint_as_float(((uint)(unsigned short)s) << 16);
}

// ---------------- 128x128 MFMA GEMM (fp32 in, bf16 out via LDS epilogue) ----------------
template<int EPI>
__global__ __launch_bounds__(256) void mgemm_k(const float* __restrict__ A,
                                               const float* __restrict__ W,
                                               const float* __restrict__ bias,
                                               __hip_bfloat16* __restrict__ Cb,
                                               int M, int N, int K){
  __shared__ short sh[128 * 136];
  short* As = sh;
  short* Ws = sh + 128 * 64;
  const int tid = threadIdx.x;
  const int bm = blockIdx.y * 128, bn = blockIdx.x * 128;
  const int wave = tid >> 6, lane = tid & 63;
  const int wm = (wave >> 1) * 64, wn = (wave & 1) * 64;
  const int s = tid & 7;
  const int row0 = tid >> 3;
  f32x4 acc[4][4] = {};
  const int lrow = lane & 15, lk = lane >> 4;

  float4 ra[8], rw[8];
#pragma unroll
  for (int i = 0; i < 4; i++){
    int row = row0 + i * 32;
    int gr = bm + row;
    float4 z = make_float4(0.f, 0.f, 0.f, 0.f);
    if (gr < M){
      const float* p = A + (size_t)gr * K + s * 8;
      ra[2 * i] = ((const float4*)p)[0]; ra[2 * i + 1] = ((const float4*)p)[1];
    } else { ra[2 * i] = z; ra[2 * i + 1] = z; }
    const float* q = W + (size_t)(bn + row) * K + s * 8;
    rw[2 * i] = ((const float4*)q)[0]; rw[2 * i + 1] = ((const float4*)q)[1];
  }

  for (int k0 = 0; k0 < K; k0 += 64){
#pragma unroll
    for (int i = 0; i < 4; i++){
      int row = row0 + i * 32;
      int sw = ((s ^ (row & 7)) << 3) + row * 64;
      float4 a0 = ra[2 * i], a1 = ra[2 * i + 1];
      short8v v;
      v[0]=f2bf(a0.x); v[1]=f2bf(a0.y); v[2]=f2bf(a0.z); v[3]=f2bf(a0.w);
      v[4]=f2bf(a1.x); v[5]=f2bf(a1.y); v[6]=f2bf(a1.z); v[7]=f2bf(a1.w);
      *(short8v*)&As[sw] = v;
      a0 = rw[2 * i]; a1 = rw[2 * i + 1];
      short8v u;
      u[0]=f2bf(a0.x); u[1]=f2bf(a0.y); u[2]=f2bf(a0.z); u[3]=f2bf(a0.w);
      u[4]=f2bf(a1.x); u[5]=f2bf(a1.y); u[6]=f2bf(a1.z); u[7]=f2bf(a1.w);
      *(short8v*)&Ws[sw] = u;
    }
    __syncthreads();
    if (k0 + 64 < K){
#pragma unroll
      for (int i = 0; i < 4; i++){
        int row = row0 + i * 32;
        int gr = bm + row;
        float4 z = make_float4(0.f, 0.f, 0.f, 0.f);
        if (gr < M){
          const float* p = A + (size_t)gr * K + k0 + 64 + s * 8;
          ra[2 * i] = ((const float4*)p)[0]; ra[2 * i + 1] = ((const float4*)p)[1];
        } else { ra[2 * i] = z; ra[2 * i + 1] = z; }
        const float* q = W + (size_t)(bn + row) * K + k0 + 64 + s * 8;
        rw[2 * i] = ((const float4*)q)[0]; rw[2 * i + 1] = ((const float4*)q)[1];
      }
    }
#pragma unroll
    for (int ks = 0; ks < 2; ks++){
      short8v af[4], bw[4];
      int slot = ks * 4 + lk;
#pragma unroll
      for (int m = 0; m < 4; m++){
        int r = wm + m * 16 + lrow;
        af[m] = *(const short8v*)&As[r * 64 + ((slot ^ (r & 7)) << 3)];
      }
#pragma unroll
      for (int n = 0; n < 4; n++){
        int r = wn + n * 16 + lrow;
        bw[n] = *(const short8v*)&Ws[r * 64 + ((slot ^ (r & 7)) << 3)];
      }
#pragma unroll
      for (int m = 0; m < 4; m++)
#pragma unroll
        for (int n = 0; n < 4; n++)
          acc[m][n] = __builtin_amdgcn_mfma_f32_16x16x32_bf16(
              __builtin_bit_cast(bf16x8, af[m]),
              __builtin_bit_cast(bf16x8, bw[n]), acc[m][n], 0, 0, 0);
    }
    __syncthreads();
  }
  const int STR = 136;
#pragma unroll
  for (int n = 0; n < 4; n++){
    int col = wn + n * 16 + lrow;
    float bsv = bias[bn + col];
#pragma unroll
    for (int m = 0; m < 4; m++){
#pragma unroll
      for (int i = 0; i < 4; i++){
        int row = wm + m * 16 + lk * 4 + i;
        float c = acc[m][n][i] + bsv;
        if (EPI == 1) c = fmaxf(c, 0.f);
        sh[row * STR + col] = f2bf(c);
      }
    }
  }
  __syncthreads();
#pragma unroll
  for (int it = 0; it < 8; it++){
    int r = it * 16 + (tid >> 4);
    int chunk = tid & 15;
    if (bm + r < M){
      uint4 v = *(const uint4*)((const char*)sh + r * 272 + chunk * 16);
      *(uint4*)((char*)Cb + ((size_t)(bm + r) * N + bn) * 2 + chunk * 16) = v;
    }
  }
}

// ---------------- dual-job 128x128 GEMM: job0 (A+A2)@W0^T -> C0, job1 A1@W1^T -> C1 ----
// K=256 both. Job0 blocks interleaved every INTER-th block for overlap.
__global__ __launch_bounds__(256) void dualgemm_k(const float* __restrict__ A0,
                                                  const float* __restrict__ A0b,
                                                  const float* __restrict__ W0,
                                                  const float* __restrict__ bias0,
                                                  __hip_bfloat16* __restrict__ C0,
                                                  int M0, int N0, int nbx0, int NJ0,
                                                  const float* __restrict__ A1,
                                                  const float* __restrict__ W1,
                                                  const float* __restrict__ bias1,
                                                  __hip_bfloat16* __restrict__ C1,
                                                  int M1, int N1, int nbx1){
  const int INTER = 7;
  __shared__ short sh[128 * 136];
  short* As = sh;
  short* Ws = sh + 128 * 64;
  const int bid = blockIdx.x;
  const int j = bid / INTER, r7 = bid % INTER;
  const float* A; const float* A2; const float* W; const float* bias;
  __hip_bfloat16* C; int M, N, bx, by;
  if (r7 == 0 && j < NJ0){
    A = A0; A2 = A0b; W = W0; bias = bias0; C = C0; M = M0; N = N0;
    bx = j % nbx0; by = j / nbx0;
  } else {
    int c0 = (j + 1 < NJ0) ? (j + 1) : NJ0;
    int idx = bid - c0;
    A = A1; A2 = nullptr; W = W1; bias = bias1; C = C1; M = M1; N = N1;
    bx = idx % nbx1; by = idx / nbx1;
  }
  const int K = 256;
  const int tid = threadIdx.x;
  const int bm = by * 128, bn = bx * 128;
  const int wave = tid >> 6, lane = tid & 63;
  const int wm = (wave >> 1) * 64, wn = (wave & 1) * 64;
  const int s = tid & 7;
  const int row0 = tid >> 3;
  f32x4 acc[4][4] = {};
  const int lrow = lane & 15, lk = lane >> 4;

  float4 ra[8], rw[8];
#pragma unroll
  for (int i = 0; i < 4; i++){
    int row = row0 + i * 32;
    int gr = bm + row;
    float4 z = make_float4(0.f, 0.f, 0.f, 0.f);
    if (gr < M){
      const float* p = A + (size_t)gr * K + s * 8;
      float4 x0 = ((const float4*)p)[0], x1 = ((const float4*)p)[1];
      if (A2){
        const float* q2 = A2 + (size_t)gr * K + s * 8;
        float4 y0 = ((const float4*)q2)[0], y1 = ((const float4*)q2)[1];
        x0.x+=y0.x; x0.y+=y0.y; x0.z+=y0.z; x0.w+=y0.w;
        x1.x+=y1.x; x1.y+=y1.y; x1.z+=y1.z; x1.w+=y1.w;
      }
      ra[2 * i] = x0; ra[2 * i + 1] = x1;
    } else { ra[2 * i] = z; ra[2 * i + 1] = z; }
    const float* q = W + (size_t)(bn + row) * K + s * 8;
    rw[2 * i] = ((const float4*)q)[0]; rw[2 * i + 1] = ((const float4*)q)[1];
  }

  for (int k0 = 0; k0 < K; k0 += 64){
#pragma unroll
    for (int i = 0; i < 4; i++){
      int row = row0 + i * 32;
      int sw = ((s ^ (row & 7)) << 3) + row * 64;
      float4 a0 = ra[2 * i], a1 = ra[2 * i + 1];
      short8v v;
      v[0]=f2bf(a0.x); v[1]=f2bf(a0.y); v[2]=f2bf(a0.z); v[3]=f2bf(a0.w);
      v[4]=f2bf(a1.x); v[5]=f2bf(a1.y); v[6]=f2bf(a1.z); v[7]=f2bf(a1.w);
      *(short8v*)&As[sw] = v;
      a0 = rw[2 * i]; a1 = rw[2 * i + 1];
      short8v u;
      u[0]=f2bf(a0.x); u[1]=f2bf(a0.y); u[2]=f2bf(a0.z); u[3]=f2bf(a0.w);
      u[4]=f2bf(a1.x); u[5]=f2bf(a1.y); u[6]=f2bf(a1.z); u[7]=f2bf(a1.w);
      *(short8v*)&Ws[sw] = u;
    }
    __syncthreads();
    if (k0 + 64 < K){
#pragma unroll
      for (int i = 0; i < 4; i++){
        int row = row0 + i * 32;
        int gr = bm + row;
        float4 z = make_float4(0.f, 0.f, 0.f, 0.f);
        if (gr < M){
          const float* p = A + (size_t)gr * K + k0 + 64 + s * 8;
          float4 x0 = ((const float4*)p)[0], x1 = ((const float4*)p)[1];
          if (A2){
            const float* q2 = A2 + (size_t)gr * K + k0 + 64 + s * 8;
            float4 y0 = ((const float4*)q2)[0], y1 = ((const float4*)q2)[1];
            x0.x+=y0.x; x0.y+=y0.y; x0.z+=y0.z; x0.w+=y0.w;
            x1.x+=y1.x; x1.y+=y1.y; x1.z+=y1.z; x1.w+=y1.w;
          }
          ra[2 * i] = x0; ra[2 * i + 1] = x1;
        } else { ra[2 * i] = z; ra[2 * i + 1] = z; }
        const float* q = W + (size_t)(bn + row) * K + k0 + 64 + s * 8;
        rw[2 * i] = ((const float4*)q)[0]; rw[2 * i + 1] = ((const float4*)q)[1];
      }
    }
#pragma unroll
    for (int ks = 0; ks < 2; ks++){
      short8v af[4], bw[4];
      int slot = ks * 4 + lk;
#pragma unroll
      for (int m = 0; m < 4; m++){
        int rr = wm + m * 16 + lrow;
        af[m] = *(const short8v*)&As[rr * 64 + ((slot ^ (rr & 7)) << 3)];
      }
#pragma unroll
      for (int n = 0; n < 4; n++){
        int rr = wn + n * 16 + lrow;
        bw[n] = *(const short8v*)&Ws[rr * 64 + ((slot ^ (rr & 7)) << 3)];
      }
#pragma unroll
      for (int m = 0; m < 4; m++)
#pragma unroll
        for (int n = 0; n < 4; n++)
          acc[m][n] = __builtin_amdgcn_mfma_f32_16x16x32_bf16(
              __builtin_bit_cast(bf16x8, af[m]),
              __builtin_bit_cast(bf16x8, bw[n]), acc[m][n], 0, 0, 0);
    }
    __syncthreads();
  }
  const int STR = 136;
#pragma unroll
  for (int n = 0; n < 4; n++){
    int col = wn + n * 16 + lrow;
    float bsv = bias[bn + col];
#pragma unroll
    for (int m = 0; m < 4; m++){
#pragma unroll
      for (int i = 0; i < 4; i++){
        int row = wm + m * 16 + lk * 4 + i;
        sh[row * STR + col] = f2bf(acc[m][n][i] + bsv);
      }
    }
  }
  __syncthreads();
#pragma unroll
  for (int it = 0; it < 8; it++){
    int r = it * 16 + (tid >> 4);
    int chunk = tid & 15;
    if (bm + r < M){
      uint4 v = *(const uint4*)((const char*)sh + r * 272 + chunk * 16);
      *(uint4*)((char*)C + ((size_t)(bm + r) * N + bn) * 2 + chunk * 16) = v;
    }
  }
}

// ---------------- 64x64 MFMA GEMM ----------------
// INB: A bf16. DUALA: A=[A0|A1] along K. EPI: 0 none,1 relu,2 sigmoid,3 +RES.
template<int EPI, int OUTB, int INB, int DUALA>
__global__ __launch_bounds__(256) void g64_k(const void* __restrict__ Av,
                                             const void* __restrict__ A1v,
                                             const float* __restrict__ W0,
                                             const float* __restrict__ W1,
                                             int NSPLIT,
                                             const float* __restrict__ bias0,
                                             const float* __restrict__ bias1,
                                             const float* __restrict__ RES,
                                             float* __restrict__ Cf,
                                             __hip_bfloat16* __restrict__ Cb,
                                             int M, int N, int K, int sA){
  __shared__ short sh64[2 * 64 * 64];
  short* As = sh64;
  short* Ws = sh64 + 64 * 64;
  const int tid = threadIdx.x;
  const int bn = blockIdx.x * 64, bm = blockIdx.y * 64;
  const int wave = tid >> 6, lane = tid & 63;
  const int wm = (wave >> 1) * 32, wn = (wave & 1) * 32;
  const int s = tid & 7, row0 = tid >> 3;
  const int lrow = lane & 15, lk = lane >> 4;
  f32x4 acc[2][2] = {};

  for (int k0 = 0; k0 < K; k0 += 64){
#pragma unroll
    for (int i = 0; i < 2; i++){
      int row = row0 + i * 32;
      int sw = ((s ^ (row & 7)) << 3) + row * 64;
      short8v v = {};
      int gr = bm + row;
      if (gr < M){
        if (INB){
          v = *(const short8v*)((const short*)Av + (size_t)gr * sA + k0 + s * 8);
        } else {
          const float* Ap;
          if (DUALA) Ap = (k0 < 256) ? (const float*)Av + (size_t)gr * 256 + k0
                                     : (const float*)A1v + (size_t)gr * 256 + (k0 - 256);
          else Ap = (const float*)Av + (size_t)gr * sA + k0;
          float4 a0 = ((const float4*)(Ap + s * 8))[0];
          float4 a1 = ((const float4*)(Ap + s * 8))[1];
          v[0]=f2bf(a0.x); v[1]=f2bf(a0.y); v[2]=f2bf(a0.z); v[3]=f2bf(a0.w);
          v[4]=f2bf(a1.x); v[5]=f2bf(a1.y); v[6]=f2bf(a1.z); v[7]=f2bf(a1.w);
        }
      }
      *(short8v*)&As[sw] = v;
      int wr = bn + row;
      const float* Wp = (wr < NSPLIT) ? W0 + (size_t)wr * K + k0
                                      : W1 + (size_t)(wr - NSPLIT) * K + k0;
      float4 b0 = ((const float4*)(Wp + s * 8))[0];
      float4 b1 = ((const float4*)(Wp + s * 8))[1];
      short8v u;
      u[0]=f2bf(b0.x); u[1]=f2bf(b0.y); u[2]=f2bf(b0.z); u[3]=f2bf(b0.w);
      u[4]=f2bf(b1.x); u[5]=f2bf(b1.y); u[6]=f2bf(b1.z); u[7]=f2bf(b1.w);
      *(short8v*)&Ws[sw] = u;
    }
    __syncthreads();
#pragma unroll
    for (int ks = 0; ks < 2; ks++){
      int slot = ks * 4 + lk;
      short8v af[2], bw[2];
#pragma unroll
      for (int m = 0; m < 2; m++){
        int r = wm + m * 16 + lrow;
        af[m] = *(const short8v*)&As[r * 64 + ((slot ^ (r & 7)) << 3)];
      }
#pragma unroll
      for (int n = 0; n < 2; n++){
        int r = wn + n * 16 + lrow;
        bw[n] = *(const short8v*)&Ws[r * 64 + ((slot ^ (r & 7)) << 3)];
      }
#pragma unroll
      for (int m = 0; m < 2; m++)
#pragma unroll
        for (int n = 0; n < 2; n++)
          acc[m][n] = __builtin_amdgcn_mfma_f32_16x16x32_bf16(
              __builtin_bit_cast(bf16x8, af[m]),
              __builtin_bit_cast(bf16x8, bw[n]), acc[m][n], 0, 0, 0);
    }
    __syncthreads();
  }
  if (OUTB){
    const int STR = 72;
#pragma unroll
    for (int n = 0; n < 2; n++){
      int col = wn + n * 16 + lrow;
      int gc = bn + col;
      float bsv = (gc < NSPLIT) ? bias0[gc] : bias1[gc - NSPLIT];
#pragma unroll
      for (int m = 0; m < 2; m++){
#pragma unroll
        for (int i = 0; i < 4; i++){
          int row = wm + m * 16 + lk * 4 + i;
          float c = acc[m][n][i] + bsv;
          if (EPI == 1) c = fmaxf(c, 0.f);
          if (EPI == 2) c = 1.f / (1.f + expf(-c));
          sh64[row * STR + col] = f2bf(c);
        }
      }
    }
    __syncthreads();
#pragma unroll
    for (int it = 0; it < 2; it++){
      int r = it * 32 + (tid >> 3);
      int chunk = tid & 7;
      if (bm + r < M){
        uint4 v = *(const uint4*)((const char*)sh64 + r * 144 + chunk * 16);
        *(uint4*)((char*)Cb + ((size_t)(bm + r) * N + bn) * 2 + chunk * 16) = v;
      }
    }
  } else {
#pragma unroll
    for (int n = 0; n < 2; n++){
      int gc = bn + wn + n * 16 + lrow;
      float bsv = (gc < NSPLIT) ? bias0[gc] : bias1[gc - NSPLIT];
#pragma unroll
      for (int m = 0; m < 2; m++){
#pragma unroll
        for (int i = 0; i < 4; i++){
          int row = bm + wm + m * 16 + lk * 4 + i;
          if (row >= M) continue;
          float c = acc[m][n][i] + bsv;
          if (EPI == 1) c = fmaxf(c, 0.f);
          if (EPI == 2) c = 1.f / (1.f + expf(-c));
          if (EPI == 3) c += RES[(size_t)row * N + gc];
          Cf[(size_t)row * N + gc] = c;
        }
      }
    }
  }
}

// ---------------- MFMA MHA: bf16 qkv in, bf16 out; NSPL strip-blocks per (b,hp) ----
template<int TP, int NSPL>
__global__ __launch_bounds__(256) void mha_mfma_k(const short* __restrict__ qkv,
                                                  __hip_bfloat16* __restrict__ out, int S){
  constexpr int MT = TP / 16;
  constexpr int KSTEPS = (TP + 31) / 32;
  constexpr int KS32 = KSTEPS * 32;
  constexpr int VSTRB = (KS32 == 128) ? 256 : 128;
  constexpr int CH = (MT + NSPL - 1) / NSPL;
  __shared__ short QK[2][TP][64];
  __shared__ short Vt[2][32][VSTRB / 2];
  __shared__ float Sc[2][16][128];
  __shared__ float rinv[2][16];

  const int tid = threadIdx.x;
  const int bid = blockIdx.x;
  const int batch = bid / (4 * NSPL);
  const int rem = bid % (4 * NSPL);
  const int hp = rem / NSPL;
  const int half = rem % NSPL;
  const int mtlo = half * CH;
  const int mthi = (mtlo + CH < MT) ? (mtlo + CH) : MT;
  const int wave = tid >> 6, lane = tid & 63;
  const int hh = wave >> 1, wsub = wave & 1;
  const int lrow = lane & 15, lk = lane >> 4;
  const float scale = 0.17677669529663687f;  // 1/sqrt(32)
  const size_t qbase = (size_t)batch * S * 768;

  for (int idx = tid; idx < 2 * TP * 4; idx += 256){
    int h2 = idx >= TP * 4;
    int rm = idx - h2 * TP * 4;
    int j = rm >> 2, s = rm & 3;
    int h = hp * 2 + h2;
    short8v qv = {}, kv = {};
    if (j < S){
      const short* p = qkv + qbase + (size_t)j * 768 + h * 32 + s * 8;
      qv = *(const short8v*)p;
      kv = *(const short8v*)(p + 256);
    }
    *(short8v*)&QK[h2][j][(s ^ (j & 7)) << 3] = qv;
    *(short8v*)&QK[h2][j][((s + 4) ^ (j & 7)) << 3] = kv;
  }
  for (int idx = tid; idx < 2 * KS32 * 4; idx += 256){
    int h2 = idx >= KS32 * 4;
    int rm = idx - h2 * KS32 * 4;
    int j = rm >> 2, e8 = rm & 3;
    int h = hp * 2 + h2;
    short8v v = {};
    if (j < S) v = *(const short8v*)(qkv + qbase + (size_t)j * 768 + h * 32 + 512 + e8 * 8);
#pragma unroll
    for (int c = 0; c < 8; c++){
      int e = e8 * 8 + c;
      char* pb = (char*)&Vt[h2][0][0] + e * VSTRB + (((j >> 3) ^ (e & 7)) << 4) + ((j & 7) << 1);
      *(short*)pb = v[c];
    }
  }
  __syncthreads();

  for (int mt = mtlo; mt < mthi; mt++){
    for (int nt = wsub; nt < MT; nt += 2){
      int ar = mt * 16 + lrow;
      short8v aq = *(const short8v*)&QK[hh][ar][(lk ^ (ar & 7)) << 3];
      int br = nt * 16 + lrow;
      short8v bk = *(const short8v*)&QK[hh][br][((lk + 4) ^ (br & 7)) << 3];
      f32x4 z = {};
      f32x4 d = __builtin_amdgcn_mfma_f32_16x16x32_bf16(
          __builtin_bit_cast(bf16x8, aq), __builtin_bit_cast(bf16x8, bk), z, 0, 0, 0);
#pragma unroll
      for (int i = 0; i < 4; i++){
        int rr = lk * 4 + i;
        int c = nt * 16 + lrow;
        Sc[hh][rr][(((c >> 2) ^ (rr & 7)) << 2) + (c & 3)] = d[i] * scale;
      }
    }
    __syncthreads();
    if (wsub == 0){
      int rr = lane >> 2, p = lane & 3;
      int grow = mt * 16 + rr;
      int Seff = (grow < S) ? S : 0;
      float mx = -1e30f;
#pragma unroll
      for (int m = 0; m < KSTEPS; m++){
        int j = p + 4 * m;
#pragma unroll
        for (int hf = 0; hf < 2; hf++){
          int ls = 2 * j + hf;
          float4 v = *(const float4*)&Sc[hh][rr][(ls ^ (rr & 7)) << 2];
          int c0 = ls * 4;
          mx = fmaxf(mx, (c0 + 0 < Seff) ? v.x : -1e30f);
          mx = fmaxf(mx, (c0 + 1 < Seff) ? v.y : -1e30f);
          mx = fmaxf(mx, (c0 + 2 < Seff) ? v.z : -1e30f);
          mx = fmaxf(mx, (c0 + 3 < Seff) ? v.w : -1e30f);
        }
      }
      mx = fmaxf(mx, __shfl_xor(mx, 1, 64));
      mx = fmaxf(mx, __shfl_xor(mx, 2, 64));
      float sum = 0.f;
#pragma unroll
      for (int m = 0; m < KSTEPS; m++){
        int j = p + 4 * m;
        float ev[8];
#pragma unroll
        for (int hf = 0; hf < 2; hf++){
          int ls = 2 * j + hf;
          float4 v = *(const float4*)&Sc[hh][rr][(ls ^ (rr & 7)) << 2];
          int c0 = ls * 4;
          ev[hf * 4 + 0] = (c0 + 0 < Seff) ? __expf(v.x - mx) : 0.f;
          ev[hf * 4 + 1] = (c0 + 1 < Seff) ? __expf(v.y - mx) : 0.f;
          ev[hf * 4 + 2] = (c0 + 2 < Seff) ? __expf(v.z - mx) : 0.f;
          ev[hf * 4 + 3] = (c0 + 3 < Seff) ? __expf(v.w - mx) : 0.f;
        }
        short8v pb;
#pragma unroll
        for (int q2 = 0; q2 < 8; q2++){ pb[q2] = f2bf(ev[q2]); sum += ev[q2]; }
        *(short8v*)((char*)&Sc[hh][rr][0] + ((j ^ (rr & 7)) << 4)) = pb;
      }
      sum += __shfl_xor(sum, 1, 64);
      sum += __shfl_xor(sum, 2, 64);
      if (p == 0) rinv[hh][rr] = (sum > 0.f) ? 1.f / sum : 0.f;
    }
    __syncthreads();
    {
      int nt2 = wsub;
      f32x4 acc = {};
#pragma unroll
      for (int ks = 0; ks < KSTEPS; ks++){
        int slot = ks * 4 + lk;
        short8v ap = *(const short8v*)((const char*)&Sc[hh][lrow][0] + ((slot ^ (lrow & 7)) << 4));
        int e = nt2 * 16 + lrow;
        short8v bv = *(const short8v*)((const char*)&Vt[hh][0][0] + e * VSTRB + ((slot ^ (e & 7)) << 4));
        acc = __builtin_amdgcn_mfma_f32_16x16x32_bf16(
            __builtin_bit_cast(bf16x8, ap), __builtin_bit_cast(bf16x8, bv), acc, 0, 0, 0);
      }
      int h = hp * 2 + hh;
#pragma unroll
      for (int i = 0; i < 4; i++){
        int row = mt * 16 + lk * 4 + i;
        if (row < S){
          float rv = rinv[hh][lk * 4 + i];
          out[((size_t)batch * S + row) * 256 + h * 32 + nt2 * 16 + lrow] =
              __float2bfloat16(acc[i] * rv);
        }
      }
    }
    __syncthreads();
  }
}

// ---------------- LayerNorm over 256 ----------------
// MODE 3: un-transpose write + qpost add; MODE 4: transpose write, x=a+b+qpre;
// MODE 5: single-input clip.
template<int MODE>
__global__ __launch_bounds__(64) void ln_k(const float* __restrict__ a,
                                           const float* __restrict__ b,
                                           const float* __restrict__ g,
                                           const float* __restrict__ be,
                                           float* __restrict__ out,
                                           const float* __restrict__ qpre,
                                           const float* __restrict__ qpost){
  int r = blockIdx.x;
  int lane = threadIdx.x;
  float4 xa = *(const float4*)(a + (size_t)r * 256 + lane * 4);
  float x[4] = { xa.x, xa.y, xa.z, xa.w };
  if (MODE != 5){
    float4 xb = *(const float4*)(b + (size_t)r * 256 + lane * 4);
    x[0] += xb.x; x[1] += xb.y; x[2] += xb.z; x[3] += xb.w;
  }
  if (MODE == 4){
    float4 xq = *(const float4*)(qpre + (size_t)r * 256 + lane * 4);
    x[0] += xq.x; x[1] += xq.y; x[2] += xq.z; x[3] += xq.w;
  }
  if (MODE == 5){
#pragma unroll
    for (int i = 0; i < 4; i++) x[i] = fminf(fmaxf(x[i], -65504.f), 65504.f);
  }
  float s = x[0] + x[1] + x[2] + x[3];
  s = wave_sum(s);
  float mean = s * (1.f / 256.f);
  float sq = 0.f;
#pragma unroll
  for (int i = 0; i < 4; i++){ float d = x[i] - mean; sq += d * d; }
  float var = wave_sum(sq) * (1.f / 256.f);
  float rstd = rsqrtf(var + 1e-5f);
  float4 gg = *(const float4*)(g + lane * 4);
  float4 bb = *(const float4*)(be + lane * 4);
  size_t orow = r;
  if (MODE == 3){
    int bi = r / LQ; int rem = r % LQ; int kk = rem / NQ_; int q = rem % NQ_;
    orow = (size_t)bi * LQ + q * NK_ + kk;
  }
  if (MODE == 4){
    int bi = r / LQ; int rem = r % LQ; int q = rem / NK_; int kk = rem % NK_;
    orow = (size_t)bi * LQ + kk * NQ_ + q;
  }
  float4 o;
  o.x = (x[0] - mean) * rstd * gg.x + bb.x;
  o.y = (x[1] - mean) * rstd * gg.y + bb.y;
  o.z = (x[2] - mean) * rstd * gg.z + bb.z;
  o.w = (x[3] - mean) * rstd * gg.w + bb.w;
  if (MODE == 3){
    float4 qv = *(const float4*)(qpost + orow * 256 + lane * 4);
    o.x += qv.x; o.y += qv.y; o.z += qv.z; o.w += qv.w;
  }
  *(float4*)(out + orow * 256 + lane * 4) = o;
}

// ---------------- gate combine + LN (G in bf16) ----------------
__global__ __launch_bounds__(64) void gate_ln_k(const short* __restrict__ G,
                                                const float* __restrict__ aq,
                                                const float* __restrict__ t2,
                                                const float* __restrict__ g,
                                                const float* __restrict__ be,
                                                float* __restrict__ out){
  int r = blockIdx.x;
  int lane = threadIdx.x;
  const short* gp = G + (size_t)r * 512 + lane * 4;
  float g1v[4], g2v[4];
#pragma unroll
  for (int i = 0; i < 4; i++){ g1v[i] = bf2f(gp[i]); g2v[i] = bf2f(gp[256 + i]); }
  float4 xa = *(const float4*)(aq + (size_t)r * 256 + lane * 4);
  float4 xt = *(const float4*)(t2 + (size_t)r * 256 + lane * 4);
  float x[4] = { g1v[0] * xa.x + g2v[0] * xt.x, g1v[1] * xa.y + g2v[1] * xt.y,
                 g1v[2] * xa.z + g2v[2] * xt.z, g1v[3] * xa.w + g2v[3] * xt.w };
  float s = x[0] + x[1] + x[2] + x[3];
  s = wave_sum(s);
  float mean = s * (1.f / 256.f);
  float sq = 0.f;
#pragma unroll
  for (int i = 0; i < 4; i++){ float d = x[i] - mean; sq += d * d; }
  float var = wave_sum(sq) * (1.f / 256.f);
  float rstd = rsqrtf(var + 1e-5f);
  float4 gg = *(const float4*)(g + lane * 4);
  float4 bb = *(const float4*)(be + lane * 4);
  float4 o;
  o.x = (x[0] - mean) * rstd * gg.x + bb.x;
  o.y = (x[1] - mean) * rstd * gg.y + bb.y;
  o.z = (x[2] - mean) * rstd * gg.z + bb.z;
  o.w = (x[3] - mean) * rstd * gg.w + bb.w;
  *(float4*)(out + (size_t)r * 256 + lane * 4) = o;
}

// ---------------- deformable sampling, two-phase; bf16 out ----------------
__global__ __launch_bounds__(256) void deform_k(const __hip_bfloat16* __restrict__ val,
                                                const float* __restrict__ offaw,
                                                const float* __restrict__ ref,
                                                unsigned int* __restrict__ outb){
  __shared__ uint2 meta[32][16][4];
  const int tid = threadIdx.x;
  const int t0 = blockIdx.x * 4;
  {
    int g = tid >> 3;
    int pair = tid & 7;
    int lt = g >> 3, h = g & 7;
    int t = t0 + lt;
    int b = t / LQ;
    int p0 = pair * 2;
    int l = p0 >> 2;
    const int starts[4] = {0, 25600, 32000, 33600};
    const int HS[4] = {160, 80, 40, 20};
    int w = HS[l];
    const float* ap = offaw + (size_t)t * 384 + 256 + h * 16;
    float a0 = ap[p0];
    float a1 = ap[p0 + 1];
    float mx = fmaxf(a0, a1);
#pragma unroll
    for (int m = 1; m <= 4; m <<= 1) mx = fmaxf(mx, __shfl_xor(mx, m, 64));
    float e0 = expf(a0 - mx), e1 = expf(a1 - mx);
    float s = e0 + e1;
#pragma unroll
    for (int m = 1; m <= 4; m <<= 1) s += __shfl_xor(s, m, 64);
    float inv = 1.f / s;
    float rx = ref[((size_t)t * 4 + l) * 2 + 0];
    float ry = ref[((size_t)t * 4 + l) * 2 + 1];
    float4 ov = *(const float4*)(offaw + (size_t)t * 384 + h * 32 + l * 8 + p0 * 2);
    int vbase = (b * LEN_VV + starts[l]) * 128 + h * 16;
#pragma unroll
    for (int pp = 0; pp < 2; pp++){
      float wgt = (pp ? e1 : e0) * inv;
      float px = rx * w + (pp ? ov.z : ov.x) - 0.5f;
      float py = ry * w + (pp ? ov.w : ov.y) - 0.5f;
      float x0f = floorf(px), y0f = floorf(py);
      float lx = px - x0f, ly = py - y0f;
      int x0 = (int)x0f, y0 = (int)y0f;
#pragma unroll
      for (int c = 0; c < 4; c++){
        int dx = c & 1, dy = c >> 1;
        int xi = x0 + dx, yi = y0 + dy;
        bool ok = (xi >= 0) & (xi < w) & (yi >= 0) & (yi < w);
        float cw = ok ? wgt * (dx ? lx : 1.f - lx) * (dy ? ly : 1.f - ly) : 0.f;
        uint idx = ok ? (uint)(vbase + (yi * w + xi) * 128) : 0u;
        uint2 m2; m2.x = idx; m2.y = __float_as_uint(cw);
        meta[g][p0 + pp][c] = m2;
      }
    }
  }
  __syncthreads();
  const uint* V2 = (const uint*)val;
  int sg = tid >> 4, lane = tid & 15;
#pragma unroll
  for (int it = 0; it < 2; it++){
    int g = it * 16 + sg;
    int lt = g >> 3, h = g & 7;
    int t = t0 + lt;
    float ax = 0.f, ay = 0.f;
#pragma unroll 4
    for (int c = 0; c < 64; c++){
      uint2 mw = meta[g][c >> 2][c & 3];
      float wv = __uint_as_float(mw.y);
      uint v = V2[(size_t)mw.x + lane];
      float lo = __uint_as_float(v << 16);
      float hi = __uint_as_float(v & 0xffff0000u);
      ax += wv * lo;
      ay += wv * hi;
    }
    uint u = ((uint)(unsigned short)f2bf(ay) << 16) | (uint)(unsigned short)f2bf(ax);
    outb[((size_t)t * 256 + h * 32) / 2 + lane] = u;
  }
}

extern "C" void kernel_launch(void* const* d_in, const int* in_sizes, int n_in,
                              void* d_out, int out_size, void* d_ws, size_t ws_size,
                              hipStream_t stream){
  const float* tgt_pose = (const float*)d_in[0];
  const float* qpos     = (const float*)d_in[1];
  const float* refp     = (const float*)d_in[2];
  const float* memory   = (const float*)d_in[3];
  const float* win_Wqkv = (const float*)d_in[4];
  const float* win_bqkv = (const float*)d_in[5];
  const float* win_Wo   = (const float*)d_in[6];
  const float* win_bo   = (const float*)d_in[7];
  const float* win_ng   = (const float*)d_in[8];
  const float* win_nb   = (const float*)d_in[9];
  const float* acr_Wqkv = (const float*)d_in[10];
  const float* acr_bqkv = (const float*)d_in[11];
  const float* acr_Wo   = (const float*)d_in[12];
  const float* acr_bo   = (const float*)d_in[13];
  const float* acr_ng   = (const float*)d_in[14];
  const float* acr_nb   = (const float*)d_in[15];
  const float* off_W    = (const float*)d_in[16];
  const float* off_b    = (const float*)d_in[17];
  const float* aw_W     = (const float*)d_in[18];
  const float* aw_b     = (const float*)d_in[19];
  const float* val_W    = (const float*)d_in[20];
  const float* val_b    = (const float*)d_in[21];
  const float* outp_W   = (const float*)d_in[22];
  const float* outp_b   = (const float*)d_in[23];
  const float* gate_W   = (const float*)d_in[24];
  const float* gate_b   = (const float*)d_in[25];
  const float* gate_ng  = (const float*)d_in[26];
  const float* gate_nb  = (const float*)d_in[27];
  const float* ffn_W1   = (const float*)d_in[28];
  const float* ffn_b1   = (const float*)d_in[29];
  const float* ffn_W2   = (const float*)d_in[30];
  const float* ffn_b2   = (const float*)d_in[31];
  const float* n2_g     = (const float*)d_in[32];
  const float* n2_b     = (const float*)d_in[33];

  float* out = (float*)d_out;
  char* ws = (char*)d_ws;
  const size_t TB = (size_t)T_TOK * 256 * 4;
  float* B0 = (float*)(ws);
  float* B1 = (float*)(ws + TB);
  float* B2 = (float*)(ws + 2 * TB);
  float* B3 = (float*)(ws + 3 * TB);
  char* p = ws + 4 * TB;
  short* Qb = (short*)p;                 p += (size_t)T_TOK * 768 * 2;
  short* ABF = (short*)p;                p += (size_t)T_TOK * 256 * 2;
  float* OFFAW = (float*)p;              p += (size_t)T_TOK * 384 * 4;
  short* Gb = (short*)p;                 p += (size_t)T_TOK * 512 * 2;
  char* Vregion = p;
  __hip_bfloat16* V = (__hip_bfloat16*)Vregion;
  short* FF = (short*)Vregion;                    // overlay (V dead after deform)

  const int GM128 = (T_TOK + 127) / 128;   // 107
  const int GM64  = (T_TOK + 63) / 64;     // 213
  const int BIG = 1 << 30;
  const int NJ0 = 6 * GM128;               // 642 qkv blocks
  const int NJ1 = 2 * 2125;                // 4250 value blocks

  // 1. dual: within-qkv (A = tgt_pose+qpos) -> Qb  ||  value proj -> V
  dualgemm_k<<<NJ0 + NJ1, 256, 0, stream>>>(
      tgt_pose, qpos, win_Wqkv, win_bqkv, (__hip_bfloat16*)Qb, T_TOK, 768, 6, NJ0,
      memory, val_W, val_b, V, BS_ * LEN_VV, 256, 2);
  // 2. within attention (S=17)
  mha_mfma_k<32,1><<<800 * 4, 256, 0, stream>>>(Qb, (__hip_bfloat16*)ABF, 17);
  // 3. out proj -> B2
  g64_k<0,0,1,0><<<dim3(4, GM64), 256, 0, stream>>>(ABF, nullptr, win_Wo, win_Wo, BIG, win_bo, win_bo, nullptr, B2, nullptr, T_TOK, 256, 256, 256);
  // 4. LN(tgt_pose + qpos + B2) + transpose-write -> B1 (b,k,q)
  ln_k<4><<<T_TOK, 64, 0, stream>>>(tgt_pose, B2, win_ng, win_nb, B1, qpos, nullptr);
  // 5. across qkv -> Qb
  mgemm_k<0><<<dim3(6, GM128), 256, 0, stream>>>(B1, acr_Wqkv, acr_bqkv, (__hip_bfloat16*)Qb, T_TOK, 768, 256);
  // 6. across attention (S=100), 2 strip-blocks per (b,hp)
  mha_mfma_k<112,2><<<136 * 8, 256, 0, stream>>>(Qb, (__hip_bfloat16*)ABF, 100);
  // 7. out proj -> B2
  g64_k<0,0,1,0><<<dim3(4, GM64), 256, 0, stream>>>(ABF, nullptr, acr_Wo, acr_Wo, BIG, acr_bo, acr_bo, nullptr, B2, nullptr, T_TOK, 256, 256, 256);
  // 8. LN + un-transpose + qpos add -> B0 = tgt_q (b,q,k)
  ln_k<3><<<T_TOK, 64, 0, stream>>>(B1, B2, acr_ng, acr_nb, B0, nullptr, qpos);
  // 9. offsets + aw logits fused (N=384) -> OFFAW
  g64_k<0,0,0,0><<<dim3(6, GM64), 256, 0, stream>>>(B0, nullptr, off_W, aw_W, 256, off_b, aw_b, nullptr, OFFAW, nullptr, T_TOK, 384, 256, 256);
  // 10. deformable sampling -> ABF bf16
  deform_k<<<T_TOK / 4, 256, 0, stream>>>(V, OFFAW, refp, (unsigned int*)ABF);
  // 11. output proj of deformable attn -> B3
  g64_k<0,0,1,0><<<dim3(4, GM64), 256, 0, stream>>>(ABF, nullptr, outp_W, outp_W, BIG, outp_b, outp_b, nullptr, B3, nullptr, T_TOK, 256, 256, 256);
  // 12. gate GEMM (dual-A concat, sigmoid, bf16 out) -> Gb
  g64_k<2,1,0,1><<<dim3(8, GM64), 256, 0, stream>>>(B0, B3, gate_W, gate_W, BIG, gate_b, gate_b, nullptr, nullptr, (__hip_bfloat16*)Gb, T_TOK, 512, 512, 256);
  // 13. gate combine + LN -> B2 = tgt3
  gate_ln_k<<<T_TOK, 64, 0, stream>>>(Gb, B0, B3, gate_ng, gate_nb, B2);
  // 14. FFN up (relu, bf16 out) -> FF
  mgemm_k<1><<<dim3(8, GM128), 256, 0, stream>>>(B2, ffn_W1, ffn_b1, (__hip_bfloat16*)FF, T_TOK, 1024, 256);
  // 15. FFN down + residual(B2) -> B1
  g64_k<3,0,1,0><<<dim3(4, GM64), 256, 0, stream>>>(FF, nullptr, ffn_W2, ffn_W2, BIG, ffn_b2, ffn_b2, B2, B1, nullptr, T_TOK, 256, 1024, 1024);
  // 16. final clip + LN -> out
  ln_k<5><<<T_TOK, 64, 0, stream>>>(B1, nullptr, n2_g, n2_b, out, nullptr, nullptr);
}